// Round 6
// baseline (1542.628 us; speedup 1.0000x reference)
//
#include <hip/hip_runtime.h>

#define DEVI static __device__ __forceinline__

constexpr int B = 8;
constexpr int N0 = 4096;
constexpr int KNB = 64;

typedef float f32x2 __attribute__((ext_vector_type(2)));

// d2 exactly as numpy: ((dx*dx + dy*dy) + dz*dz), no FMA contraction.
DEVI float dist2f(float ax, float ay, float az, float bx, float by, float bz) {
#pragma clang fp contract(off)
  float dx = ax - bx;
  float dy = ay - by;
  float dz = az - bz;
  return (dx * dx + dy * dy) + dz * dz;
}
// packed-pair version; same per-component rounding (mul/add only, no contract)
DEVI f32x2 dist2v(f32x2 ax, f32x2 ay, f32x2 az, float bx, float by, float bz) {
#pragma clang fp contract(off)
  f32x2 dx = ax - bx;
  f32x2 dy = ay - by;
  f32x2 dz = az - bz;
  return (dx * dx + dy * dy) + dz * dz;
}

// ascending key: min (d2, idx) wins; d2>=0 so float bits are monotone
DEVI unsigned long long packMinKey(float v, int i) {
  return ((unsigned long long)__float_as_uint(v) << 32) | (unsigned int)i;
}

// f32 max / u32 min wave-64 reductions on the VALU pipe (DPP), result
// broadcast to all lanes via readlane(63).
template <int CTRL, int RM>
DEVI float dppMaxF32(float v) {
  int o = __builtin_amdgcn_update_dpp(__float_as_int(v), __float_as_int(v),
                                      CTRL, RM, 0xf, false);
  return fmaxf(v, __int_as_float(o));
}
DEVI float waveMaxF32(float v) {
  v = dppMaxF32<0x111, 0xf>(v);  // row_shr:1
  v = dppMaxF32<0x112, 0xf>(v);  // row_shr:2
  v = dppMaxF32<0x114, 0xf>(v);  // row_shr:4
  v = dppMaxF32<0x118, 0xf>(v);  // row_shr:8
  v = dppMaxF32<0x142, 0xa>(v);  // row_bcast:15 -> rows 1,3
  v = dppMaxF32<0x143, 0xc>(v);  // row_bcast:31 -> rows 2,3
  return __int_as_float(__builtin_amdgcn_readlane(__float_as_int(v), 63));
}
template <int CTRL, int RM>
DEVI unsigned dppMinU32(unsigned v) {
  int o = __builtin_amdgcn_update_dpp((int)v, (int)v, CTRL, RM, 0xf, false);
  unsigned ov = (unsigned)o;
  return v < ov ? v : ov;
}
DEVI unsigned waveMinU32(unsigned v) {
  v = dppMinU32<0x111, 0xf>(v);
  v = dppMinU32<0x112, 0xf>(v);
  v = dppMinU32<0x114, 0xf>(v);
  v = dppMinU32<0x118, 0xf>(v);
  v = dppMinU32<0x142, 0xa>(v);
  v = dppMinU32<0x143, 0xc>(v);
  return (unsigned)__builtin_amdgcn_readlane((int)v, 63);
}

// ---------------- embedding + point_id_emb ----------------
__global__ void __launch_bounds__(256) x0_kernel(const int* __restrict__ feat,
                                                 const float* __restrict__ emb,
                                                 const float* __restrict__ pid,
                                                 float* __restrict__ x0) {
  int gid = blockIdx.x * 256 + threadIdx.x;  // over B*N0*32
  if (gid >= B * N0 * 32) return;
  int c = gid & 31;
  int bn = gid >> 5;
  int n = bn & (N0 - 1);
  int f = feat[bn];
  float v = emb[f * 32 + c];
  if (n < 1024) v += pid[n * 32 + c];
  x0[gid] = v;
}

// ---------------- farthest point sampling ----------------
// CRITICAL: no global stores inside the loop — __syncthreads drains vmcnt(0),
// so an in-loop pos_out store puts HBM store-retire latency on every
// iteration's critical path. Selected positions accumulate in LDS (outp) and
// are dumped once at the end.
// Selection semantics identical to jnp.argmax (ties -> lowest index).
template <int NPTS, int M, int BLK>
__global__ void __launch_bounds__(BLK) fps_kernel(const float* __restrict__ pos,
                                                  float* __restrict__ pos_out) {
  constexpr int EPT = NPTS / BLK;
  constexpr int EP2 = EPT / 2;
  constexpr int NW = BLK / 64;
  __shared__ float4 posl[NPTS];
  __shared__ float4 outp[M];
  __shared__ alignas(16) unsigned long long redk[2][NW < 2 ? 2 : NW];
  const int b = blockIdx.x;
  const int t = threadIdx.x;
  const float* pb = pos + (size_t)b * NPTS * 3;
  f32x2 px[EP2], py[EP2], pz[EP2], d[EP2];
#pragma unroll
  for (int e = 0; e < EP2; ++e) {
    int i0 = t + (2 * e) * BLK;
    int i1 = t + (2 * e + 1) * BLK;
    float x0 = pb[i0 * 3 + 0], y0 = pb[i0 * 3 + 1], z0 = pb[i0 * 3 + 2];
    float x1 = pb[i1 * 3 + 0], y1 = pb[i1 * 3 + 1], z1 = pb[i1 * 3 + 2];
    px[e] = (f32x2){x0, x1};
    py[e] = (f32x2){y0, y1};
    pz[e] = (f32x2){z0, z1};
    posl[i0] = make_float4(x0, y0, z0, 0.f);
    posl[i1] = make_float4(x1, y1, z1, 0.f);
  }
  float sx = pb[0], sy = pb[1], sz = pb[2];
  if (t == 0) outp[0] = make_float4(sx, sy, sz, 0.f);
#pragma unroll
  for (int e = 0; e < EP2; ++e) d[e] = dist2v(px[e], py[e], pz[e], sx, sy, sz);

  for (int it = 1; it < M; ++it) {
    // wave max value (exact fmax tree -> DPP -> uniform via readlane)
    float lm = fmaxf(d[0].x, d[0].y);
#pragma unroll
    for (int e = 1; e < EP2; ++e) lm = fmaxf(lm, fmaxf(d[e].x, d[e].y));
    const float vstar = waveMaxF32(lm);
    // wave's lowest index attaining vstar (>=1 lane matches within the wave)
    unsigned cand = 0xffffffffu;
#pragma unroll
    for (int e = 0; e < EP2; ++e) {
      unsigned c0 = (d[e].x == vstar) ? (unsigned)(t + (2 * e) * BLK) : 0xffffffffu;
      unsigned c1 = (d[e].y == vstar) ? (unsigned)(t + (2 * e + 1) * BLK) : 0xffffffffu;
      cand = cand < c0 ? cand : c0;
      cand = cand < c1 ? cand : c1;
    }
    cand = waveMinU32(cand);
    unsigned sel;
    if constexpr (NW > 1) {
      if ((t & 63) == 0) {
        unsigned long long key =
            ((unsigned long long)__float_as_uint(vstar) << 32) |
            (unsigned)(0x7fffffffu - cand);
        redk[it & 1][t >> 6] = key;
      }
      __syncthreads();  // double-buffered -> single barrier is race-free
      unsigned long long kk = redk[it & 1][0];
#pragma unroll
      for (int w = 1; w < NW; ++w) {
        unsigned long long o = redk[it & 1][w];
        kk = (kk > o) ? kk : o;
      }
      sel = 0x7fffffffu - (unsigned)(kk & 0xffffffffULL);
    } else {
      sel = cand;
    }
    float4 sp = posl[sel];  // LDS broadcast
    if (t == 0) outp[it] = sp;  // LDS only — no vmcnt traffic in the loop
#pragma unroll
    for (int e = 0; e < EP2; ++e) {
      f32x2 nd = dist2v(px[e], py[e], pz[e], sp.x, sp.y, sp.z);
      d[e].x = fminf(d[e].x, nd.x);
      d[e].y = fminf(d[e].y, nd.y);
    }
  }
  __syncthreads();
  for (int m = t; m < M; m += BLK) {
    float4 q = outp[m];
    pos_out[(size_t)(b * M + m) * 3 + 0] = q.x;
    pos_out[(size_t)(b * M + m) * 3 + 1] = q.y;
    pos_out[(size_t)(b * M + m) * 3 + 2] = q.z;
  }
}

// ---------------- radius neighbors (<=64 nearest within r) ----------------
// Single distance pass compacts candidate keys (atomic order irrelevant);
// if count <= 64 the first-pass nbr writes stand (set semantics — max-agg is
// order-independent). Overflow: rank select — rank_i = #{j: key_j < key_i}
// over broadcast LDS reads; keys unique -> ranks unique -> exact top-64 by
// (d2, idx) ascending == lax.top_k ordering with ties -> lower index.
template <int NPTS, int M>
__global__ void __launch_bounds__(256) radius_kernel(const float* __restrict__ pos,
                                                     const float* __restrict__ pos_s,
                                                     float r2,
                                                     int* __restrict__ nbr,
                                                     int* __restrict__ cnt) {
  __shared__ unsigned long long candkey[NPTS];
  __shared__ int ctr;
  const int blk = blockIdx.x;
  const int t = threadIdx.x;
  const int b = blk / M;
  const float* pb = pos + (size_t)b * NPTS * 3;
  const float cx = pos_s[(size_t)blk * 3 + 0];
  const float cy = pos_s[(size_t)blk * 3 + 1];
  const float cz = pos_s[(size_t)blk * 3 + 2];
  if (t == 0) ctr = 0;
  __syncthreads();
  for (int j = t; j < NPTS; j += 256) {
    float d2 = dist2f(pb[j * 3 + 0], pb[j * 3 + 1], pb[j * 3 + 2], cx, cy, cz);
    if (d2 <= r2) {
      int p = atomicAdd(&ctr, 1);
      candkey[p] = packMinKey(d2, j);
      if (p < KNB) nbr[(size_t)blk * KNB + p] = j;
    }
  }
  __syncthreads();
  const int c = ctr;
  if (c <= KNB) {
    if (t == 0) cnt[blk] = c;
    return;
  }
  for (int s = t; s < c; s += 256) {
    unsigned long long mykey = candkey[s];
    int rank = 0;
#pragma unroll 4
    for (int j = 0; j < c; ++j) {
      rank += (candkey[j] < mykey) ? 1 : 0;  // uniform addr -> LDS broadcast
    }
    if (rank < KNB)
      nbr[(size_t)blk * KNB + rank] = (int)(unsigned)(mykey & 0xffffffffULL);
  }
  if (t == 0) cnt[blk] = KNB;
}

// ---------------- stage 1 conv: 35 -> 64 -> 64 -> 64, max over nbrs ----------------
__global__ void __launch_bounds__(64) conv1_kernel(
    const float* __restrict__ x0, const float* __restrict__ pos,
    const float* __restrict__ pos_s, const int* __restrict__ nbr,
    const int* __restrict__ cntp,
    const float* __restrict__ w0, const float* __restrict__ b0,
    const float* __restrict__ w1, const float* __restrict__ b1,
    const float* __restrict__ w2, const float* __restrict__ b2,
    float* __restrict__ x1) {
  __shared__ float ins[35];
  __shared__ float h[64];
  const int blk = blockIdx.x;  // B*1024
  const int t = threadIdx.x;
  const int b = blk >> 10;
  const int c = cntp[blk];
  const float cx = pos_s[(size_t)blk * 3 + 0];
  const float cy = pos_s[(size_t)blk * 3 + 1];
  const float cz = pos_s[(size_t)blk * 3 + 2];
  float best = -__builtin_inff();
  for (int r = 0; r < c; ++r) {
    int j = nbr[(size_t)blk * KNB + r];
    if (t < 32) {
      ins[t] = x0[((size_t)(b * N0) + j) * 32 + t];
    } else if (t < 35) {
      float pv = pos[((size_t)(b * N0) + j) * 3 + (t - 32)];
      float cv = (t == 32) ? cx : (t == 33) ? cy : cz;
      ins[t] = pv - cv;
    }
    __syncthreads();
    float v = b0[t];
#pragma unroll
    for (int i = 0; i < 35; ++i) v = fmaf(ins[i], w0[i * 64 + t], v);
    v = fmaxf(v, 0.f);
    h[t] = v;
    __syncthreads();
    float v2 = b1[t];
#pragma unroll
    for (int i = 0; i < 64; ++i) v2 = fmaf(h[i], w1[i * 64 + t], v2);
    v2 = fmaxf(v2, 0.f);
    __syncthreads();
    h[t] = v2;
    __syncthreads();
    float v3 = b2[t];
#pragma unroll
    for (int i = 0; i < 64; ++i) v3 = fmaf(h[i], w2[i * 64 + t], v3);
    best = fmaxf(best, v3);
    __syncthreads();
  }
  x1[(size_t)blk * 64 + t] = best;
}

// ---------------- stage 2 conv: 67 -> 128 -> 128 -> 256, max over nbrs ----------------
__global__ void __launch_bounds__(256) conv2_kernel(
    const float* __restrict__ x1, const float* __restrict__ pos1,
    const float* __restrict__ pos2, const int* __restrict__ nbr,
    const int* __restrict__ cntp,
    const float* __restrict__ w0, const float* __restrict__ b0,
    const float* __restrict__ w1, const float* __restrict__ b1,
    const float* __restrict__ w2, const float* __restrict__ b2,
    float* __restrict__ x2) {
  __shared__ __attribute__((aligned(16))) float msg[64][68];
  __shared__ __attribute__((aligned(16))) float h[64][128];
  __shared__ float red[8][256];
  const int blk = blockIdx.x;  // B*256
  const int t = threadIdx.x;
  const int b = blk >> 8;
  const int c = cntp[blk];
  const float cx = pos2[(size_t)blk * 3 + 0];
  const float cy = pos2[(size_t)blk * 3 + 1];
  const float cz = pos2[(size_t)blk * 3 + 2];
  for (int idx = t; idx < 64 * 68; idx += 256) {
    int r = idx / 68;
    int k = idx - r * 68;
    float v = 0.f;
    if (r < c && k < 67) {
      int j = nbr[(size_t)blk * KNB + r];
      if (k < 64) {
        v = x1[((size_t)(b * 1024) + j) * 64 + k];
      } else {
        float pv = pos1[((size_t)(b * 1024) + j) * 3 + (k - 64)];
        v = pv - ((k == 64) ? cx : (k == 65) ? cy : cz);
      }
    }
    msg[r][k] = v;
  }
  __syncthreads();
  const int rg = t >> 5;  // 8 row-groups of 8 rows
  const int cg = t & 31;
  // L1: K=67 -> h[64][128]
  {
    float acc[8][4] = {};
    for (int i4 = 0; i4 < 16; ++i4) {
      float wv[4][4];
#pragma unroll
      for (int k = 0; k < 4; ++k) {
        float4 q = *(const float4*)&w0[(size_t)(i4 * 4 + k) * 128 + cg * 4];
        wv[k][0] = q.x; wv[k][1] = q.y; wv[k][2] = q.z; wv[k][3] = q.w;
      }
#pragma unroll
      for (int rr = 0; rr < 8; ++rr) {
        float4 aq = *(const float4*)&msg[rg * 8 + rr][i4 * 4];
        float a[4] = {aq.x, aq.y, aq.z, aq.w};
#pragma unroll
        for (int k = 0; k < 4; ++k)
#pragma unroll
          for (int cc = 0; cc < 4; ++cc)
            acc[rr][cc] = fmaf(a[k], wv[k][cc], acc[rr][cc]);
      }
    }
#pragma unroll
    for (int i = 64; i < 67; ++i) {
      float wv[4];
#pragma unroll
      for (int cc = 0; cc < 4; ++cc) wv[cc] = w0[(size_t)i * 128 + cg * 4 + cc];
#pragma unroll
      for (int rr = 0; rr < 8; ++rr) {
        float a = msg[rg * 8 + rr][i];
#pragma unroll
        for (int cc = 0; cc < 4; ++cc) acc[rr][cc] = fmaf(a, wv[cc], acc[rr][cc]);
      }
    }
#pragma unroll
    for (int rr = 0; rr < 8; ++rr)
#pragma unroll
      for (int cc = 0; cc < 4; ++cc)
        h[rg * 8 + rr][cg * 4 + cc] = fmaxf(acc[rr][cc] + b0[cg * 4 + cc], 0.f);
  }
  __syncthreads();
  // L2: K=128, in-place on h
  {
    float acc[8][4] = {};
    for (int i4 = 0; i4 < 32; ++i4) {
      float wv[4][4];
#pragma unroll
      for (int k = 0; k < 4; ++k) {
        float4 q = *(const float4*)&w1[(size_t)(i4 * 4 + k) * 128 + cg * 4];
        wv[k][0] = q.x; wv[k][1] = q.y; wv[k][2] = q.z; wv[k][3] = q.w;
      }
#pragma unroll
      for (int rr = 0; rr < 8; ++rr) {
        float4 aq = *(const float4*)&h[rg * 8 + rr][i4 * 4];
        float a[4] = {aq.x, aq.y, aq.z, aq.w};
#pragma unroll
        for (int k = 0; k < 4; ++k)
#pragma unroll
          for (int cc = 0; cc < 4; ++cc)
            acc[rr][cc] = fmaf(a[k], wv[k][cc], acc[rr][cc]);
      }
    }
    __syncthreads();  // all reads of h done before overwrite
#pragma unroll
    for (int rr = 0; rr < 8; ++rr)
#pragma unroll
      for (int cc = 0; cc < 4; ++cc)
        h[rg * 8 + rr][cg * 4 + cc] = fmaxf(acc[rr][cc] + b1[cg * 4 + cc], 0.f);
  }
  __syncthreads();
  // L3: K=128 -> 64x256, then masked max over rows
  {
    float acc[8][8] = {};
    for (int i4 = 0; i4 < 32; ++i4) {
      float wv[4][8];
#pragma unroll
      for (int k = 0; k < 4; ++k) {
        float4 q0 = *(const float4*)&w2[(size_t)(i4 * 4 + k) * 256 + cg * 8];
        float4 q1 = *(const float4*)&w2[(size_t)(i4 * 4 + k) * 256 + cg * 8 + 4];
        wv[k][0] = q0.x; wv[k][1] = q0.y; wv[k][2] = q0.z; wv[k][3] = q0.w;
        wv[k][4] = q1.x; wv[k][5] = q1.y; wv[k][6] = q1.z; wv[k][7] = q1.w;
      }
#pragma unroll
      for (int rr = 0; rr < 8; ++rr) {
        float4 aq = *(const float4*)&h[rg * 8 + rr][i4 * 4];
        float a[4] = {aq.x, aq.y, aq.z, aq.w};
#pragma unroll
        for (int k = 0; k < 4; ++k)
#pragma unroll
          for (int cc = 0; cc < 8; ++cc)
            acc[rr][cc] = fmaf(a[k], wv[k][cc], acc[rr][cc]);
      }
    }
    float mx[8];
#pragma unroll
    for (int cc = 0; cc < 8; ++cc) mx[cc] = -__builtin_inff();
#pragma unroll
    for (int rr = 0; rr < 8; ++rr) {
      if (rg * 8 + rr < c) {
#pragma unroll
        for (int cc = 0; cc < 8; ++cc)
          mx[cc] = fmaxf(mx[cc], acc[rr][cc] + b2[cg * 8 + cc]);
      }
    }
#pragma unroll
    for (int cc = 0; cc < 8; ++cc) red[rg][cg * 8 + cc] = mx[cc];
  }
  __syncthreads();
  {
    float v = red[0][t];
#pragma unroll
    for (int g = 1; g < 8; ++g) v = fmaxf(v, red[g][t]);
    x2[(size_t)blk * 256 + t] = v;
  }
}

// ---------------- stage 3 conv: 259 -> 256 -> 512 -> 512, max over nbrs ----------------
__global__ void __launch_bounds__(256) conv3_kernel(
    const float* __restrict__ x2, const float* __restrict__ pos2,
    const float* __restrict__ pos3, const int* __restrict__ nbr,
    const int* __restrict__ cntp,
    const float* __restrict__ w0, const float* __restrict__ b0,
    const float* __restrict__ w1, const float* __restrict__ b1,
    const float* __restrict__ w2, const float* __restrict__ b2,
    float* __restrict__ out) {
  __shared__ __attribute__((aligned(16))) float msg[16][260];
  __shared__ __attribute__((aligned(16))) float h[16][512];
  __shared__ float red[4][512];
  __shared__ float omax[512];
  const int blk = blockIdx.x;  // B*64
  const int t = threadIdx.x;
  const int b = blk >> 6;
  const int c = cntp[blk];
  const float cx = pos3[(size_t)blk * 3 + 0];
  const float cy = pos3[(size_t)blk * 3 + 1];
  const float cz = pos3[(size_t)blk * 3 + 2];
  omax[t] = -__builtin_inff();
  omax[t + 256] = -__builtin_inff();
  const int rg = t >> 6;  // 4 row-groups of 4 rows
  const int cg = t & 63;
  __syncthreads();
  for (int ch = 0; ch < 4; ++ch) {
    if (ch * 16 >= c) break;
    for (int idx = t; idx < 16 * 260; idx += 256) {
      int r = idx / 260;
      int k = idx - r * 260;
      int rglob = ch * 16 + r;
      float v = 0.f;
      if (rglob < c && k < 259) {
        int j = nbr[(size_t)blk * KNB + rglob];
        if (k < 256) {
          v = x2[((size_t)(b * 256) + j) * 256 + k];
        } else {
          float pv = pos2[((size_t)(b * 256) + j) * 3 + (k - 256)];
          v = pv - ((k == 256) ? cx : (k == 257) ? cy : cz);
        }
      }
      msg[r][k] = v;
    }
    __syncthreads();
    // L1: 16x256, K=259
    {
      float acc[4][4] = {};
      for (int i4 = 0; i4 < 64; ++i4) {
        float wv[4][4];
#pragma unroll
        for (int k = 0; k < 4; ++k) {
          float4 q = *(const float4*)&w0[(size_t)(i4 * 4 + k) * 256 + cg * 4];
          wv[k][0] = q.x; wv[k][1] = q.y; wv[k][2] = q.z; wv[k][3] = q.w;
        }
#pragma unroll
        for (int rr = 0; rr < 4; ++rr) {
          float4 aq = *(const float4*)&msg[rg * 4 + rr][i4 * 4];
          float a[4] = {aq.x, aq.y, aq.z, aq.w};
#pragma unroll
          for (int k = 0; k < 4; ++k)
#pragma unroll
            for (int cc = 0; cc < 4; ++cc)
              acc[rr][cc] = fmaf(a[k], wv[k][cc], acc[rr][cc]);
        }
      }
#pragma unroll
      for (int i = 256; i < 259; ++i) {
        float wv[4];
#pragma unroll
        for (int cc = 0; cc < 4; ++cc) wv[cc] = w0[(size_t)i * 256 + cg * 4 + cc];
#pragma unroll
        for (int rr = 0; rr < 4; ++rr) {
          float a = msg[rg * 4 + rr][i];
#pragma unroll
          for (int cc = 0; cc < 4; ++cc) acc[rr][cc] = fmaf(a, wv[cc], acc[rr][cc]);
        }
      }
#pragma unroll
      for (int rr = 0; rr < 4; ++rr)
#pragma unroll
        for (int cc = 0; cc < 4; ++cc)
          h[rg * 4 + rr][cg * 4 + cc] = fmaxf(acc[rr][cc] + b0[cg * 4 + cc], 0.f);
    }
    __syncthreads();
    // L2: 16x512, K=256, in-place on h (read cols 0..255, write 0..511)
    {
      float acc[4][8] = {};
      for (int i4 = 0; i4 < 64; ++i4) {
        float wv[4][8];
#pragma unroll
        for (int k = 0; k < 4; ++k) {
          float4 q0 = *(const float4*)&w1[(size_t)(i4 * 4 + k) * 512 + cg * 8];
          float4 q1 = *(const float4*)&w1[(size_t)(i4 * 4 + k) * 512 + cg * 8 + 4];
          wv[k][0] = q0.x; wv[k][1] = q0.y; wv[k][2] = q0.z; wv[k][3] = q0.w;
          wv[k][4] = q1.x; wv[k][5] = q1.y; wv[k][6] = q1.z; wv[k][7] = q1.w;
        }
#pragma unroll
        for (int rr = 0; rr < 4; ++rr) {
          float4 aq = *(const float4*)&h[rg * 4 + rr][i4 * 4];
          float a[4] = {aq.x, aq.y, aq.z, aq.w};
#pragma unroll
          for (int k = 0; k < 4; ++k)
#pragma unroll
            for (int cc = 0; cc < 8; ++cc)
              acc[rr][cc] = fmaf(a[k], wv[k][cc], acc[rr][cc]);
        }
      }
      __syncthreads();
#pragma unroll
      for (int rr = 0; rr < 4; ++rr)
#pragma unroll
        for (int cc = 0; cc < 8; ++cc)
          h[rg * 4 + rr][cg * 8 + cc] = fmaxf(acc[rr][cc] + b1[cg * 8 + cc], 0.f);
    }
    __syncthreads();
    // L3: 16x512, K=512, masked max
    {
      float acc[4][8] = {};
      for (int i4 = 0; i4 < 128; ++i4) {
        float wv[4][8];
#pragma unroll
        for (int k = 0; k < 4; ++k) {
          float4 q0 = *(const float4*)&w2[(size_t)(i4 * 4 + k) * 512 + cg * 8];
          float4 q1 = *(const float4*)&w2[(size_t)(i4 * 4 + k) * 512 + cg * 8 + 4];
          wv[k][0] = q0.x; wv[k][1] = q0.y; wv[k][2] = q0.z; wv[k][3] = q0.w;
          wv[k][4] = q1.x; wv[k][5] = q1.y; wv[k][6] = q1.z; wv[k][7] = q1.w;
        }
#pragma unroll
        for (int rr = 0; rr < 4; ++rr) {
          float4 aq = *(const float4*)&h[rg * 4 + rr][i4 * 4];
          float a[4] = {aq.x, aq.y, aq.z, aq.w};
#pragma unroll
          for (int k = 0; k < 4; ++k)
#pragma unroll
            for (int cc = 0; cc < 8; ++cc)
              acc[rr][cc] = fmaf(a[k], wv[k][cc], acc[rr][cc]);
        }
      }
      float mx[8];
#pragma unroll
      for (int cc = 0; cc < 8; ++cc) mx[cc] = -__builtin_inff();
#pragma unroll
      for (int rr = 0; rr < 4; ++rr) {
        if (ch * 16 + rg * 4 + rr < c) {
#pragma unroll
          for (int cc = 0; cc < 8; ++cc)
            mx[cc] = fmaxf(mx[cc], acc[rr][cc] + b2[cg * 8 + cc]);
        }
      }
#pragma unroll
      for (int cc = 0; cc < 8; ++cc) red[rg][cg * 8 + cc] = mx[cc];
    }
    __syncthreads();
    for (int k = t; k < 512; k += 256) {
      float v = omax[k];
#pragma unroll
      for (int g = 0; g < 4; ++g) v = fmaxf(v, red[g][k]);
      omax[k] = v;
    }
    __syncthreads();
  }
  out[(size_t)blk * 512 + t] = omax[t];
  out[(size_t)blk * 512 + t + 256] = omax[t + 256];
}

extern "C" void kernel_launch(void* const* d_in, const int* in_sizes, int n_in,
                              void* d_out, int out_size, void* d_ws, size_t ws_size,
                              hipStream_t stream) {
  const int* feat = (const int*)d_in[0];
  const float* pos = (const float*)d_in[1];
  const float* emb = (const float*)d_in[2];
  const float* pid = (const float*)d_in[3];
  const float* s1w0 = (const float*)d_in[4];
  const float* s1b0 = (const float*)d_in[5];
  const float* s1w1 = (const float*)d_in[6];
  const float* s1b1 = (const float*)d_in[7];
  const float* s1w2 = (const float*)d_in[8];
  const float* s1b2 = (const float*)d_in[9];
  const float* s2w0 = (const float*)d_in[10];
  const float* s2b0 = (const float*)d_in[11];
  const float* s2w1 = (const float*)d_in[12];
  const float* s2b1 = (const float*)d_in[13];
  const float* s2w2 = (const float*)d_in[14];
  const float* s2b2 = (const float*)d_in[15];
  const float* s3w0 = (const float*)d_in[16];
  const float* s3b0 = (const float*)d_in[17];
  const float* s3w1 = (const float*)d_in[18];
  const float* s3b1 = (const float*)d_in[19];
  const float* s3w2 = (const float*)d_in[20];
  const float* s3b2 = (const float*)d_in[21];
  (void)in_sizes; (void)n_in; (void)out_size; (void)ws_size;

  char* ws = (char*)d_ws;
  size_t off = 0;
  auto alloc = [&](size_t nbytes) {
    void* p = ws + off;
    off = (off + nbytes + 255) & ~(size_t)255;
    return p;
  };
  float* x0 = (float*)alloc((size_t)B * N0 * 32 * 4);
  float* pos1 = (float*)alloc((size_t)B * 1024 * 3 * 4);
  int* nbr1 = (int*)alloc((size_t)B * 1024 * KNB * 4);
  int* cnt1 = (int*)alloc((size_t)B * 1024 * 4);
  float* x1 = (float*)alloc((size_t)B * 1024 * 64 * 4);
  float* pos2 = (float*)alloc((size_t)B * 256 * 3 * 4);
  int* nbr2 = (int*)alloc((size_t)B * 256 * KNB * 4);
  int* cnt2 = (int*)alloc((size_t)B * 256 * 4);
  float* x2 = (float*)alloc((size_t)B * 256 * 256 * 4);
  int* nbr3 = (int*)alloc((size_t)B * 64 * KNB * 4);
  int* cnt3 = (int*)alloc((size_t)B * 64 * 4);

  float* xout = (float*)d_out;                 // (B,64,512)
  float* pos3 = xout + (size_t)B * 64 * 512;   // (B,64,3)

  const float r2a = (float)(0.05 * 0.05);
  const float r2b = (float)(0.3 * 0.3);
  const float r2c = (float)(0.5 * 0.5);

  x0_kernel<<<(B * N0 * 32 + 255) / 256, 256, 0, stream>>>(feat, emb, pid, x0);

  fps_kernel<4096, 1024, 256><<<B, 256, 0, stream>>>(pos, pos1);
  radius_kernel<4096, 1024><<<B * 1024, 256, 0, stream>>>(pos, pos1, r2a, nbr1, cnt1);
  conv1_kernel<<<B * 1024, 64, 0, stream>>>(x0, pos, pos1, nbr1, cnt1,
                                            s1w0, s1b0, s1w1, s1b1, s1w2, s1b2, x1);

  fps_kernel<1024, 256, 256><<<B, 256, 0, stream>>>(pos1, pos2);
  radius_kernel<1024, 256><<<B * 256, 256, 0, stream>>>(pos1, pos2, r2b, nbr2, cnt2);
  conv2_kernel<<<B * 256, 256, 0, stream>>>(x1, pos1, pos2, nbr2, cnt2,
                                            s2w0, s2b0, s2w1, s2b1, s2w2, s2b2, x2);

  fps_kernel<256, 64, 64><<<B, 64, 0, stream>>>(pos2, pos3);
  radius_kernel<256, 64><<<B * 64, 256, 0, stream>>>(pos2, pos3, r2c, nbr3, cnt3);
  conv3_kernel<<<B * 64, 256, 0, stream>>>(x2, pos2, pos3, nbr3, cnt3,
                                           s3w0, s3b0, s3w1, s3b1, s3w2, s3b2, xout);
}

// Round 7
// 1516.950 us; speedup vs baseline: 1.0169x; 1.0169x over previous
//
#include <hip/hip_runtime.h>

#define DEVI static __device__ __forceinline__

constexpr int B = 8;
constexpr int N0 = 4096;
constexpr int KNB = 64;

typedef float f32x2 __attribute__((ext_vector_type(2)));

// d2 exactly as numpy: ((dx*dx + dy*dy) + dz*dz), no FMA contraction.
DEVI float dist2f(float ax, float ay, float az, float bx, float by, float bz) {
#pragma clang fp contract(off)
  float dx = ax - bx;
  float dy = ay - by;
  float dz = az - bz;
  return (dx * dx + dy * dy) + dz * dz;
}
// packed-pair version; same per-component rounding (mul/add only, no contract)
DEVI f32x2 dist2v(f32x2 ax, f32x2 ay, f32x2 az, float bx, float by, float bz) {
#pragma clang fp contract(off)
  f32x2 dx = ax - bx;
  f32x2 dy = ay - by;
  f32x2 dz = az - bz;
  return (dx * dx + dy * dy) + dz * dz;
}

// ascending key: min (d2, idx) wins; d2>=0 so float bits are monotone
DEVI unsigned long long packMinKey(float v, int i) {
  return ((unsigned long long)__float_as_uint(v) << 32) | (unsigned int)i;
}

// f32 max / u32 min wave-64 reductions on the VALU pipe (DPP), result
// broadcast to all lanes via readlane(63).
template <int CTRL, int RM>
DEVI float dppMaxF32(float v) {
  int o = __builtin_amdgcn_update_dpp(__float_as_int(v), __float_as_int(v),
                                      CTRL, RM, 0xf, false);
  return fmaxf(v, __int_as_float(o));
}
DEVI float waveMaxF32(float v) {
  v = dppMaxF32<0x111, 0xf>(v);  // row_shr:1
  v = dppMaxF32<0x112, 0xf>(v);  // row_shr:2
  v = dppMaxF32<0x114, 0xf>(v);  // row_shr:4
  v = dppMaxF32<0x118, 0xf>(v);  // row_shr:8
  v = dppMaxF32<0x142, 0xa>(v);  // row_bcast:15 -> rows 1,3
  v = dppMaxF32<0x143, 0xc>(v);  // row_bcast:31 -> rows 2,3
  return __int_as_float(__builtin_amdgcn_readlane(__float_as_int(v), 63));
}
template <int CTRL, int RM>
DEVI unsigned dppMinU32(unsigned v) {
  int o = __builtin_amdgcn_update_dpp((int)v, (int)v, CTRL, RM, 0xf, false);
  unsigned ov = (unsigned)o;
  return v < ov ? v : ov;
}
DEVI unsigned waveMinU32(unsigned v) {
  v = dppMinU32<0x111, 0xf>(v);
  v = dppMinU32<0x112, 0xf>(v);
  v = dppMinU32<0x114, 0xf>(v);
  v = dppMinU32<0x118, 0xf>(v);
  v = dppMinU32<0x142, 0xa>(v);
  v = dppMinU32<0x143, 0xc>(v);
  return (unsigned)__builtin_amdgcn_readlane((int)v, 63);
}

// ================= device bodies (smem carved from a per-kernel union) ======

// ---- embedding + point_id_emb ----
DEVI void x0_body(const int* __restrict__ feat, const float* __restrict__ emb,
                  const float* __restrict__ pid, float* __restrict__ x0buf,
                  int bx, int t) {
  int gid = bx * 256 + t;  // over B*N0*32
  if (gid >= B * N0 * 32) return;
  int c = gid & 31;
  int bn = gid >> 5;
  int n = bn & (N0 - 1);
  int f = feat[bn];
  float v = emb[f * 32 + c];
  if (n < 1024) v += pid[n * 32 + c];
  x0buf[gid] = v;
}

// ---- farthest point sampling ----
// smem layout: posl[NPTS] float4 | outp[M] float4 | redk[2][NW] u64
// Selection semantics identical to jnp.argmax (ties -> lowest index).
template <int NPTS, int M, int BLK>
DEVI void fps_body(char* smem, const float* __restrict__ pos,
                   float* __restrict__ pos_out, int b, int t) {
  constexpr int EPT = NPTS / BLK;
  constexpr int EP2 = EPT / 2;
  constexpr int NW = BLK / 64;
  float4* posl = (float4*)smem;
  float4* outp = (float4*)(smem + (size_t)NPTS * 16);
  unsigned long long* redk =
      (unsigned long long*)(smem + (size_t)(NPTS + M) * 16);  // [2][NW]
  const float* pb = pos + (size_t)b * NPTS * 3;
  f32x2 px[EP2], py[EP2], pz[EP2], d[EP2];
#pragma unroll
  for (int e = 0; e < EP2; ++e) {
    int i0 = t + (2 * e) * BLK;
    int i1 = t + (2 * e + 1) * BLK;
    float x0 = pb[i0 * 3 + 0], y0 = pb[i0 * 3 + 1], z0 = pb[i0 * 3 + 2];
    float x1 = pb[i1 * 3 + 0], y1 = pb[i1 * 3 + 1], z1 = pb[i1 * 3 + 2];
    px[e] = (f32x2){x0, x1};
    py[e] = (f32x2){y0, y1};
    pz[e] = (f32x2){z0, z1};
    posl[i0] = make_float4(x0, y0, z0, 0.f);
    posl[i1] = make_float4(x1, y1, z1, 0.f);
  }
  float sx = pb[0], sy = pb[1], sz = pb[2];
  if (t == 0) outp[0] = make_float4(sx, sy, sz, 0.f);
  f32x2 m2 = (f32x2){-1.f, -1.f};  // running lane max (fused into update)
#pragma unroll
  for (int e = 0; e < EP2; ++e) {
    d[e] = dist2v(px[e], py[e], pz[e], sx, sy, sz);
    m2.x = fmaxf(m2.x, d[e].x);
    m2.y = fmaxf(m2.y, d[e].y);
  }
  for (int it = 1; it < M; ++it) {
    const float vstar = waveMaxF32(fmaxf(m2.x, m2.y));
    // wave's lowest index attaining vstar
    unsigned cand = 0xffffffffu;
#pragma unroll
    for (int e = 0; e < EP2; ++e) {
      unsigned c0 = (d[e].x == vstar) ? (unsigned)(t + (2 * e) * BLK) : 0xffffffffu;
      unsigned c1 = (d[e].y == vstar) ? (unsigned)(t + (2 * e + 1) * BLK) : 0xffffffffu;
      cand = cand < c0 ? cand : c0;
      cand = cand < c1 ? cand : c1;
    }
    cand = waveMinU32(cand);
    unsigned sel;
    if constexpr (NW > 1) {
      if ((t & 63) == 0) {
        unsigned long long key =
            ((unsigned long long)__float_as_uint(vstar) << 32) |
            (unsigned)(0x7fffffffu - cand);
        redk[(it & 1) * NW + (t >> 6)] = key;
      }
      __syncthreads();  // double-buffered -> single barrier is race-free
      unsigned long long kk = redk[(it & 1) * NW + 0];
#pragma unroll
      for (int w = 1; w < NW; ++w) {
        unsigned long long o = redk[(it & 1) * NW + w];
        kk = (kk > o) ? kk : o;
      }
      sel = 0x7fffffffu - (unsigned)(kk & 0xffffffffULL);
    } else {
      sel = cand;
    }
    float4 sp = posl[sel];  // LDS broadcast
    if (t == 0) outp[it] = sp;
    m2 = (f32x2){-1.f, -1.f};
#pragma unroll
    for (int e = 0; e < EP2; ++e) {
      f32x2 nd = dist2v(px[e], py[e], pz[e], sp.x, sp.y, sp.z);
      d[e].x = fminf(d[e].x, nd.x);
      d[e].y = fminf(d[e].y, nd.y);
      m2.x = fmaxf(m2.x, d[e].x);
      m2.y = fmaxf(m2.y, d[e].y);
    }
  }
  if constexpr (NW > 1) __syncthreads();
  for (int m = t; m < M; m += BLK) {
    float4 q = outp[m];
    pos_out[(size_t)(b * M + m) * 3 + 0] = q.x;
    pos_out[(size_t)(b * M + m) * 3 + 1] = q.y;
    pos_out[(size_t)(b * M + m) * 3 + 2] = q.z;
  }
}

// ---- radius neighbors (<=64 nearest within r) ----
// smem layout: candkey[NPTS] u64 | ctr int
// Rank-select on overflow: exact top-64 by (d2, idx) == lax.top_k semantics.
template <int NPTS, int M>
DEVI void radius_body(char* smem, const float* __restrict__ pos,
                      const float* __restrict__ pos_s, float r2,
                      int* __restrict__ nbr, int* __restrict__ cnt, int blk,
                      int t) {
  unsigned long long* candkey = (unsigned long long*)smem;
  int* ctrp = (int*)(smem + (size_t)NPTS * 8);
  const int b = blk / M;
  const float* pb = pos + (size_t)b * NPTS * 3;
  const float cx = pos_s[(size_t)blk * 3 + 0];
  const float cy = pos_s[(size_t)blk * 3 + 1];
  const float cz = pos_s[(size_t)blk * 3 + 2];
  if (t == 0) *ctrp = 0;
  __syncthreads();
  for (int j = t; j < NPTS; j += 256) {
    float d2 = dist2f(pb[j * 3 + 0], pb[j * 3 + 1], pb[j * 3 + 2], cx, cy, cz);
    if (d2 <= r2) {
      int p = atomicAdd(ctrp, 1);
      candkey[p] = packMinKey(d2, j);
      if (p < KNB) nbr[(size_t)blk * KNB + p] = j;
    }
  }
  __syncthreads();
  const int c = *ctrp;
  if (c <= KNB) {
    if (t == 0) cnt[blk] = c;
    return;
  }
  for (int s = t; s < c; s += 256) {
    unsigned long long mykey = candkey[s];
    int rank = 0;
#pragma unroll 4
    for (int j = 0; j < c; ++j) {
      rank += (candkey[j] < mykey) ? 1 : 0;  // uniform addr -> LDS broadcast
    }
    if (rank < KNB)
      nbr[(size_t)blk * KNB + rank] = (int)(unsigned)(mykey & 0xffffffffULL);
  }
  if (t == 0) cnt[blk] = KNB;
}

// ---- stage 1 conv: 35 -> 64 -> 64 -> 64, max over nbrs ----
// 256 threads = 4 neighbor-slots x 64 channels. Max-agg is order-independent
// -> exact. LDS rows padded (+1) to avoid 4-way bank conflicts.
// smem layout: ins[4][36] | hh[4][65] | sred[4][65]  (floats)
DEVI void conv1_body(char* smem, const float* __restrict__ x0buf,
                     const float* __restrict__ pos,
                     const float* __restrict__ pos_s,
                     const int* __restrict__ nbr, const int* __restrict__ cntp,
                     const float* __restrict__ w0, const float* __restrict__ b0,
                     const float* __restrict__ w1, const float* __restrict__ b1,
                     const float* __restrict__ w2, const float* __restrict__ b2,
                     float* __restrict__ x1, int blk, int t) {
  float(*ins)[36] = (float(*)[36])smem;
  float(*hh)[65] = (float(*)[65])(smem + 576);
  float(*sred)[65] = (float(*)[65])(smem + 1616);
  const int slot = t >> 6;
  const int ch = t & 63;
  const int b = blk >> 10;
  const int c = cntp[blk];
  const float cx = pos_s[(size_t)blk * 3 + 0];
  const float cy = pos_s[(size_t)blk * 3 + 1];
  const float cz = pos_s[(size_t)blk * 3 + 2];
  float best = -__builtin_inff();
  for (int r0 = 0; r0 < c; r0 += 4) {
    const int r = r0 + slot;
    const bool act = r < c;
    const int j = nbr[(size_t)blk * KNB + (act ? r : 0)];
    if (ch < 32) {
      ins[slot][ch] = x0buf[((size_t)(b * N0) + j) * 32 + ch];
    } else if (ch < 35) {
      float pv = pos[((size_t)(b * N0) + j) * 3 + (ch - 32)];
      float cv = (ch == 32) ? cx : (ch == 33) ? cy : cz;
      ins[slot][ch] = pv - cv;
    }
    __syncthreads();
    float v = b0[ch];
#pragma unroll
    for (int i = 0; i < 35; ++i) v = fmaf(ins[slot][i], w0[i * 64 + ch], v);
    v = fmaxf(v, 0.f);
    hh[slot][ch] = v;
    __syncthreads();
    float v2 = b1[ch];
#pragma unroll
    for (int i = 0; i < 64; ++i) v2 = fmaf(hh[slot][i], w1[i * 64 + ch], v2);
    v2 = fmaxf(v2, 0.f);
    __syncthreads();
    hh[slot][ch] = v2;
    __syncthreads();
    float v3 = b2[ch];
#pragma unroll
    for (int i = 0; i < 64; ++i) v3 = fmaf(hh[slot][i], w2[i * 64 + ch], v3);
    if (act) best = fmaxf(best, v3);
    __syncthreads();  // ins/hh reused next iteration
  }
  sred[slot][ch] = best;
  __syncthreads();
  if (t < 64) {
    float v = sred[0][t];
#pragma unroll
    for (int s = 1; s < 4; ++s) v = fmaxf(v, sred[s][t]);
    x1[(size_t)blk * 64 + t] = v;
  }
}

// ---- stage 2 conv: 67 -> 128 -> 128 -> 256, max over nbrs ----
// smem layout: msg[64][68] | h[64][128] | red[8][256]  (floats)
DEVI void conv2_body(char* smem, const float* __restrict__ x1,
                     const float* __restrict__ pos1,
                     const float* __restrict__ pos2,
                     const int* __restrict__ nbr, const int* __restrict__ cntp,
                     const float* __restrict__ w0, const float* __restrict__ b0,
                     const float* __restrict__ w1, const float* __restrict__ b1,
                     const float* __restrict__ w2, const float* __restrict__ b2,
                     float* __restrict__ x2, int blk, int t) {
  float(*msg)[68] = (float(*)[68])smem;
  float(*h)[128] = (float(*)[128])(smem + 17408);
  float(*red)[256] = (float(*)[256])(smem + 17408 + 32768);
  const int b = blk >> 8;
  const int c = cntp[blk];
  const float cx = pos2[(size_t)blk * 3 + 0];
  const float cy = pos2[(size_t)blk * 3 + 1];
  const float cz = pos2[(size_t)blk * 3 + 2];
  for (int idx = t; idx < 64 * 68; idx += 256) {
    int r = idx / 68;
    int k = idx - r * 68;
    float v = 0.f;
    if (r < c && k < 67) {
      int j = nbr[(size_t)blk * KNB + r];
      if (k < 64) {
        v = x1[((size_t)(b * 1024) + j) * 64 + k];
      } else {
        float pv = pos1[((size_t)(b * 1024) + j) * 3 + (k - 64)];
        v = pv - ((k == 64) ? cx : (k == 65) ? cy : cz);
      }
    }
    msg[r][k] = v;
  }
  __syncthreads();
  const int rg = t >> 5;  // 8 row-groups of 8 rows
  const int cg = t & 31;
  // L1: K=67 -> h[64][128]
  {
    float acc[8][4] = {};
    for (int i4 = 0; i4 < 16; ++i4) {
      float wv[4][4];
#pragma unroll
      for (int k = 0; k < 4; ++k) {
        float4 q = *(const float4*)&w0[(size_t)(i4 * 4 + k) * 128 + cg * 4];
        wv[k][0] = q.x; wv[k][1] = q.y; wv[k][2] = q.z; wv[k][3] = q.w;
      }
#pragma unroll
      for (int rr = 0; rr < 8; ++rr) {
        float4 aq = *(const float4*)&msg[rg * 8 + rr][i4 * 4];
        float a[4] = {aq.x, aq.y, aq.z, aq.w};
#pragma unroll
        for (int k = 0; k < 4; ++k)
#pragma unroll
          for (int cc = 0; cc < 4; ++cc)
            acc[rr][cc] = fmaf(a[k], wv[k][cc], acc[rr][cc]);
      }
    }
#pragma unroll
    for (int i = 64; i < 67; ++i) {
      float wv[4];
#pragma unroll
      for (int cc = 0; cc < 4; ++cc) wv[cc] = w0[(size_t)i * 128 + cg * 4 + cc];
#pragma unroll
      for (int rr = 0; rr < 8; ++rr) {
        float a = msg[rg * 8 + rr][i];
#pragma unroll
        for (int cc = 0; cc < 4; ++cc) acc[rr][cc] = fmaf(a, wv[cc], acc[rr][cc]);
      }
    }
#pragma unroll
    for (int rr = 0; rr < 8; ++rr)
#pragma unroll
      for (int cc = 0; cc < 4; ++cc)
        h[rg * 8 + rr][cg * 4 + cc] = fmaxf(acc[rr][cc] + b0[cg * 4 + cc], 0.f);
  }
  __syncthreads();
  // L2: K=128, in-place on h
  {
    float acc[8][4] = {};
    for (int i4 = 0; i4 < 32; ++i4) {
      float wv[4][4];
#pragma unroll
      for (int k = 0; k < 4; ++k) {
        float4 q = *(const float4*)&w1[(size_t)(i4 * 4 + k) * 128 + cg * 4];
        wv[k][0] = q.x; wv[k][1] = q.y; wv[k][2] = q.z; wv[k][3] = q.w;
      }
#pragma unroll
      for (int rr = 0; rr < 8; ++rr) {
        float4 aq = *(const float4*)&h[rg * 8 + rr][i4 * 4];
        float a[4] = {aq.x, aq.y, aq.z, aq.w};
#pragma unroll
        for (int k = 0; k < 4; ++k)
#pragma unroll
          for (int cc = 0; cc < 4; ++cc)
            acc[rr][cc] = fmaf(a[k], wv[k][cc], acc[rr][cc]);
      }
    }
    __syncthreads();  // all reads of h done before overwrite
#pragma unroll
    for (int rr = 0; rr < 8; ++rr)
#pragma unroll
      for (int cc = 0; cc < 4; ++cc)
        h[rg * 8 + rr][cg * 4 + cc] = fmaxf(acc[rr][cc] + b1[cg * 4 + cc], 0.f);
  }
  __syncthreads();
  // L3: K=128 -> 64x256, then masked max over rows
  {
    float acc[8][8] = {};
    for (int i4 = 0; i4 < 32; ++i4) {
      float wv[4][8];
#pragma unroll
      for (int k = 0; k < 4; ++k) {
        float4 q0 = *(const float4*)&w2[(size_t)(i4 * 4 + k) * 256 + cg * 8];
        float4 q1 = *(const float4*)&w2[(size_t)(i4 * 4 + k) * 256 + cg * 8 + 4];
        wv[k][0] = q0.x; wv[k][1] = q0.y; wv[k][2] = q0.z; wv[k][3] = q0.w;
        wv[k][4] = q1.x; wv[k][5] = q1.y; wv[k][6] = q1.z; wv[k][7] = q1.w;
      }
#pragma unroll
      for (int rr = 0; rr < 8; ++rr) {
        float4 aq = *(const float4*)&h[rg * 8 + rr][i4 * 4];
        float a[4] = {aq.x, aq.y, aq.z, aq.w};
#pragma unroll
        for (int k = 0; k < 4; ++k)
#pragma unroll
          for (int cc = 0; cc < 8; ++cc)
            acc[rr][cc] = fmaf(a[k], wv[k][cc], acc[rr][cc]);
      }
    }
    float mx[8];
#pragma unroll
    for (int cc = 0; cc < 8; ++cc) mx[cc] = -__builtin_inff();
#pragma unroll
    for (int rr = 0; rr < 8; ++rr) {
      if (rg * 8 + rr < c) {
#pragma unroll
        for (int cc = 0; cc < 8; ++cc)
          mx[cc] = fmaxf(mx[cc], acc[rr][cc] + b2[cg * 8 + cc]);
      }
    }
#pragma unroll
    for (int cc = 0; cc < 8; ++cc) red[rg][cg * 8 + cc] = mx[cc];
  }
  __syncthreads();
  {
    float v = red[0][t];
#pragma unroll
    for (int g = 1; g < 8; ++g) v = fmaxf(v, red[g][t]);
    x2[(size_t)blk * 256 + t] = v;
  }
}

// ================= merged launch kernels ====================================

// L1: fps1 (blocks 0..7) || x0 (blocks 8..4103)
__global__ void __launch_bounds__(256) l1_kernel(
    const float* __restrict__ pos, float* __restrict__ pos1,
    const int* __restrict__ feat, const float* __restrict__ emb,
    const float* __restrict__ pid, float* __restrict__ x0buf) {
  __shared__ __attribute__((aligned(16))) char smem[81984];
  if (blockIdx.x < 8) {
    fps_body<4096, 1024, 256>(smem, pos, pos1, blockIdx.x, threadIdx.x);
  } else {
    x0_body(feat, emb, pid, x0buf, blockIdx.x - 8, threadIdx.x);
  }
}

// L2: fps2 (blocks 0..7) || radius1 (blocks 8..8199)
__global__ void __launch_bounds__(256) l2_kernel(
    const float* __restrict__ pos1, float* __restrict__ pos2,
    const float* __restrict__ pos, float r2a, int* __restrict__ nbr1,
    int* __restrict__ cnt1) {
  __shared__ __attribute__((aligned(16))) char smem[33024];
  if (blockIdx.x < 8) {
    fps_body<1024, 256, 256>(smem, pos1, pos2, blockIdx.x, threadIdx.x);
  } else {
    radius_body<4096, 1024>(smem, pos, pos1, r2a, nbr1, cnt1, blockIdx.x - 8,
                            threadIdx.x);
  }
}

// L3: fps3 (blocks 0..7, wave0 only) || radius2 (8..2055) || conv1 (2056..10247)
__global__ void __launch_bounds__(256) l3_kernel(
    const float* __restrict__ pos2, float* __restrict__ pos3, float r2b,
    int* __restrict__ nbr2, int* __restrict__ cnt2,
    const float* __restrict__ pos1, const float* __restrict__ x0buf,
    const float* __restrict__ pos, const int* __restrict__ nbr1,
    const int* __restrict__ cnt1, const float* __restrict__ w0,
    const float* __restrict__ b0, const float* __restrict__ w1,
    const float* __restrict__ b1, const float* __restrict__ w2,
    const float* __restrict__ b2, float* __restrict__ x1) {
  __shared__ __attribute__((aligned(16))) char smem[8448];
  if (blockIdx.x < 8) {
    if (threadIdx.x < 64)
      fps_body<256, 64, 64>(smem, pos2, pos3, blockIdx.x, threadIdx.x);
  } else if (blockIdx.x < 8 + 2048) {
    radius_body<1024, 256>(smem, pos1, pos2, r2b, nbr2, cnt2, blockIdx.x - 8,
                           threadIdx.x);
  } else {
    conv1_body(smem, x0buf, pos, pos1, nbr1, cnt1, w0, b0, w1, b1, w2, b2, x1,
               blockIdx.x - (8 + 2048), threadIdx.x);
  }
}

// L4: radius3 (blocks 0..511) || conv2 (blocks 512..2559)
__global__ void __launch_bounds__(256) l4_kernel(
    const float* __restrict__ pos2, const float* __restrict__ pos3, float r2c,
    int* __restrict__ nbr3, int* __restrict__ cnt3,
    const float* __restrict__ x1, const float* __restrict__ pos1,
    const int* __restrict__ nbr2, const int* __restrict__ cnt2,
    const float* __restrict__ w0, const float* __restrict__ b0,
    const float* __restrict__ w1, const float* __restrict__ b1,
    const float* __restrict__ w2, const float* __restrict__ b2,
    float* __restrict__ x2) {
  __shared__ __attribute__((aligned(16))) char smem[58368];
  if (blockIdx.x < 512) {
    radius_body<256, 64>(smem, pos2, pos3, r2c, nbr3, cnt3, blockIdx.x,
                         threadIdx.x);
  } else {
    conv2_body(smem, x1, pos1, pos2, nbr2, cnt2, w0, b0, w1, b1, w2, b2, x2,
               blockIdx.x - 512, threadIdx.x);
  }
}

// ---------------- stage 3 conv: 259 -> 256 -> 512 -> 512, max over nbrs -----
__global__ void __launch_bounds__(256) conv3_kernel(
    const float* __restrict__ x2, const float* __restrict__ pos2,
    const float* __restrict__ pos3, const int* __restrict__ nbr,
    const int* __restrict__ cntp,
    const float* __restrict__ w0, const float* __restrict__ b0,
    const float* __restrict__ w1, const float* __restrict__ b1,
    const float* __restrict__ w2, const float* __restrict__ b2,
    float* __restrict__ out) {
  __shared__ __attribute__((aligned(16))) float msg[16][260];
  __shared__ __attribute__((aligned(16))) float h[16][512];
  __shared__ float red[4][512];
  __shared__ float omax[512];
  const int blk = blockIdx.x;  // B*64
  const int t = threadIdx.x;
  const int b = blk >> 6;
  const int c = cntp[blk];
  const float cx = pos3[(size_t)blk * 3 + 0];
  const float cy = pos3[(size_t)blk * 3 + 1];
  const float cz = pos3[(size_t)blk * 3 + 2];
  omax[t] = -__builtin_inff();
  omax[t + 256] = -__builtin_inff();
  const int rg = t >> 6;  // 4 row-groups of 4 rows
  const int cg = t & 63;
  __syncthreads();
  for (int ch = 0; ch < 4; ++ch) {
    if (ch * 16 >= c) break;
    for (int idx = t; idx < 16 * 260; idx += 256) {
      int r = idx / 260;
      int k = idx - r * 260;
      int rglob = ch * 16 + r;
      float v = 0.f;
      if (rglob < c && k < 259) {
        int j = nbr[(size_t)blk * KNB + rglob];
        if (k < 256) {
          v = x2[((size_t)(b * 256) + j) * 256 + k];
        } else {
          float pv = pos2[((size_t)(b * 256) + j) * 3 + (k - 256)];
          v = pv - ((k == 256) ? cx : (k == 257) ? cy : cz);
        }
      }
      msg[r][k] = v;
    }
    __syncthreads();
    // L1: 16x256, K=259
    {
      float acc[4][4] = {};
      for (int i4 = 0; i4 < 64; ++i4) {
        float wv[4][4];
#pragma unroll
        for (int k = 0; k < 4; ++k) {
          float4 q = *(const float4*)&w0[(size_t)(i4 * 4 + k) * 256 + cg * 4];
          wv[k][0] = q.x; wv[k][1] = q.y; wv[k][2] = q.z; wv[k][3] = q.w;
        }
#pragma unroll
        for (int rr = 0; rr < 4; ++rr) {
          float4 aq = *(const float4*)&msg[rg * 4 + rr][i4 * 4];
          float a[4] = {aq.x, aq.y, aq.z, aq.w};
#pragma unroll
          for (int k = 0; k < 4; ++k)
#pragma unroll
            for (int cc = 0; cc < 4; ++cc)
              acc[rr][cc] = fmaf(a[k], wv[k][cc], acc[rr][cc]);
        }
      }
#pragma unroll
      for (int i = 256; i < 259; ++i) {
        float wv[4];
#pragma unroll
        for (int cc = 0; cc < 4; ++cc) wv[cc] = w0[(size_t)i * 256 + cg * 4 + cc];
#pragma unroll
        for (int rr = 0; rr < 4; ++rr) {
          float a = msg[rg * 4 + rr][i];
#pragma unroll
          for (int cc = 0; cc < 4; ++cc) acc[rr][cc] = fmaf(a, wv[cc], acc[rr][cc]);
        }
      }
#pragma unroll
      for (int rr = 0; rr < 4; ++rr)
#pragma unroll
        for (int cc = 0; cc < 4; ++cc)
          h[rg * 4 + rr][cg * 4 + cc] = fmaxf(acc[rr][cc] + b0[cg * 4 + cc], 0.f);
    }
    __syncthreads();
    // L2: 16x512, K=256, in-place on h (read cols 0..255, write 0..511)
    {
      float acc[4][8] = {};
      for (int i4 = 0; i4 < 64; ++i4) {
        float wv[4][8];
#pragma unroll
        for (int k = 0; k < 4; ++k) {
          float4 q0 = *(const float4*)&w1[(size_t)(i4 * 4 + k) * 512 + cg * 8];
          float4 q1 = *(const float4*)&w1[(size_t)(i4 * 4 + k) * 512 + cg * 8 + 4];
          wv[k][0] = q0.x; wv[k][1] = q0.y; wv[k][2] = q0.z; wv[k][3] = q0.w;
          wv[k][4] = q1.x; wv[k][5] = q1.y; wv[k][6] = q1.z; wv[k][7] = q1.w;
        }
#pragma unroll
        for (int rr = 0; rr < 4; ++rr) {
          float4 aq = *(const float4*)&h[rg * 4 + rr][i4 * 4];
          float a[4] = {aq.x, aq.y, aq.z, aq.w};
#pragma unroll
          for (int k = 0; k < 4; ++k)
#pragma unroll
            for (int cc = 0; cc < 8; ++cc)
              acc[rr][cc] = fmaf(a[k], wv[k][cc], acc[rr][cc]);
        }
      }
      __syncthreads();
#pragma unroll
      for (int rr = 0; rr < 4; ++rr)
#pragma unroll
        for (int cc = 0; cc < 8; ++cc)
          h[rg * 4 + rr][cg * 8 + cc] = fmaxf(acc[rr][cc] + b1[cg * 8 + cc], 0.f);
    }
    __syncthreads();
    // L3: 16x512, K=512, masked max
    {
      float acc[4][8] = {};
      for (int i4 = 0; i4 < 128; ++i4) {
        float wv[4][8];
#pragma unroll
        for (int k = 0; k < 4; ++k) {
          float4 q0 = *(const float4*)&w2[(size_t)(i4 * 4 + k) * 512 + cg * 8];
          float4 q1 = *(const float4*)&w2[(size_t)(i4 * 4 + k) * 512 + cg * 8 + 4];
          wv[k][0] = q0.x; wv[k][1] = q0.y; wv[k][2] = q0.z; wv[k][3] = q0.w;
          wv[k][4] = q1.x; wv[k][5] = q1.y; wv[k][6] = q1.z; wv[k][7] = q1.w;
        }
#pragma unroll
        for (int rr = 0; rr < 4; ++rr) {
          float4 aq = *(const float4*)&h[rg * 4 + rr][i4 * 4];
          float a[4] = {aq.x, aq.y, aq.z, aq.w};
#pragma unroll
          for (int k = 0; k < 4; ++k)
#pragma unroll
            for (int cc = 0; cc < 8; ++cc)
              acc[rr][cc] = fmaf(a[k], wv[k][cc], acc[rr][cc]);
        }
      }
      float mx[8];
#pragma unroll
      for (int cc = 0; cc < 8; ++cc) mx[cc] = -__builtin_inff();
#pragma unroll
      for (int rr = 0; rr < 4; ++rr) {
        if (ch * 16 + rg * 4 + rr < c) {
#pragma unroll
          for (int cc = 0; cc < 8; ++cc)
            mx[cc] = fmaxf(mx[cc], acc[rr][cc] + b2[cg * 8 + cc]);
        }
      }
#pragma unroll
      for (int cc = 0; cc < 8; ++cc) red[rg][cg * 8 + cc] = mx[cc];
    }
    __syncthreads();
    for (int k = t; k < 512; k += 256) {
      float v = omax[k];
#pragma unroll
      for (int g = 0; g < 4; ++g) v = fmaxf(v, red[g][k]);
      omax[k] = v;
    }
    __syncthreads();
  }
  out[(size_t)blk * 512 + t] = omax[t];
  out[(size_t)blk * 512 + t + 256] = omax[t + 256];
}

extern "C" void kernel_launch(void* const* d_in, const int* in_sizes, int n_in,
                              void* d_out, int out_size, void* d_ws, size_t ws_size,
                              hipStream_t stream) {
  const int* feat = (const int*)d_in[0];
  const float* pos = (const float*)d_in[1];
  const float* emb = (const float*)d_in[2];
  const float* pid = (const float*)d_in[3];
  const float* s1w0 = (const float*)d_in[4];
  const float* s1b0 = (const float*)d_in[5];
  const float* s1w1 = (const float*)d_in[6];
  const float* s1b1 = (const float*)d_in[7];
  const float* s1w2 = (const float*)d_in[8];
  const float* s1b2 = (const float*)d_in[9];
  const float* s2w0 = (const float*)d_in[10];
  const float* s2b0 = (const float*)d_in[11];
  const float* s2w1 = (const float*)d_in[12];
  const float* s2b1 = (const float*)d_in[13];
  const float* s2w2 = (const float*)d_in[14];
  const float* s2b2 = (const float*)d_in[15];
  const float* s3w0 = (const float*)d_in[16];
  const float* s3b0 = (const float*)d_in[17];
  const float* s3w1 = (const float*)d_in[18];
  const float* s3b1 = (const float*)d_in[19];
  const float* s3w2 = (const float*)d_in[20];
  const float* s3b2 = (const float*)d_in[21];
  (void)in_sizes; (void)n_in; (void)out_size; (void)ws_size;

  char* ws = (char*)d_ws;
  size_t off = 0;
  auto alloc = [&](size_t nbytes) {
    void* p = ws + off;
    off = (off + nbytes + 255) & ~(size_t)255;
    return p;
  };
  float* x0 = (float*)alloc((size_t)B * N0 * 32 * 4);
  float* pos1 = (float*)alloc((size_t)B * 1024 * 3 * 4);
  int* nbr1 = (int*)alloc((size_t)B * 1024 * KNB * 4);
  int* cnt1 = (int*)alloc((size_t)B * 1024 * 4);
  float* x1 = (float*)alloc((size_t)B * 1024 * 64 * 4);
  float* pos2 = (float*)alloc((size_t)B * 256 * 3 * 4);
  int* nbr2 = (int*)alloc((size_t)B * 256 * KNB * 4);
  int* cnt2 = (int*)alloc((size_t)B * 256 * 4);
  float* x2 = (float*)alloc((size_t)B * 256 * 256 * 4);
  int* nbr3 = (int*)alloc((size_t)B * 64 * KNB * 4);
  int* cnt3 = (int*)alloc((size_t)B * 64 * 4);

  float* xout = (float*)d_out;                 // (B,64,512)
  float* pos3 = xout + (size_t)B * 64 * 512;   // (B,64,3)

  const float r2a = (float)(0.05 * 0.05);
  const float r2b = (float)(0.3 * 0.3);
  const float r2c = (float)(0.5 * 0.5);

  l1_kernel<<<8 + 4096, 256, 0, stream>>>(pos, pos1, feat, emb, pid, x0);
  l2_kernel<<<8 + 8192, 256, 0, stream>>>(pos1, pos2, pos, r2a, nbr1, cnt1);
  l3_kernel<<<8 + 2048 + 8192, 256, 0, stream>>>(
      pos2, pos3, r2b, nbr2, cnt2, pos1, x0, pos, nbr1, cnt1,
      s1w0, s1b0, s1w1, s1b1, s1w2, s1b2, x1);
  l4_kernel<<<512 + 2048, 256, 0, stream>>>(
      pos2, pos3, r2c, nbr3, cnt3, x1, pos1, nbr2, cnt2,
      s2w0, s2b0, s2w1, s2b1, s2w2, s2b2, x2);
  conv3_kernel<<<B * 64, 256, 0, stream>>>(x2, pos2, pos3, nbr3, cnt3,
                                           s3w0, s3b0, s3w1, s3b1, s3w2, s3b2, xout);
}

// Round 8
// 1460.275 us; speedup vs baseline: 1.0564x; 1.0388x over previous
//
#include <hip/hip_runtime.h>

#define DEVI static __device__ __forceinline__

constexpr int B = 8;
constexpr int N0 = 4096;
constexpr int KNB = 64;

typedef float f32x2 __attribute__((ext_vector_type(2)));
typedef float f32x4 __attribute__((ext_vector_type(4)));
typedef short bf16x8 __attribute__((ext_vector_type(8)));

// d2 exactly as numpy: ((dx*dx + dy*dy) + dz*dz), no FMA contraction.
DEVI float dist2f(float ax, float ay, float az, float bx, float by, float bz) {
#pragma clang fp contract(off)
  float dx = ax - bx;
  float dy = ay - by;
  float dz = az - bz;
  return (dx * dx + dy * dy) + dz * dz;
}
DEVI f32x2 dist2v(f32x2 ax, f32x2 ay, f32x2 az, float bx, float by, float bz) {
#pragma clang fp contract(off)
  f32x2 dx = ax - bx;
  f32x2 dy = ay - by;
  f32x2 dz = az - bz;
  return (dx * dx + dy * dy) + dz * dz;
}

DEVI unsigned long long packMinKey(float v, int i) {
  return ((unsigned long long)__float_as_uint(v) << 32) | (unsigned int)i;
}

template <int CTRL, int RM>
DEVI float dppMaxF32(float v) {
  int o = __builtin_amdgcn_update_dpp(__float_as_int(v), __float_as_int(v),
                                      CTRL, RM, 0xf, false);
  return fmaxf(v, __int_as_float(o));
}
DEVI float waveMaxF32(float v) {
  v = dppMaxF32<0x111, 0xf>(v);
  v = dppMaxF32<0x112, 0xf>(v);
  v = dppMaxF32<0x114, 0xf>(v);
  v = dppMaxF32<0x118, 0xf>(v);
  v = dppMaxF32<0x142, 0xa>(v);
  v = dppMaxF32<0x143, 0xc>(v);
  return __int_as_float(__builtin_amdgcn_readlane(__float_as_int(v), 63));
}
template <int CTRL, int RM>
DEVI unsigned dppMinU32(unsigned v) {
  int o = __builtin_amdgcn_update_dpp((int)v, (int)v, CTRL, RM, 0xf, false);
  unsigned ov = (unsigned)o;
  return v < ov ? v : ov;
}
DEVI unsigned waveMinU32(unsigned v) {
  v = dppMinU32<0x111, 0xf>(v);
  v = dppMinU32<0x112, 0xf>(v);
  v = dppMinU32<0x114, 0xf>(v);
  v = dppMinU32<0x118, 0xf>(v);
  v = dppMinU32<0x142, 0xa>(v);
  v = dppMinU32<0x143, 0xc>(v);
  return (unsigned)__builtin_amdgcn_readlane((int)v, 63);
}

// ---- bf16 split helpers (RNE) ----
DEVI unsigned short bfhi(float x) {
  unsigned u = __float_as_uint(x);
  return (unsigned short)((u + 0x7FFFu + ((u >> 16) & 1u)) >> 16);
}
DEVI float bf2f(unsigned short h) { return __uint_as_float(((unsigned)h) << 16); }
DEVI void mkfrag(const float* p, bf16x8& hi, bf16x8& lo) {
#pragma unroll
  for (int e = 0; e < 8; ++e) {
    float x = p[e];
    unsigned short h = bfhi(x);
    float r = x - bf2f(h);
    unsigned short l2 = bfhi(r);
    hi[e] = (short)h;
    lo[e] = (short)l2;
  }
}

// ================= device bodies ======

DEVI void x0_body(const int* __restrict__ feat, const float* __restrict__ emb,
                  const float* __restrict__ pid, float* __restrict__ x0buf,
                  int bx, int t) {
  int gid = bx * 256 + t;
  if (gid >= B * N0 * 32) return;
  int c = gid & 31;
  int bn = gid >> 5;
  int n = bn & (N0 - 1);
  int f = feat[bn];
  float v = emb[f * 32 + c];
  if (n < 1024) v += pid[n * 32 + c];
  x0buf[gid] = v;
}

// ---- farthest point sampling (selection semantics == jnp.argmax) ----
template <int NPTS, int M, int BLK>
DEVI void fps_body(char* smem, const float* __restrict__ pos,
                   float* __restrict__ pos_out, int b, int t) {
  constexpr int EPT = NPTS / BLK;
  constexpr int EP2 = EPT / 2;
  constexpr int NW = BLK / 64;
  float4* posl = (float4*)smem;
  float4* outp = (float4*)(smem + (size_t)NPTS * 16);
  unsigned long long* redk =
      (unsigned long long*)(smem + (size_t)(NPTS + M) * 16);  // [2][NW]
  const float* pb = pos + (size_t)b * NPTS * 3;
  f32x2 px[EP2], py[EP2], pz[EP2], d[EP2];
#pragma unroll
  for (int e = 0; e < EP2; ++e) {
    int i0 = t + (2 * e) * BLK;
    int i1 = t + (2 * e + 1) * BLK;
    float x0 = pb[i0 * 3 + 0], y0 = pb[i0 * 3 + 1], z0 = pb[i0 * 3 + 2];
    float x1 = pb[i1 * 3 + 0], y1 = pb[i1 * 3 + 1], z1 = pb[i1 * 3 + 2];
    px[e] = (f32x2){x0, x1};
    py[e] = (f32x2){y0, y1};
    pz[e] = (f32x2){z0, z1};
    posl[i0] = make_float4(x0, y0, z0, 0.f);
    posl[i1] = make_float4(x1, y1, z1, 0.f);
  }
  float sx = pb[0], sy = pb[1], sz = pb[2];
  if (t == 0) outp[0] = make_float4(sx, sy, sz, 0.f);
  f32x2 m2 = (f32x2){-1.f, -1.f};
#pragma unroll
  for (int e = 0; e < EP2; ++e) {
    d[e] = dist2v(px[e], py[e], pz[e], sx, sy, sz);
    m2.x = fmaxf(m2.x, d[e].x);
    m2.y = fmaxf(m2.y, d[e].y);
  }
  for (int it = 1; it < M; ++it) {
    const float vstar = waveMaxF32(fmaxf(m2.x, m2.y));
    unsigned cand = 0xffffffffu;
#pragma unroll
    for (int e = 0; e < EP2; ++e) {
      unsigned c0 = (d[e].x == vstar) ? (unsigned)(t + (2 * e) * BLK) : 0xffffffffu;
      unsigned c1 = (d[e].y == vstar) ? (unsigned)(t + (2 * e + 1) * BLK) : 0xffffffffu;
      cand = cand < c0 ? cand : c0;
      cand = cand < c1 ? cand : c1;
    }
    cand = waveMinU32(cand);
    unsigned sel;
    if constexpr (NW > 1) {
      if ((t & 63) == 0) {
        unsigned long long key =
            ((unsigned long long)__float_as_uint(vstar) << 32) |
            (unsigned)(0x7fffffffu - cand);
        redk[(it & 1) * NW + (t >> 6)] = key;
      }
      __syncthreads();
      unsigned long long kk = redk[(it & 1) * NW + 0];
#pragma unroll
      for (int w = 1; w < NW; ++w) {
        unsigned long long o = redk[(it & 1) * NW + w];
        kk = (kk > o) ? kk : o;
      }
      sel = 0x7fffffffu - (unsigned)(kk & 0xffffffffULL);
    } else {
      sel = cand;
    }
    float4 sp = posl[sel];
    if (t == 0) outp[it] = sp;
    m2 = (f32x2){-1.f, -1.f};
#pragma unroll
    for (int e = 0; e < EP2; ++e) {
      f32x2 nd = dist2v(px[e], py[e], pz[e], sp.x, sp.y, sp.z);
      d[e].x = fminf(d[e].x, nd.x);
      d[e].y = fminf(d[e].y, nd.y);
      m2.x = fmaxf(m2.x, d[e].x);
      m2.y = fmaxf(m2.y, d[e].y);
    }
  }
  if constexpr (NW > 1) __syncthreads();
  for (int m = t; m < M; m += BLK) {
    float4 q = outp[m];
    pos_out[(size_t)(b * M + m) * 3 + 0] = q.x;
    pos_out[(size_t)(b * M + m) * 3 + 1] = q.y;
    pos_out[(size_t)(b * M + m) * 3 + 2] = q.z;
  }
}

// ---- radius neighbors (<=64 nearest within r), rank-select overflow ----
template <int NPTS, int M>
DEVI void radius_body(char* smem, const float* __restrict__ pos,
                      const float* __restrict__ pos_s, float r2,
                      int* __restrict__ nbr, int* __restrict__ cnt, int blk,
                      int t) {
  unsigned long long* candkey = (unsigned long long*)smem;
  int* ctrp = (int*)(smem + (size_t)NPTS * 8);
  const int b = blk / M;
  const float* pb = pos + (size_t)b * NPTS * 3;
  const float cx = pos_s[(size_t)blk * 3 + 0];
  const float cy = pos_s[(size_t)blk * 3 + 1];
  const float cz = pos_s[(size_t)blk * 3 + 2];
  if (t == 0) *ctrp = 0;
  __syncthreads();
  for (int j = t; j < NPTS; j += 256) {
    float d2 = dist2f(pb[j * 3 + 0], pb[j * 3 + 1], pb[j * 3 + 2], cx, cy, cz);
    if (d2 <= r2) {
      int p = atomicAdd(ctrp, 1);
      candkey[p] = packMinKey(d2, j);
      if (p < KNB) nbr[(size_t)blk * KNB + p] = j;
    }
  }
  __syncthreads();
  const int c = *ctrp;
  if (c <= KNB) {
    if (t == 0) cnt[blk] = c;
    return;
  }
  for (int s = t; s < c; s += 256) {
    unsigned long long mykey = candkey[s];
    int rank = 0;
#pragma unroll 4
    for (int j = 0; j < c; ++j) {
      rank += (candkey[j] < mykey) ? 1 : 0;
    }
    if (rank < KNB)
      nbr[(size_t)blk * KNB + rank] = (int)(unsigned)(mykey & 0xffffffffULL);
  }
  if (t == 0) cnt[blk] = KNB;
}

// ---- stage 1 conv: 35 -> 64 -> 64 -> 64, max over nbrs (4 slots x 64ch) ----
DEVI void conv1_body(char* smem, const float* __restrict__ x0buf,
                     const float* __restrict__ pos,
                     const float* __restrict__ pos_s,
                     const int* __restrict__ nbr, const int* __restrict__ cntp,
                     const float* __restrict__ w0, const float* __restrict__ b0,
                     const float* __restrict__ w1, const float* __restrict__ b1,
                     const float* __restrict__ w2, const float* __restrict__ b2,
                     float* __restrict__ x1, int blk, int t) {
  float(*ins)[36] = (float(*)[36])smem;
  float(*hh)[65] = (float(*)[65])(smem + 576);
  float(*sred)[65] = (float(*)[65])(smem + 1616);
  const int slot = t >> 6;
  const int ch = t & 63;
  const int b = blk >> 10;
  const int c = cntp[blk];
  const float cx = pos_s[(size_t)blk * 3 + 0];
  const float cy = pos_s[(size_t)blk * 3 + 1];
  const float cz = pos_s[(size_t)blk * 3 + 2];
  float best = -__builtin_inff();
  for (int r0 = 0; r0 < c; r0 += 4) {
    const int r = r0 + slot;
    const bool act = r < c;
    const int j = nbr[(size_t)blk * KNB + (act ? r : 0)];
    if (ch < 32) {
      ins[slot][ch] = x0buf[((size_t)(b * N0) + j) * 32 + ch];
    } else if (ch < 35) {
      float pv = pos[((size_t)(b * N0) + j) * 3 + (ch - 32)];
      float cv = (ch == 32) ? cx : (ch == 33) ? cy : cz;
      ins[slot][ch] = pv - cv;
    }
    __syncthreads();
    float v = b0[ch];
#pragma unroll
    for (int i = 0; i < 35; ++i) v = fmaf(ins[slot][i], w0[i * 64 + ch], v);
    v = fmaxf(v, 0.f);
    hh[slot][ch] = v;
    __syncthreads();
    float v2 = b1[ch];
#pragma unroll
    for (int i = 0; i < 64; ++i) v2 = fmaf(hh[slot][i], w1[i * 64 + ch], v2);
    v2 = fmaxf(v2, 0.f);
    __syncthreads();
    hh[slot][ch] = v2;
    __syncthreads();
    float v3 = b2[ch];
#pragma unroll
    for (int i = 0; i < 64; ++i) v3 = fmaf(hh[slot][i], w2[i * 64 + ch], v3);
    if (act) best = fmaxf(best, v3);
    __syncthreads();
  }
  sred[slot][ch] = best;
  __syncthreads();
  if (t < 64) {
    float v = sred[0][t];
#pragma unroll
    for (int s = 1; s < 4; ++s) v = fmaxf(v, sred[s][t]);
    x1[(size_t)blk * 64 + t] = v;
  }
}

// ---- stage 2 conv: 67 -> 128 -> 128 -> 256 (fp32 register GEMM) ----
DEVI void conv2_body(char* smem, const float* __restrict__ x1,
                     const float* __restrict__ pos1,
                     const float* __restrict__ pos2,
                     const int* __restrict__ nbr, const int* __restrict__ cntp,
                     const float* __restrict__ w0, const float* __restrict__ b0,
                     const float* __restrict__ w1, const float* __restrict__ b1,
                     const float* __restrict__ w2, const float* __restrict__ b2,
                     float* __restrict__ x2, int blk, int t) {
  float(*msg)[68] = (float(*)[68])smem;
  float(*h)[128] = (float(*)[128])(smem + 17408);
  float(*red)[256] = (float(*)[256])(smem + 17408 + 32768);
  const int b = blk >> 8;
  const int c = cntp[blk];
  const float cx = pos2[(size_t)blk * 3 + 0];
  const float cy = pos2[(size_t)blk * 3 + 1];
  const float cz = pos2[(size_t)blk * 3 + 2];
  for (int idx = t; idx < 64 * 68; idx += 256) {
    int r = idx / 68;
    int k = idx - r * 68;
    float v = 0.f;
    if (r < c && k < 67) {
      int j = nbr[(size_t)blk * KNB + r];
      if (k < 64) {
        v = x1[((size_t)(b * 1024) + j) * 64 + k];
      } else {
        float pv = pos1[((size_t)(b * 1024) + j) * 3 + (k - 64)];
        v = pv - ((k == 64) ? cx : (k == 65) ? cy : cz);
      }
    }
    msg[r][k] = v;
  }
  __syncthreads();
  const int rg = t >> 5;
  const int cg = t & 31;
  {
    float acc[8][4] = {};
    for (int i4 = 0; i4 < 16; ++i4) {
      float wv[4][4];
#pragma unroll
      for (int k = 0; k < 4; ++k) {
        float4 q = *(const float4*)&w0[(size_t)(i4 * 4 + k) * 128 + cg * 4];
        wv[k][0] = q.x; wv[k][1] = q.y; wv[k][2] = q.z; wv[k][3] = q.w;
      }
#pragma unroll
      for (int rr = 0; rr < 8; ++rr) {
        float4 aq = *(const float4*)&msg[rg * 8 + rr][i4 * 4];
        float a[4] = {aq.x, aq.y, aq.z, aq.w};
#pragma unroll
        for (int k = 0; k < 4; ++k)
#pragma unroll
          for (int cc = 0; cc < 4; ++cc)
            acc[rr][cc] = fmaf(a[k], wv[k][cc], acc[rr][cc]);
      }
    }
#pragma unroll
    for (int i = 64; i < 67; ++i) {
      float wv[4];
#pragma unroll
      for (int cc = 0; cc < 4; ++cc) wv[cc] = w0[(size_t)i * 128 + cg * 4 + cc];
#pragma unroll
      for (int rr = 0; rr < 8; ++rr) {
        float a = msg[rg * 8 + rr][i];
#pragma unroll
        for (int cc = 0; cc < 4; ++cc) acc[rr][cc] = fmaf(a, wv[cc], acc[rr][cc]);
      }
    }
#pragma unroll
    for (int rr = 0; rr < 8; ++rr)
#pragma unroll
      for (int cc = 0; cc < 4; ++cc)
        h[rg * 8 + rr][cg * 4 + cc] = fmaxf(acc[rr][cc] + b0[cg * 4 + cc], 0.f);
  }
  __syncthreads();
  {
    float acc[8][4] = {};
    for (int i4 = 0; i4 < 32; ++i4) {
      float wv[4][4];
#pragma unroll
      for (int k = 0; k < 4; ++k) {
        float4 q = *(const float4*)&w1[(size_t)(i4 * 4 + k) * 128 + cg * 4];
        wv[k][0] = q.x; wv[k][1] = q.y; wv[k][2] = q.z; wv[k][3] = q.w;
      }
#pragma unroll
      for (int rr = 0; rr < 8; ++rr) {
        float4 aq = *(const float4*)&h[rg * 8 + rr][i4 * 4];
        float a[4] = {aq.x, aq.y, aq.z, aq.w};
#pragma unroll
        for (int k = 0; k < 4; ++k)
#pragma unroll
          for (int cc = 0; cc < 4; ++cc)
            acc[rr][cc] = fmaf(a[k], wv[k][cc], acc[rr][cc]);
      }
    }
    __syncthreads();
#pragma unroll
    for (int rr = 0; rr < 8; ++rr)
#pragma unroll
      for (int cc = 0; cc < 4; ++cc)
        h[rg * 8 + rr][cg * 4 + cc] = fmaxf(acc[rr][cc] + b1[cg * 4 + cc], 0.f);
  }
  __syncthreads();
  {
    float acc[8][8] = {};
    for (int i4 = 0; i4 < 32; ++i4) {
      float wv[4][8];
#pragma unroll
      for (int k = 0; k < 4; ++k) {
        float4 q0 = *(const float4*)&w2[(size_t)(i4 * 4 + k) * 256 + cg * 8];
        float4 q1 = *(const float4*)&w2[(size_t)(i4 * 4 + k) * 256 + cg * 8 + 4];
        wv[k][0] = q0.x; wv[k][1] = q0.y; wv[k][2] = q0.z; wv[k][3] = q0.w;
        wv[k][4] = q1.x; wv[k][5] = q1.y; wv[k][6] = q1.z; wv[k][7] = q1.w;
      }
#pragma unroll
      for (int rr = 0; rr < 8; ++rr) {
        float4 aq = *(const float4*)&h[rg * 8 + rr][i4 * 4];
        float a[4] = {aq.x, aq.y, aq.z, aq.w};
#pragma unroll
        for (int k = 0; k < 4; ++k)
#pragma unroll
          for (int cc = 0; cc < 8; ++cc)
            acc[rr][cc] = fmaf(a[k], wv[k][cc], acc[rr][cc]);
      }
    }
    float mx[8];
#pragma unroll
    for (int cc = 0; cc < 8; ++cc) mx[cc] = -__builtin_inff();
#pragma unroll
    for (int rr = 0; rr < 8; ++rr) {
      if (rg * 8 + rr < c) {
#pragma unroll
        for (int cc = 0; cc < 8; ++cc)
          mx[cc] = fmaxf(mx[cc], acc[rr][cc] + b2[cg * 8 + cc]);
      }
    }
#pragma unroll
    for (int cc = 0; cc < 8; ++cc) red[rg][cg * 8 + cc] = mx[cc];
  }
  __syncthreads();
  {
    float v = red[0][t];
#pragma unroll
    for (int g = 1; g < 8; ++g) v = fmaxf(v, red[g][t]);
    x2[(size_t)blk * 256 + t] = v;
  }
}

// ================= merged launch kernels ====================================

__global__ void __launch_bounds__(256) l1_kernel(
    const float* __restrict__ pos, float* __restrict__ pos1,
    const int* __restrict__ feat, const float* __restrict__ emb,
    const float* __restrict__ pid, float* __restrict__ x0buf) {
  __shared__ __attribute__((aligned(16))) char smem[81984];
  if (blockIdx.x < 8) {
    fps_body<4096, 1024, 256>(smem, pos, pos1, blockIdx.x, threadIdx.x);
  } else {
    x0_body(feat, emb, pid, x0buf, blockIdx.x - 8, threadIdx.x);
  }
}

__global__ void __launch_bounds__(256) l2_kernel(
    const float* __restrict__ pos1, float* __restrict__ pos2,
    const float* __restrict__ pos, float r2a, int* __restrict__ nbr1,
    int* __restrict__ cnt1) {
  __shared__ __attribute__((aligned(16))) char smem[33024];
  if (blockIdx.x < 8) {
    fps_body<1024, 256, 256>(smem, pos1, pos2, blockIdx.x, threadIdx.x);
  } else {
    radius_body<4096, 1024>(smem, pos, pos1, r2a, nbr1, cnt1, blockIdx.x - 8,
                            threadIdx.x);
  }
}

__global__ void __launch_bounds__(256) l3_kernel(
    const float* __restrict__ pos2, float* __restrict__ pos3, float r2b,
    int* __restrict__ nbr2, int* __restrict__ cnt2,
    const float* __restrict__ pos1, const float* __restrict__ x0buf,
    const float* __restrict__ pos, const int* __restrict__ nbr1,
    const int* __restrict__ cnt1, const float* __restrict__ w0,
    const float* __restrict__ b0, const float* __restrict__ w1,
    const float* __restrict__ b1, const float* __restrict__ w2,
    const float* __restrict__ b2, float* __restrict__ x1) {
  __shared__ __attribute__((aligned(16))) char smem[8448];
  if (blockIdx.x < 8) {
    if (threadIdx.x < 64)
      fps_body<256, 64, 64>(smem, pos2, pos3, blockIdx.x, threadIdx.x);
  } else if (blockIdx.x < 8 + 2048) {
    radius_body<1024, 256>(smem, pos1, pos2, r2b, nbr2, cnt2, blockIdx.x - 8,
                           threadIdx.x);
  } else {
    conv1_body(smem, x0buf, pos, pos1, nbr1, cnt1, w0, b0, w1, b1, w2, b2, x1,
               blockIdx.x - (8 + 2048), threadIdx.x);
  }
}

__global__ void __launch_bounds__(256) l4_kernel(
    const float* __restrict__ pos2, const float* __restrict__ pos3, float r2c,
    int* __restrict__ nbr3, int* __restrict__ cnt3,
    const float* __restrict__ x1, const float* __restrict__ pos1,
    const int* __restrict__ nbr2, const int* __restrict__ cnt2,
    const float* __restrict__ w0, const float* __restrict__ b0,
    const float* __restrict__ w1, const float* __restrict__ b1,
    const float* __restrict__ w2, const float* __restrict__ b2,
    float* __restrict__ x2) {
  __shared__ __attribute__((aligned(16))) char smem[58368];
  if (blockIdx.x < 512) {
    radius_body<256, 64>(smem, pos2, pos3, r2c, nbr3, cnt3, blockIdx.x,
                         threadIdx.x);
  } else {
    conv2_body(smem, x1, pos1, pos2, nbr2, cnt2, w0, b0, w1, b1, w2, b2, x2,
               blockIdx.x - 512, threadIdx.x);
  }
}

// ---------------- weight packing into MFMA-B fragment order -----------------
// B-fragment for mfma_f32_16x16x32_bf16: lane l holds col n = l&15,
// k = (l>>4)*8 + e (e=0..7). Packed order: elem = ((nt*KS + ks)*64 + l)*8 + e
// where n = nt*16 + (l&15), k = ks*32 + (l>>4)*8 + e; k >= Kreal -> 0.
__global__ void __launch_bounds__(256) pack_kernel(
    const float* __restrict__ W, int Kreal, int KS, int N,
    unsigned short* __restrict__ hi, unsigned short* __restrict__ lo) {
  int gid = blockIdx.x * 256 + threadIdx.x;
  int total = (N / 16) * KS * 64 * 8;
  if (gid >= total) return;
  int e = gid & 7;
  int l = (gid >> 3) & 63;
  int rest = gid >> 9;
  int ks = rest % KS;
  int nt = rest / KS;
  int n = nt * 16 + (l & 15);
  int k = ks * 32 + (l >> 4) * 8 + e;
  float val = (k < Kreal) ? W[(size_t)k * N + n] : 0.f;
  unsigned short h = bfhi(val);
  float r = val - bf2f(h);
  hi[gid] = h;
  lo[gid] = bfhi(r);
}

// ---------------- stage 3 conv via split-bf16 MFMA --------------------------
// One block per center (512 blocks), 256 thr = 4 waves; wave w owns rows
// [16w,16w+16). D = A*B via 3 MFMAs (hh, lh, hl); rel err ~1e-5.
// A-frag: m = lane&15, k = (lane>>4)*8+e. C/D: n = lane&15, m=(lane>>4)*4+r.
__global__ void __launch_bounds__(256) conv3_mfma(
    const float* __restrict__ x2, const float* __restrict__ pos2,
    const float* __restrict__ pos3, const int* __restrict__ nbr,
    const int* __restrict__ cntp,
    const unsigned short* __restrict__ w0h, const unsigned short* __restrict__ w0l,
    const float* __restrict__ b0,
    const unsigned short* __restrict__ w1h, const unsigned short* __restrict__ w1l,
    const float* __restrict__ b1,
    const unsigned short* __restrict__ w2h, const unsigned short* __restrict__ w2l,
    const float* __restrict__ b2, float* __restrict__ out) {
  __shared__ __attribute__((aligned(16))) float h1s[64 * 268];   // K2=256 (+12 pad)
  __shared__ __attribute__((aligned(16))) float h2cs[64 * 140];  // 128-col chunk
  __shared__ __attribute__((aligned(16))) float msgcs[64 * 44];  // 32-k slice
  const int blk = blockIdx.x;
  const int t = threadIdx.x;
  const int b = blk >> 6;
  const int c = cntp[blk];
  const int w = t >> 6;
  const int lane = t & 63;
  const int cb = lane & 15;   // col-in-tile for B/C/D
  const int kb = lane >> 4;   // k-block for A/B, row-group for C/D
  const float cx = pos3[(size_t)blk * 3 + 0];
  const float cy = pos3[(size_t)blk * 3 + 1];
  const float cz = pos3[(size_t)blk * 3 + 2];
  const int mrow = w * 16 + cb;  // A-fragment row for this lane

  // ---------- L1: K=259 (pad 288), N=256 ----------
  f32x4 acc1[16];
#pragma unroll
  for (int nt = 0; nt < 16; ++nt) acc1[nt] = (f32x4){0.f, 0.f, 0.f, 0.f};
  for (int ks = 0; ks < 9; ++ks) {
    // gather 32-k slice of msg into LDS
#pragma unroll
    for (int i = 0; i < 8; ++i) {
      int idx = t + i * 256;
      int row = idx >> 5;
      int col = idx & 31;
      int kg = ks * 32 + col;
      int j = nbr[(size_t)blk * KNB + (row < c ? row : c - 1)];
      float v = 0.f;
      if (kg < 256) {
        v = x2[((size_t)(b * 256) + j) * 256 + kg];
      } else if (kg < 259) {
        float pv = pos2[((size_t)(b * 256) + j) * 3 + (kg - 256)];
        v = pv - ((kg == 256) ? cx : (kg == 257) ? cy : cz);
      }
      msgcs[row * 44 + col] = v;
    }
    __syncthreads();
    bf16x8 ahi, alo;
    mkfrag(&msgcs[mrow * 44 + kb * 8], ahi, alo);
#pragma unroll
    for (int nt = 0; nt < 16; ++nt) {
      size_t off = ((size_t)(nt * 9 + ks) * 64 + lane) * 8;
      bf16x8 bhi = *(const bf16x8*)(w0h + off);
      bf16x8 blo = *(const bf16x8*)(w0l + off);
      acc1[nt] = __builtin_amdgcn_mfma_f32_16x16x32_bf16(ahi, bhi, acc1[nt], 0, 0, 0);
      acc1[nt] = __builtin_amdgcn_mfma_f32_16x16x32_bf16(alo, bhi, acc1[nt], 0, 0, 0);
      acc1[nt] = __builtin_amdgcn_mfma_f32_16x16x32_bf16(ahi, blo, acc1[nt], 0, 0, 0);
    }
    __syncthreads();
  }
  // write h1 = ReLU(acc1 + b0); C/D: row m = w*16 + kb*4 + r, col = nt*16+cb
  {
    const int mw = w * 16 + kb * 4;
#pragma unroll
    for (int nt = 0; nt < 16; ++nt) {
      float bias = b0[nt * 16 + cb];
#pragma unroll
      for (int r = 0; r < 4; ++r)
        h1s[(mw + r) * 268 + nt * 16 + cb] = fmaxf(acc1[nt][r] + bias, 0.f);
    }
  }
  __syncthreads();

  // ---------- L2 (K=256, N=512 in 4 chunks) + L3 (K=512 streamed) ----------
  f32x4 acc3[32];
#pragma unroll
  for (int nt = 0; nt < 32; ++nt) acc3[nt] = (f32x4){0.f, 0.f, 0.f, 0.f};
  for (int ch = 0; ch < 4; ++ch) {
    f32x4 acc2[8];
#pragma unroll
    for (int nt = 0; nt < 8; ++nt) acc2[nt] = (f32x4){0.f, 0.f, 0.f, 0.f};
#pragma unroll
    for (int ks = 0; ks < 8; ++ks) {
      bf16x8 ahi, alo;
      mkfrag(&h1s[mrow * 268 + ks * 32 + kb * 8], ahi, alo);
#pragma unroll
      for (int nt = 0; nt < 8; ++nt) {
        size_t off = ((size_t)((ch * 8 + nt) * 8 + ks) * 64 + lane) * 8;
        bf16x8 bhi = *(const bf16x8*)(w1h + off);
        bf16x8 blo = *(const bf16x8*)(w1l + off);
        acc2[nt] = __builtin_amdgcn_mfma_f32_16x16x32_bf16(ahi, bhi, acc2[nt], 0, 0, 0);
        acc2[nt] = __builtin_amdgcn_mfma_f32_16x16x32_bf16(alo, bhi, acc2[nt], 0, 0, 0);
        acc2[nt] = __builtin_amdgcn_mfma_f32_16x16x32_bf16(ahi, blo, acc2[nt], 0, 0, 0);
      }
    }
    // write h2 chunk = ReLU(acc2 + b1)
    {
      const int mw = w * 16 + kb * 4;
#pragma unroll
      for (int nt = 0; nt < 8; ++nt) {
        float bias = b1[ch * 128 + nt * 16 + cb];
#pragma unroll
        for (int r = 0; r < 4; ++r)
          h2cs[(mw + r) * 140 + nt * 16 + cb] = fmaxf(acc2[nt][r] + bias, 0.f);
      }
    }
    __syncthreads();
    // L3 partial over this chunk's 128 k
#pragma unroll
    for (int ks3 = 0; ks3 < 4; ++ks3) {
      bf16x8 ahi, alo;
      mkfrag(&h2cs[mrow * 140 + ks3 * 32 + kb * 8], ahi, alo);
#pragma unroll
      for (int nt = 0; nt < 32; ++nt) {
        size_t off = ((size_t)(nt * 16 + ch * 4 + ks3) * 64 + lane) * 8;
        bf16x8 bhi = *(const bf16x8*)(w2h + off);
        bf16x8 blo = *(const bf16x8*)(w2l + off);
        acc3[nt] = __builtin_amdgcn_mfma_f32_16x16x32_bf16(ahi, bhi, acc3[nt], 0, 0, 0);
        acc3[nt] = __builtin_amdgcn_mfma_f32_16x16x32_bf16(alo, bhi, acc3[nt], 0, 0, 0);
        acc3[nt] = __builtin_amdgcn_mfma_f32_16x16x32_bf16(ahi, blo, acc3[nt], 0, 0, 0);
      }
    }
    __syncthreads();  // h2cs reused next chunk
  }

  // ---------- bias + masked row-max ----------
  float* redw = h1s;  // alias: h1 dead; need 16*512 floats
  {
    const int mw = w * 16 + kb * 4;
#pragma unroll
    for (int nt = 0; nt < 32; ++nt) {
      float bias = b2[nt * 16 + cb];
      float mx = -__builtin_inff();
#pragma unroll
      for (int r = 0; r < 4; ++r) {
        if (mw + r < c) mx = fmaxf(mx, acc3[nt][r] + bias);
      }
      redw[(w * 4 + kb) * 512 + nt * 16 + cb] = mx;
    }
  }
  __syncthreads();
#pragma unroll
  for (int half = 0; half < 2; ++half) {
    int col = t + half * 256;
    float v = redw[col];
#pragma unroll
    for (int g = 1; g < 16; ++g) v = fmaxf(v, redw[g * 512 + col]);
    out[(size_t)blk * 512 + col] = v;
  }
}

extern "C" void kernel_launch(void* const* d_in, const int* in_sizes, int n_in,
                              void* d_out, int out_size, void* d_ws, size_t ws_size,
                              hipStream_t stream) {
  const int* feat = (const int*)d_in[0];
  const float* pos = (const float*)d_in[1];
  const float* emb = (const float*)d_in[2];
  const float* pid = (const float*)d_in[3];
  const float* s1w0 = (const float*)d_in[4];
  const float* s1b0 = (const float*)d_in[5];
  const float* s1w1 = (const float*)d_in[6];
  const float* s1b1 = (const float*)d_in[7];
  const float* s1w2 = (const float*)d_in[8];
  const float* s1b2 = (const float*)d_in[9];
  const float* s2w0 = (const float*)d_in[10];
  const float* s2b0 = (const float*)d_in[11];
  const float* s2w1 = (const float*)d_in[12];
  const float* s2b1 = (const float*)d_in[13];
  const float* s2w2 = (const float*)d_in[14];
  const float* s2b2 = (const float*)d_in[15];
  const float* s3w0 = (const float*)d_in[16];
  const float* s3b0 = (const float*)d_in[17];
  const float* s3w1 = (const float*)d_in[18];
  const float* s3b1 = (const float*)d_in[19];
  const float* s3w2 = (const float*)d_in[20];
  const float* s3b2 = (const float*)d_in[21];
  (void)in_sizes; (void)n_in; (void)out_size; (void)ws_size;

  char* ws = (char*)d_ws;
  size_t off = 0;
  auto alloc = [&](size_t nbytes) {
    void* p = ws + off;
    off = (off + nbytes + 255) & ~(size_t)255;
    return p;
  };
  float* x0 = (float*)alloc((size_t)B * N0 * 32 * 4);
  float* pos1 = (float*)alloc((size_t)B * 1024 * 3 * 4);
  int* nbr1 = (int*)alloc((size_t)B * 1024 * KNB * 4);
  int* cnt1 = (int*)alloc((size_t)B * 1024 * 4);
  float* x1 = (float*)alloc((size_t)B * 1024 * 64 * 4);
  float* pos2 = (float*)alloc((size_t)B * 256 * 3 * 4);
  int* nbr2 = (int*)alloc((size_t)B * 256 * KNB * 4);
  int* cnt2 = (int*)alloc((size_t)B * 256 * 4);
  float* x2 = (float*)alloc((size_t)B * 256 * 256 * 4);
  int* nbr3 = (int*)alloc((size_t)B * 64 * KNB * 4);
  int* cnt3 = (int*)alloc((size_t)B * 64 * 4);
  // packed split-bf16 weights for conv3 MFMA
  const int T0 = 16 * 9 * 64 * 8;    // L1: N=256 (16 nt), KS=9
  const int T1 = 32 * 8 * 64 * 8;    // L2: N=512, KS=8
  const int T2 = 32 * 16 * 64 * 8;   // L3: N=512, KS=16
  unsigned short* w0h = (unsigned short*)alloc((size_t)T0 * 2);
  unsigned short* w0l = (unsigned short*)alloc((size_t)T0 * 2);
  unsigned short* w1h = (unsigned short*)alloc((size_t)T1 * 2);
  unsigned short* w1l = (unsigned short*)alloc((size_t)T1 * 2);
  unsigned short* w2h = (unsigned short*)alloc((size_t)T2 * 2);
  unsigned short* w2l = (unsigned short*)alloc((size_t)T2 * 2);

  float* xout = (float*)d_out;                 // (B,64,512)
  float* pos3 = xout + (size_t)B * 64 * 512;   // (B,64,3)

  const float r2a = (float)(0.05 * 0.05);
  const float r2b = (float)(0.3 * 0.3);
  const float r2c = (float)(0.5 * 0.5);

  pack_kernel<<<(T0 + 255) / 256, 256, 0, stream>>>(s3w0, 259, 9, 256, w0h, w0l);
  pack_kernel<<<(T1 + 255) / 256, 256, 0, stream>>>(s3w1, 256, 8, 512, w1h, w1l);
  pack_kernel<<<(T2 + 255) / 256, 256, 0, stream>>>(s3w2, 512, 16, 512, w2h, w2l);

  l1_kernel<<<8 + 4096, 256, 0, stream>>>(pos, pos1, feat, emb, pid, x0);
  l2_kernel<<<8 + 8192, 256, 0, stream>>>(pos1, pos2, pos, r2a, nbr1, cnt1);
  l3_kernel<<<8 + 2048 + 8192, 256, 0, stream>>>(
      pos2, pos3, r2b, nbr2, cnt2, pos1, x0, pos, nbr1, cnt1,
      s1w0, s1b0, s1w1, s1b1, s1w2, s1b2, x1);
  l4_kernel<<<512 + 2048, 256, 0, stream>>>(
      pos2, pos3, r2c, nbr3, cnt3, x1, pos1, nbr2, cnt2,
      s2w0, s2b0, s2w1, s2b1, s2w2, s2b2, x2);
  conv3_mfma<<<B * 64, 256, 0, stream>>>(x2, pos2, pos3, nbr3, cnt3,
                                         w0h, w0l, s3b0, w1h, w1l, s3b1,
                                         w2h, w2l, s3b2, xout);
}

// Round 9
// 1327.296 us; speedup vs baseline: 1.1622x; 1.1002x over previous
//
#include <hip/hip_runtime.h>

#define DEVI static __device__ __forceinline__

constexpr int B = 8;
constexpr int N0 = 4096;
constexpr int KNB = 64;

typedef float f32x2 __attribute__((ext_vector_type(2)));
typedef float f32x4 __attribute__((ext_vector_type(4)));
typedef short bf16x8 __attribute__((ext_vector_type(8)));

// d2 exactly as numpy: ((dx*dx + dy*dy) + dz*dz), no FMA contraction.
DEVI float dist2f(float ax, float ay, float az, float bx, float by, float bz) {
#pragma clang fp contract(off)
  float dx = ax - bx;
  float dy = ay - by;
  float dz = az - bz;
  return (dx * dx + dy * dy) + dz * dz;
}
DEVI f32x2 dist2v(f32x2 ax, f32x2 ay, f32x2 az, float bx, float by, float bz) {
#pragma clang fp contract(off)
  f32x2 dx = ax - bx;
  f32x2 dy = ay - by;
  f32x2 dz = az - bz;
  return (dx * dx + dy * dy) + dz * dz;
}

DEVI unsigned long long packMinKey(float v, int i) {
  return ((unsigned long long)__float_as_uint(v) << 32) | (unsigned int)i;
}

template <int CTRL, int RM>
DEVI float dppMaxF32(float v) {
  int o = __builtin_amdgcn_update_dpp(__float_as_int(v), __float_as_int(v),
                                      CTRL, RM, 0xf, false);
  return fmaxf(v, __int_as_float(o));
}
DEVI float waveMaxF32(float v) {
  v = dppMaxF32<0x111, 0xf>(v);
  v = dppMaxF32<0x112, 0xf>(v);
  v = dppMaxF32<0x114, 0xf>(v);
  v = dppMaxF32<0x118, 0xf>(v);
  v = dppMaxF32<0x142, 0xa>(v);
  v = dppMaxF32<0x143, 0xc>(v);
  return __int_as_float(__builtin_amdgcn_readlane(__float_as_int(v), 63));
}
template <int CTRL, int RM>
DEVI unsigned dppMinU32(unsigned v) {
  int o = __builtin_amdgcn_update_dpp((int)v, (int)v, CTRL, RM, 0xf, false);
  unsigned ov = (unsigned)o;
  return v < ov ? v : ov;
}
DEVI unsigned waveMinU32(unsigned v) {
  v = dppMinU32<0x111, 0xf>(v);
  v = dppMinU32<0x112, 0xf>(v);
  v = dppMinU32<0x114, 0xf>(v);
  v = dppMinU32<0x118, 0xf>(v);
  v = dppMinU32<0x142, 0xa>(v);
  v = dppMinU32<0x143, 0xc>(v);
  return (unsigned)__builtin_amdgcn_readlane((int)v, 63);
}

// ---- bf16 split helpers (RNE) ----
DEVI unsigned short bfhi(float x) {
  unsigned u = __float_as_uint(x);
  return (unsigned short)((u + 0x7FFFu + ((u >> 16) & 1u)) >> 16);
}
DEVI float bf2f(unsigned short h) { return __uint_as_float(((unsigned)h) << 16); }
DEVI void mkfrag(const float* p, bf16x8& hi, bf16x8& lo) {
#pragma unroll
  for (int e = 0; e < 8; ++e) {
    float x = p[e];
    unsigned short h = bfhi(x);
    float r = x - bf2f(h);
    unsigned short l2 = bfhi(r);
    hi[e] = (short)h;
    lo[e] = (short)l2;
  }
}

// ================= device bodies ======

DEVI void x0_body(const int* __restrict__ feat, const float* __restrict__ emb,
                  const float* __restrict__ pid, float* __restrict__ x0buf,
                  int bx, int t) {
  int gid = bx * 256 + t;
  if (gid >= B * N0 * 32) return;
  int c = gid & 31;
  int bn = gid >> 5;
  int n = bn & (N0 - 1);
  int f = feat[bn];
  float v = emb[f * 32 + c];
  if (n < 1024) v += pid[n * 32 + c];
  x0buf[gid] = v;
}

// ---- farthest point sampling (selection semantics == jnp.argmax) ----
template <int NPTS, int M, int BLK>
DEVI void fps_body(char* smem, const float* __restrict__ pos,
                   float* __restrict__ pos_out, int b, int t) {
  constexpr int EPT = NPTS / BLK;
  constexpr int EP2 = EPT / 2;
  constexpr int NW = BLK / 64;
  float4* posl = (float4*)smem;
  float4* outp = (float4*)(smem + (size_t)NPTS * 16);
  unsigned long long* redk =
      (unsigned long long*)(smem + (size_t)(NPTS + M) * 16);  // [2][NW]
  const float* pb = pos + (size_t)b * NPTS * 3;
  f32x2 px[EP2], py[EP2], pz[EP2], d[EP2];
#pragma unroll
  for (int e = 0; e < EP2; ++e) {
    int i0 = t + (2 * e) * BLK;
    int i1 = t + (2 * e + 1) * BLK;
    float x0 = pb[i0 * 3 + 0], y0 = pb[i0 * 3 + 1], z0 = pb[i0 * 3 + 2];
    float x1 = pb[i1 * 3 + 0], y1 = pb[i1 * 3 + 1], z1 = pb[i1 * 3 + 2];
    px[e] = (f32x2){x0, x1};
    py[e] = (f32x2){y0, y1};
    pz[e] = (f32x2){z0, z1};
    posl[i0] = make_float4(x0, y0, z0, 0.f);
    posl[i1] = make_float4(x1, y1, z1, 0.f);
  }
  float sx = pb[0], sy = pb[1], sz = pb[2];
  if (t == 0) outp[0] = make_float4(sx, sy, sz, 0.f);
  f32x2 m2 = (f32x2){-1.f, -1.f};
#pragma unroll
  for (int e = 0; e < EP2; ++e) {
    d[e] = dist2v(px[e], py[e], pz[e], sx, sy, sz);
    m2.x = fmaxf(m2.x, d[e].x);
    m2.y = fmaxf(m2.y, d[e].y);
  }
  for (int it = 1; it < M; ++it) {
    const float vstar = waveMaxF32(fmaxf(m2.x, m2.y));
    unsigned cand = 0xffffffffu;
#pragma unroll
    for (int e = 0; e < EP2; ++e) {
      unsigned c0 = (d[e].x == vstar) ? (unsigned)(t + (2 * e) * BLK) : 0xffffffffu;
      unsigned c1 = (d[e].y == vstar) ? (unsigned)(t + (2 * e + 1) * BLK) : 0xffffffffu;
      cand = cand < c0 ? cand : c0;
      cand = cand < c1 ? cand : c1;
    }
    cand = waveMinU32(cand);
    unsigned sel;
    if constexpr (NW > 1) {
      if ((t & 63) == 0) {
        unsigned long long key =
            ((unsigned long long)__float_as_uint(vstar) << 32) |
            (unsigned)(0x7fffffffu - cand);
        redk[(it & 1) * NW + (t >> 6)] = key;
      }
      __syncthreads();
      unsigned long long kk = redk[(it & 1) * NW + 0];
#pragma unroll
      for (int w = 1; w < NW; ++w) {
        unsigned long long o = redk[(it & 1) * NW + w];
        kk = (kk > o) ? kk : o;
      }
      sel = 0x7fffffffu - (unsigned)(kk & 0xffffffffULL);
    } else {
      sel = cand;
    }
    float4 sp = posl[sel];
    if (t == 0) outp[it] = sp;
    m2 = (f32x2){-1.f, -1.f};
#pragma unroll
    for (int e = 0; e < EP2; ++e) {
      f32x2 nd = dist2v(px[e], py[e], pz[e], sp.x, sp.y, sp.z);
      d[e].x = fminf(d[e].x, nd.x);
      d[e].y = fminf(d[e].y, nd.y);
      m2.x = fmaxf(m2.x, d[e].x);
      m2.y = fmaxf(m2.y, d[e].y);
    }
  }
  if constexpr (NW > 1) __syncthreads();
  for (int m = t; m < M; m += BLK) {
    float4 q = outp[m];
    pos_out[(size_t)(b * M + m) * 3 + 0] = q.x;
    pos_out[(size_t)(b * M + m) * 3 + 1] = q.y;
    pos_out[(size_t)(b * M + m) * 3 + 2] = q.z;
  }
}

// ---- radius neighbors (<=64 nearest within r), rank-select overflow ----
template <int NPTS, int M>
DEVI void radius_body(char* smem, const float* __restrict__ pos,
                      const float* __restrict__ pos_s, float r2,
                      int* __restrict__ nbr, int* __restrict__ cnt, int blk,
                      int t) {
  unsigned long long* candkey = (unsigned long long*)smem;
  int* ctrp = (int*)(smem + (size_t)NPTS * 8);
  const int b = blk / M;
  const float* pb = pos + (size_t)b * NPTS * 3;
  const float cx = pos_s[(size_t)blk * 3 + 0];
  const float cy = pos_s[(size_t)blk * 3 + 1];
  const float cz = pos_s[(size_t)blk * 3 + 2];
  if (t == 0) *ctrp = 0;
  __syncthreads();
  for (int j = t; j < NPTS; j += 256) {
    float d2 = dist2f(pb[j * 3 + 0], pb[j * 3 + 1], pb[j * 3 + 2], cx, cy, cz);
    if (d2 <= r2) {
      int p = atomicAdd(ctrp, 1);
      candkey[p] = packMinKey(d2, j);
      if (p < KNB) nbr[(size_t)blk * KNB + p] = j;
    }
  }
  __syncthreads();
  const int c = *ctrp;
  if (c <= KNB) {
    if (t == 0) cnt[blk] = c;
    return;
  }
  for (int s = t; s < c; s += 256) {
    unsigned long long mykey = candkey[s];
    int rank = 0;
#pragma unroll 4
    for (int j = 0; j < c; ++j) {
      rank += (candkey[j] < mykey) ? 1 : 0;
    }
    if (rank < KNB)
      nbr[(size_t)blk * KNB + rank] = (int)(unsigned)(mykey & 0xffffffffULL);
  }
  if (t == 0) cnt[blk] = KNB;
}

// ---- stage 1 conv: 35 -> 64 -> 64 -> 64, max over nbrs (4 slots x 64ch) ----
DEVI void conv1_body(char* smem, const float* __restrict__ x0buf,
                     const float* __restrict__ pos,
                     const float* __restrict__ pos_s,
                     const int* __restrict__ nbr, const int* __restrict__ cntp,
                     const float* __restrict__ w0, const float* __restrict__ b0,
                     const float* __restrict__ w1, const float* __restrict__ b1,
                     const float* __restrict__ w2, const float* __restrict__ b2,
                     float* __restrict__ x1, int blk, int t) {
  float(*ins)[36] = (float(*)[36])smem;
  float(*hh)[65] = (float(*)[65])(smem + 576);
  float(*sred)[65] = (float(*)[65])(smem + 1616);
  const int slot = t >> 6;
  const int ch = t & 63;
  const int b = blk >> 10;
  const int c = cntp[blk];
  const float cx = pos_s[(size_t)blk * 3 + 0];
  const float cy = pos_s[(size_t)blk * 3 + 1];
  const float cz = pos_s[(size_t)blk * 3 + 2];
  float best = -__builtin_inff();
  for (int r0 = 0; r0 < c; r0 += 4) {
    const int r = r0 + slot;
    const bool act = r < c;
    const int j = nbr[(size_t)blk * KNB + (act ? r : 0)];
    if (ch < 32) {
      ins[slot][ch] = x0buf[((size_t)(b * N0) + j) * 32 + ch];
    } else if (ch < 35) {
      float pv = pos[((size_t)(b * N0) + j) * 3 + (ch - 32)];
      float cv = (ch == 32) ? cx : (ch == 33) ? cy : cz;
      ins[slot][ch] = pv - cv;
    }
    __syncthreads();
    float v = b0[ch];
#pragma unroll
    for (int i = 0; i < 35; ++i) v = fmaf(ins[slot][i], w0[i * 64 + ch], v);
    v = fmaxf(v, 0.f);
    hh[slot][ch] = v;
    __syncthreads();
    float v2 = b1[ch];
#pragma unroll
    for (int i = 0; i < 64; ++i) v2 = fmaf(hh[slot][i], w1[i * 64 + ch], v2);
    v2 = fmaxf(v2, 0.f);
    __syncthreads();
    hh[slot][ch] = v2;
    __syncthreads();
    float v3 = b2[ch];
#pragma unroll
    for (int i = 0; i < 64; ++i) v3 = fmaf(hh[slot][i], w2[i * 64 + ch], v3);
    if (act) best = fmaxf(best, v3);
    __syncthreads();
  }
  sred[slot][ch] = best;
  __syncthreads();
  if (t < 64) {
    float v = sred[0][t];
#pragma unroll
    for (int s = 1; s < 4; ++s) v = fmaxf(v, sred[s][t]);
    x1[(size_t)blk * 64 + t] = v;
  }
}

// ---- stage 2 conv via split-bf16 MFMA: 67 -> 128 -> 128 -> 256 ----
// (x_hi + x_lo) * w_hi : 2 MFMAs per tile; dropped x*w_lo term ~2e-3 abs err.
// One block per center; wave w owns rows [16w,16w+16). L1's A comes straight
// from global x1 (L2-resident) — no msg staging.
// smem: h1[64][132] | h2[64][132]; red aliases h1. Total 67584 B.
DEVI void conv2_mfma_body(char* smem, const float* __restrict__ x1,
                          const float* __restrict__ pos1,
                          const float* __restrict__ pos2,
                          const int* __restrict__ nbr,
                          const int* __restrict__ cntp,
                          const unsigned short* __restrict__ w0h,
                          const float* __restrict__ b0,
                          const unsigned short* __restrict__ w1h,
                          const float* __restrict__ b1,
                          const unsigned short* __restrict__ w2h,
                          const float* __restrict__ b2,
                          float* __restrict__ x2, int blk, int t) {
  float(*h1)[132] = (float(*)[132])smem;
  float(*h2)[132] = (float(*)[132])(smem + 33792);
  float* red = (float*)smem;  // alias h1 (dead after L2 reads)
  const int b = blk >> 8;
  const int c = cntp[blk];
  const int w = t >> 6;
  const int lane = t & 63;
  const int cb = lane & 15;
  const int kb = lane >> 4;
  const int mrow = w * 16 + cb;  // A-fragment row
  const int jrow = nbr[(size_t)blk * KNB + (mrow < c ? mrow : c - 1)];
  const float* xrow = x1 + ((size_t)(b * 1024) + jrow) * 64;
  const float cx = pos2[(size_t)blk * 3 + 0];
  const float cy = pos2[(size_t)blk * 3 + 1];
  const float cz = pos2[(size_t)blk * 3 + 2];

  // ---------- L1: K=67 (pad 96, KS=3), N=128 ----------
  f32x4 acc1[8];
#pragma unroll
  for (int nt = 0; nt < 8; ++nt) acc1[nt] = (f32x4){0.f, 0.f, 0.f, 0.f};
#pragma unroll
  for (int ks = 0; ks < 2; ++ks) {
    float xv[8];
    *(float4*)&xv[0] = *(const float4*)&xrow[ks * 32 + kb * 8];
    *(float4*)&xv[4] = *(const float4*)&xrow[ks * 32 + kb * 8 + 4];
    bf16x8 ahi, alo;
    mkfrag(xv, ahi, alo);
#pragma unroll
    for (int nt = 0; nt < 8; ++nt) {
      size_t off = ((size_t)(nt * 3 + ks) * 64 + lane) * 8;
      bf16x8 bhi = *(const bf16x8*)(w0h + off);
      acc1[nt] = __builtin_amdgcn_mfma_f32_16x16x32_bf16(ahi, bhi, acc1[nt], 0, 0, 0);
      acc1[nt] = __builtin_amdgcn_mfma_f32_16x16x32_bf16(alo, bhi, acc1[nt], 0, 0, 0);
    }
  }
  {  // ks=2: k=64..66 = pos-diff (kb==0, e<3); weights zero-padded past 67
    float xv[8] = {0.f, 0.f, 0.f, 0.f, 0.f, 0.f, 0.f, 0.f};
    if (kb == 0) {
      xv[0] = pos1[((size_t)(b * 1024) + jrow) * 3 + 0] - cx;
      xv[1] = pos1[((size_t)(b * 1024) + jrow) * 3 + 1] - cy;
      xv[2] = pos1[((size_t)(b * 1024) + jrow) * 3 + 2] - cz;
    }
    bf16x8 ahi, alo;
    mkfrag(xv, ahi, alo);
#pragma unroll
    for (int nt = 0; nt < 8; ++nt) {
      size_t off = ((size_t)(nt * 3 + 2) * 64 + lane) * 8;
      bf16x8 bhi = *(const bf16x8*)(w0h + off);
      acc1[nt] = __builtin_amdgcn_mfma_f32_16x16x32_bf16(ahi, bhi, acc1[nt], 0, 0, 0);
      acc1[nt] = __builtin_amdgcn_mfma_f32_16x16x32_bf16(alo, bhi, acc1[nt], 0, 0, 0);
    }
  }
  {  // h1 = ReLU(acc1 + b0); C/D row = w*16 + kb*4 + r, col = nt*16 + cb
    const int mw = w * 16 + kb * 4;
#pragma unroll
    for (int nt = 0; nt < 8; ++nt) {
      float bias = b0[nt * 16 + cb];
#pragma unroll
      for (int r = 0; r < 4; ++r)
        h1[mw + r][nt * 16 + cb] = fmaxf(acc1[nt][r] + bias, 0.f);
    }
  }
  __syncthreads();

  // ---------- L2: K=128 (KS=4), N=128 ----------
  f32x4 acc2[8];
#pragma unroll
  for (int nt = 0; nt < 8; ++nt) acc2[nt] = (f32x4){0.f, 0.f, 0.f, 0.f};
#pragma unroll
  for (int ks = 0; ks < 4; ++ks) {
    bf16x8 ahi, alo;
    mkfrag(&h1[mrow][ks * 32 + kb * 8], ahi, alo);
#pragma unroll
    for (int nt = 0; nt < 8; ++nt) {
      size_t off = ((size_t)(nt * 4 + ks) * 64 + lane) * 8;
      bf16x8 bhi = *(const bf16x8*)(w1h + off);
      acc2[nt] = __builtin_amdgcn_mfma_f32_16x16x32_bf16(ahi, bhi, acc2[nt], 0, 0, 0);
      acc2[nt] = __builtin_amdgcn_mfma_f32_16x16x32_bf16(alo, bhi, acc2[nt], 0, 0, 0);
    }
  }
  {
    const int mw = w * 16 + kb * 4;
#pragma unroll
    for (int nt = 0; nt < 8; ++nt) {
      float bias = b1[nt * 16 + cb];
#pragma unroll
      for (int r = 0; r < 4; ++r)
        h2[mw + r][nt * 16 + cb] = fmaxf(acc2[nt][r] + bias, 0.f);
    }
  }
  __syncthreads();

  // ---------- L3: K=128 (KS=4), N=256 ----------
  f32x4 acc3[16];
#pragma unroll
  for (int nt = 0; nt < 16; ++nt) acc3[nt] = (f32x4){0.f, 0.f, 0.f, 0.f};
#pragma unroll
  for (int ks = 0; ks < 4; ++ks) {
    bf16x8 ahi, alo;
    mkfrag(&h2[mrow][ks * 32 + kb * 8], ahi, alo);
#pragma unroll
    for (int nt = 0; nt < 16; ++nt) {
      size_t off = ((size_t)(nt * 4 + ks) * 64 + lane) * 8;
      bf16x8 bhi = *(const bf16x8*)(w2h + off);
      acc3[nt] = __builtin_amdgcn_mfma_f32_16x16x32_bf16(ahi, bhi, acc3[nt], 0, 0, 0);
      acc3[nt] = __builtin_amdgcn_mfma_f32_16x16x32_bf16(alo, bhi, acc3[nt], 0, 0, 0);
    }
  }
  __syncthreads();  // h1 area now reused as red
  {
    const int mw = w * 16 + kb * 4;
#pragma unroll
    for (int nt = 0; nt < 16; ++nt) {
      float bias = b2[nt * 16 + cb];
      float mx = -__builtin_inff();
#pragma unroll
      for (int r = 0; r < 4; ++r) {
        if (mw + r < c) mx = fmaxf(mx, acc3[nt][r] + bias);
      }
      red[(w * 4 + kb) * 256 + nt * 16 + cb] = mx;
    }
  }
  __syncthreads();
  {
    float v = red[t];
#pragma unroll
    for (int g = 1; g < 16; ++g) v = fmaxf(v, red[g * 256 + t]);
    x2[(size_t)blk * 256 + t] = v;
  }
}

// ================= merged launch kernels ====================================

__global__ void __launch_bounds__(256) l1_kernel(
    const float* __restrict__ pos, float* __restrict__ pos1,
    const int* __restrict__ feat, const float* __restrict__ emb,
    const float* __restrict__ pid, float* __restrict__ x0buf) {
  __shared__ __attribute__((aligned(16))) char smem[81984];
  if (blockIdx.x < 8) {
    fps_body<4096, 1024, 256>(smem, pos, pos1, blockIdx.x, threadIdx.x);
  } else {
    x0_body(feat, emb, pid, x0buf, blockIdx.x - 8, threadIdx.x);
  }
}

__global__ void __launch_bounds__(256) l2_kernel(
    const float* __restrict__ pos1, float* __restrict__ pos2,
    const float* __restrict__ pos, float r2a, int* __restrict__ nbr1,
    int* __restrict__ cnt1) {
  __shared__ __attribute__((aligned(16))) char smem[33024];
  if (blockIdx.x < 8) {
    fps_body<1024, 256, 256>(smem, pos1, pos2, blockIdx.x, threadIdx.x);
  } else {
    radius_body<4096, 1024>(smem, pos, pos1, r2a, nbr1, cnt1, blockIdx.x - 8,
                            threadIdx.x);
  }
}

__global__ void __launch_bounds__(256) l3_kernel(
    const float* __restrict__ pos2, float* __restrict__ pos3, float r2b,
    int* __restrict__ nbr2, int* __restrict__ cnt2,
    const float* __restrict__ pos1, const float* __restrict__ x0buf,
    const float* __restrict__ pos, const int* __restrict__ nbr1,
    const int* __restrict__ cnt1, const float* __restrict__ w0,
    const float* __restrict__ b0, const float* __restrict__ w1,
    const float* __restrict__ b1, const float* __restrict__ w2,
    const float* __restrict__ b2, float* __restrict__ x1) {
  __shared__ __attribute__((aligned(16))) char smem[8448];
  if (blockIdx.x < 8) {
    if (threadIdx.x < 64)
      fps_body<256, 64, 64>(smem, pos2, pos3, blockIdx.x, threadIdx.x);
  } else if (blockIdx.x < 8 + 2048) {
    radius_body<1024, 256>(smem, pos1, pos2, r2b, nbr2, cnt2, blockIdx.x - 8,
                           threadIdx.x);
  } else {
    conv1_body(smem, x0buf, pos, pos1, nbr1, cnt1, w0, b0, w1, b1, w2, b2, x1,
               blockIdx.x - (8 + 2048), threadIdx.x);
  }
}

// L4: radius3 (blocks 0..511) || conv2-MFMA (blocks 512..2559)
__global__ void __launch_bounds__(256) l4_kernel(
    const float* __restrict__ pos2, const float* __restrict__ pos3, float r2c,
    int* __restrict__ nbr3, int* __restrict__ cnt3,
    const float* __restrict__ x1, const float* __restrict__ pos1,
    const int* __restrict__ nbr2, const int* __restrict__ cnt2,
    const unsigned short* __restrict__ v0h, const float* __restrict__ b0,
    const unsigned short* __restrict__ v1h, const float* __restrict__ b1,
    const unsigned short* __restrict__ v2h, const float* __restrict__ b2,
    float* __restrict__ x2) {
  __shared__ __attribute__((aligned(16))) char smem[67584];
  if (blockIdx.x < 512) {
    radius_body<256, 64>(smem, pos2, pos3, r2c, nbr3, cnt3, blockIdx.x,
                         threadIdx.x);
  } else {
    conv2_mfma_body(smem, x1, pos1, pos2, nbr2, cnt2, v0h, b0, v1h, b1, v2h,
                    b2, x2, blockIdx.x - 512, threadIdx.x);
  }
}

// ---------------- weight packing into MFMA-B fragment order -----------------
// B-fragment for mfma_f32_16x16x32_bf16: lane l holds col n = l&15,
// k = (l>>4)*8 + e (e=0..7). Packed: elem = ((nt*KS + ks)*64 + l)*8 + e
// where n = nt*16 + (l&15), k = ks*32 + (l>>4)*8 + e; k >= Kreal -> 0.
__global__ void __launch_bounds__(256) pack_kernel(
    const float* __restrict__ W, int Kreal, int KS, int N,
    unsigned short* __restrict__ hi, unsigned short* __restrict__ lo) {
  int gid = blockIdx.x * 256 + threadIdx.x;
  int total = (N / 16) * KS * 64 * 8;
  if (gid >= total) return;
  int e = gid & 7;
  int l = (gid >> 3) & 63;
  int rest = gid >> 9;
  int ks = rest % KS;
  int nt = rest / KS;
  int n = nt * 16 + (l & 15);
  int k = ks * 32 + (l >> 4) * 8 + e;
  float val = (k < Kreal) ? W[(size_t)k * N + n] : 0.f;
  unsigned short h = bfhi(val);
  float r = val - bf2f(h);
  hi[gid] = h;
  lo[gid] = bfhi(r);
}

// ---------------- stage 3 conv via split-bf16 MFMA (3-term, proven) ---------
__global__ void __launch_bounds__(256) conv3_mfma(
    const float* __restrict__ x2, const float* __restrict__ pos2,
    const float* __restrict__ pos3, const int* __restrict__ nbr,
    const int* __restrict__ cntp,
    const unsigned short* __restrict__ w0h, const unsigned short* __restrict__ w0l,
    const float* __restrict__ b0,
    const unsigned short* __restrict__ w1h, const unsigned short* __restrict__ w1l,
    const float* __restrict__ b1,
    const unsigned short* __restrict__ w2h, const unsigned short* __restrict__ w2l,
    const float* __restrict__ b2, float* __restrict__ out) {
  __shared__ __attribute__((aligned(16))) float h1s[64 * 268];
  __shared__ __attribute__((aligned(16))) float h2cs[64 * 140];
  __shared__ __attribute__((aligned(16))) float msgcs[64 * 44];
  const int blk = blockIdx.x;
  const int t = threadIdx.x;
  const int b = blk >> 6;
  const int c = cntp[blk];
  const int w = t >> 6;
  const int lane = t & 63;
  const int cb = lane & 15;
  const int kb = lane >> 4;
  const float cx = pos3[(size_t)blk * 3 + 0];
  const float cy = pos3[(size_t)blk * 3 + 1];
  const float cz = pos3[(size_t)blk * 3 + 2];
  const int mrow = w * 16 + cb;

  f32x4 acc1[16];
#pragma unroll
  for (int nt = 0; nt < 16; ++nt) acc1[nt] = (f32x4){0.f, 0.f, 0.f, 0.f};
  for (int ks = 0; ks < 9; ++ks) {
#pragma unroll
    for (int i = 0; i < 8; ++i) {
      int idx = t + i * 256;
      int row = idx >> 5;
      int col = idx & 31;
      int kg = ks * 32 + col;
      int j = nbr[(size_t)blk * KNB + (row < c ? row : c - 1)];
      float v = 0.f;
      if (kg < 256) {
        v = x2[((size_t)(b * 256) + j) * 256 + kg];
      } else if (kg < 259) {
        float pv = pos2[((size_t)(b * 256) + j) * 3 + (kg - 256)];
        v = pv - ((kg == 256) ? cx : (kg == 257) ? cy : cz);
      }
      msgcs[row * 44 + col] = v;
    }
    __syncthreads();
    bf16x8 ahi, alo;
    mkfrag(&msgcs[mrow * 44 + kb * 8], ahi, alo);
#pragma unroll
    for (int nt = 0; nt < 16; ++nt) {
      size_t off = ((size_t)(nt * 9 + ks) * 64 + lane) * 8;
      bf16x8 bhi = *(const bf16x8*)(w0h + off);
      bf16x8 blo = *(const bf16x8*)(w0l + off);
      acc1[nt] = __builtin_amdgcn_mfma_f32_16x16x32_bf16(ahi, bhi, acc1[nt], 0, 0, 0);
      acc1[nt] = __builtin_amdgcn_mfma_f32_16x16x32_bf16(alo, bhi, acc1[nt], 0, 0, 0);
      acc1[nt] = __builtin_amdgcn_mfma_f32_16x16x32_bf16(ahi, blo, acc1[nt], 0, 0, 0);
    }
    __syncthreads();
  }
  {
    const int mw = w * 16 + kb * 4;
#pragma unroll
    for (int nt = 0; nt < 16; ++nt) {
      float bias = b0[nt * 16 + cb];
#pragma unroll
      for (int r = 0; r < 4; ++r)
        h1s[(mw + r) * 268 + nt * 16 + cb] = fmaxf(acc1[nt][r] + bias, 0.f);
    }
  }
  __syncthreads();

  f32x4 acc3[32];
#pragma unroll
  for (int nt = 0; nt < 32; ++nt) acc3[nt] = (f32x4){0.f, 0.f, 0.f, 0.f};
  for (int ch = 0; ch < 4; ++ch) {
    f32x4 acc2[8];
#pragma unroll
    for (int nt = 0; nt < 8; ++nt) acc2[nt] = (f32x4){0.f, 0.f, 0.f, 0.f};
#pragma unroll
    for (int ks = 0; ks < 8; ++ks) {
      bf16x8 ahi, alo;
      mkfrag(&h1s[mrow * 268 + ks * 32 + kb * 8], ahi, alo);
#pragma unroll
      for (int nt = 0; nt < 8; ++nt) {
        size_t off = ((size_t)((ch * 8 + nt) * 8 + ks) * 64 + lane) * 8;
        bf16x8 bhi = *(const bf16x8*)(w1h + off);
        bf16x8 blo = *(const bf16x8*)(w1l + off);
        acc2[nt] = __builtin_amdgcn_mfma_f32_16x16x32_bf16(ahi, bhi, acc2[nt], 0, 0, 0);
        acc2[nt] = __builtin_amdgcn_mfma_f32_16x16x32_bf16(alo, bhi, acc2[nt], 0, 0, 0);
        acc2[nt] = __builtin_amdgcn_mfma_f32_16x16x32_bf16(ahi, blo, acc2[nt], 0, 0, 0);
      }
    }
    {
      const int mw = w * 16 + kb * 4;
#pragma unroll
      for (int nt = 0; nt < 8; ++nt) {
        float bias = b1[ch * 128 + nt * 16 + cb];
#pragma unroll
        for (int r = 0; r < 4; ++r)
          h2cs[(mw + r) * 140 + nt * 16 + cb] = fmaxf(acc2[nt][r] + bias, 0.f);
      }
    }
    __syncthreads();
#pragma unroll
    for (int ks3 = 0; ks3 < 4; ++ks3) {
      bf16x8 ahi, alo;
      mkfrag(&h2cs[mrow * 140 + ks3 * 32 + kb * 8], ahi, alo);
#pragma unroll
      for (int nt = 0; nt < 32; ++nt) {
        size_t off = ((size_t)(nt * 16 + ch * 4 + ks3) * 64 + lane) * 8;
        bf16x8 bhi = *(const bf16x8*)(w2h + off);
        bf16x8 blo = *(const bf16x8*)(w2l + off);
        acc3[nt] = __builtin_amdgcn_mfma_f32_16x16x32_bf16(ahi, bhi, acc3[nt], 0, 0, 0);
        acc3[nt] = __builtin_amdgcn_mfma_f32_16x16x32_bf16(alo, bhi, acc3[nt], 0, 0, 0);
        acc3[nt] = __builtin_amdgcn_mfma_f32_16x16x32_bf16(ahi, blo, acc3[nt], 0, 0, 0);
      }
    }
    __syncthreads();
  }

  float* redw = h1s;
  {
    const int mw = w * 16 + kb * 4;
#pragma unroll
    for (int nt = 0; nt < 32; ++nt) {
      float bias = b2[nt * 16 + cb];
      float mx = -__builtin_inff();
#pragma unroll
      for (int r = 0; r < 4; ++r) {
        if (mw + r < c) mx = fmaxf(mx, acc3[nt][r] + bias);
      }
      redw[(w * 4 + kb) * 512 + nt * 16 + cb] = mx;
    }
  }
  __syncthreads();
#pragma unroll
  for (int half = 0; half < 2; ++half) {
    int col = t + half * 256;
    float v = redw[col];
#pragma unroll
    for (int g = 1; g < 16; ++g) v = fmaxf(v, redw[g * 512 + col]);
    out[(size_t)blk * 512 + col] = v;
  }
}

extern "C" void kernel_launch(void* const* d_in, const int* in_sizes, int n_in,
                              void* d_out, int out_size, void* d_ws, size_t ws_size,
                              hipStream_t stream) {
  const int* feat = (const int*)d_in[0];
  const float* pos = (const float*)d_in[1];
  const float* emb = (const float*)d_in[2];
  const float* pid = (const float*)d_in[3];
  const float* s1w0 = (const float*)d_in[4];
  const float* s1b0 = (const float*)d_in[5];
  const float* s1w1 = (const float*)d_in[6];
  const float* s1b1 = (const float*)d_in[7];
  const float* s1w2 = (const float*)d_in[8];
  const float* s1b2 = (const float*)d_in[9];
  const float* s2w0 = (const float*)d_in[10];
  const float* s2b0 = (const float*)d_in[11];
  const float* s2w1 = (const float*)d_in[12];
  const float* s2b1 = (const float*)d_in[13];
  const float* s2w2 = (const float*)d_in[14];
  const float* s2b2 = (const float*)d_in[15];
  const float* s3w0 = (const float*)d_in[16];
  const float* s3b0 = (const float*)d_in[17];
  const float* s3w1 = (const float*)d_in[18];
  const float* s3b1 = (const float*)d_in[19];
  const float* s3w2 = (const float*)d_in[20];
  const float* s3b2 = (const float*)d_in[21];
  (void)in_sizes; (void)n_in; (void)out_size; (void)ws_size;

  char* ws = (char*)d_ws;
  size_t off = 0;
  auto alloc = [&](size_t nbytes) {
    void* p = ws + off;
    off = (off + nbytes + 255) & ~(size_t)255;
    return p;
  };
  float* x0 = (float*)alloc((size_t)B * N0 * 32 * 4);
  float* pos1 = (float*)alloc((size_t)B * 1024 * 3 * 4);
  int* nbr1 = (int*)alloc((size_t)B * 1024 * KNB * 4);
  int* cnt1 = (int*)alloc((size_t)B * 1024 * 4);
  float* x1 = (float*)alloc((size_t)B * 1024 * 64 * 4);
  float* pos2 = (float*)alloc((size_t)B * 256 * 3 * 4);
  int* nbr2 = (int*)alloc((size_t)B * 256 * KNB * 4);
  int* cnt2 = (int*)alloc((size_t)B * 256 * 4);
  float* x2 = (float*)alloc((size_t)B * 256 * 256 * 4);
  int* nbr3 = (int*)alloc((size_t)B * 64 * KNB * 4);
  int* cnt3 = (int*)alloc((size_t)B * 64 * 4);
  // packed split-bf16 weights: conv3 (hi+lo used) and conv2 (hi used)
  const int T0 = 16 * 9 * 64 * 8;
  const int T1 = 32 * 8 * 64 * 8;
  const int T2 = 32 * 16 * 64 * 8;
  unsigned short* w0h = (unsigned short*)alloc((size_t)T0 * 2);
  unsigned short* w0l = (unsigned short*)alloc((size_t)T0 * 2);
  unsigned short* w1h = (unsigned short*)alloc((size_t)T1 * 2);
  unsigned short* w1l = (unsigned short*)alloc((size_t)T1 * 2);
  unsigned short* w2h = (unsigned short*)alloc((size_t)T2 * 2);
  unsigned short* w2l = (unsigned short*)alloc((size_t)T2 * 2);
  const int U0 = 8 * 3 * 64 * 8;
  const int U1 = 8 * 4 * 64 * 8;
  const int U2 = 16 * 4 * 64 * 8;
  unsigned short* v0h = (unsigned short*)alloc((size_t)U0 * 2);
  unsigned short* v0l = (unsigned short*)alloc((size_t)U0 * 2);
  unsigned short* v1h = (unsigned short*)alloc((size_t)U1 * 2);
  unsigned short* v1l = (unsigned short*)alloc((size_t)U1 * 2);
  unsigned short* v2h = (unsigned short*)alloc((size_t)U2 * 2);
  unsigned short* v2l = (unsigned short*)alloc((size_t)U2 * 2);

  float* xout = (float*)d_out;                 // (B,64,512)
  float* pos3 = xout + (size_t)B * 64 * 512;   // (B,64,3)

  const float r2a = (float)(0.05 * 0.05);
  const float r2b = (float)(0.3 * 0.3);
  const float r2c = (float)(0.5 * 0.5);

  pack_kernel<<<(T0 + 255) / 256, 256, 0, stream>>>(s3w0, 259, 9, 256, w0h, w0l);
  pack_kernel<<<(T1 + 255) / 256, 256, 0, stream>>>(s3w1, 256, 8, 512, w1h, w1l);
  pack_kernel<<<(T2 + 255) / 256, 256, 0, stream>>>(s3w2, 512, 16, 512, w2h, w2l);
  pack_kernel<<<(U0 + 255) / 256, 256, 0, stream>>>(s2w0, 67, 3, 128, v0h, v0l);
  pack_kernel<<<(U1 + 255) / 256, 256, 0, stream>>>(s2w1, 128, 4, 128, v1h, v1l);
  pack_kernel<<<(U2 + 255) / 256, 256, 0, stream>>>(s2w2, 128, 4, 256, v2h, v2l);

  l1_kernel<<<8 + 4096, 256, 0, stream>>>(pos, pos1, feat, emb, pid, x0);
  l2_kernel<<<8 + 8192, 256, 0, stream>>>(pos1, pos2, pos, r2a, nbr1, cnt1);
  l3_kernel<<<8 + 2048 + 8192, 256, 0, stream>>>(
      pos2, pos3, r2b, nbr2, cnt2, pos1, x0, pos, nbr1, cnt1,
      s1w0, s1b0, s1w1, s1b1, s1w2, s1b2, x1);
  l4_kernel<<<512 + 2048, 256, 0, stream>>>(
      pos2, pos3, r2c, nbr3, cnt3, x1, pos1, nbr2, cnt2,
      v0h, s2b0, v1h, s2b1, v2h, s2b2, x2);
  conv3_mfma<<<B * 64, 256, 0, stream>>>(x2, pos2, pos3, nbr3, cnt3,
                                         w0h, w0l, s3b0, w1h, w1l, s3b1,
                                         w2h, w2l, s3b2, xout);
}

// Round 10
// 1279.741 us; speedup vs baseline: 1.2054x; 1.0372x over previous
//
#include <hip/hip_runtime.h>

#define DEVI static __device__ __forceinline__

constexpr int B = 8;
constexpr int N0 = 4096;
constexpr int KNB = 64;

typedef float f32x2 __attribute__((ext_vector_type(2)));
typedef float f32x4 __attribute__((ext_vector_type(4)));
typedef short bf16x8 __attribute__((ext_vector_type(8)));

// d2 exactly as numpy: ((dx*dx + dy*dy) + dz*dz), no FMA contraction.
DEVI float dist2f(float ax, float ay, float az, float bx, float by, float bz) {
#pragma clang fp contract(off)
  float dx = ax - bx;
  float dy = ay - by;
  float dz = az - bz;
  return (dx * dx + dy * dy) + dz * dz;
}
DEVI f32x2 dist2v(f32x2 ax, f32x2 ay, f32x2 az, float bx, float by, float bz) {
#pragma clang fp contract(off)
  f32x2 dx = ax - bx;
  f32x2 dy = ay - by;
  f32x2 dz = az - bz;
  return (dx * dx + dy * dy) + dz * dz;
}

DEVI unsigned long long packMinKey(float v, int i) {
  return ((unsigned long long)__float_as_uint(v) << 32) | (unsigned int)i;
}

template <int CTRL, int RM>
DEVI float dppMaxF32(float v) {
  int o = __builtin_amdgcn_update_dpp(__float_as_int(v), __float_as_int(v),
                                      CTRL, RM, 0xf, false);
  return fmaxf(v, __int_as_float(o));
}
DEVI float waveMaxF32(float v) {
  v = dppMaxF32<0x111, 0xf>(v);
  v = dppMaxF32<0x112, 0xf>(v);
  v = dppMaxF32<0x114, 0xf>(v);
  v = dppMaxF32<0x118, 0xf>(v);
  v = dppMaxF32<0x142, 0xa>(v);
  v = dppMaxF32<0x143, 0xc>(v);
  return __int_as_float(__builtin_amdgcn_readlane(__float_as_int(v), 63));
}
template <int CTRL, int RM>
DEVI unsigned dppMinU32(unsigned v) {
  int o = __builtin_amdgcn_update_dpp((int)v, (int)v, CTRL, RM, 0xf, false);
  unsigned ov = (unsigned)o;
  return v < ov ? v : ov;
}
DEVI unsigned waveMinU32(unsigned v) {
  v = dppMinU32<0x111, 0xf>(v);
  v = dppMinU32<0x112, 0xf>(v);
  v = dppMinU32<0x114, 0xf>(v);
  v = dppMinU32<0x118, 0xf>(v);
  v = dppMinU32<0x142, 0xa>(v);
  v = dppMinU32<0x143, 0xc>(v);
  return (unsigned)__builtin_amdgcn_readlane((int)v, 63);
}

// ---- bf16 split helpers (RNE) ----
DEVI unsigned short bfhi(float x) {
  unsigned u = __float_as_uint(x);
  return (unsigned short)((u + 0x7FFFu + ((u >> 16) & 1u)) >> 16);
}
DEVI float bf2f(unsigned short h) { return __uint_as_float(((unsigned)h) << 16); }
DEVI void mkfrag(const float* p, bf16x8& hi, bf16x8& lo) {
#pragma unroll
  for (int e = 0; e < 8; ++e) {
    float x = p[e];
    unsigned short h = bfhi(x);
    float r = x - bf2f(h);
    unsigned short l2 = bfhi(r);
    hi[e] = (short)h;
    lo[e] = (short)l2;
  }
}

// ================= device bodies ======

DEVI void x0_body(const int* __restrict__ feat, const float* __restrict__ emb,
                  const float* __restrict__ pid, float* __restrict__ x0buf,
                  int bx, int t) {
  int gid = bx * 256 + t;
  if (gid >= B * N0 * 32) return;
  int c = gid & 31;
  int bn = gid >> 5;
  int n = bn & (N0 - 1);
  int f = feat[bn];
  float v = emb[f * 32 + c];
  if (n < 1024) v += pid[n * 32 + c];
  x0buf[gid] = v;
}

// ---- farthest point sampling (selection semantics == jnp.argmax) ----
template <int NPTS, int M, int BLK>
DEVI void fps_body(char* smem, const float* __restrict__ pos,
                   float* __restrict__ pos_out, int b, int t) {
  constexpr int EPT = NPTS / BLK;
  constexpr int EP2 = EPT / 2;
  constexpr int NW = BLK / 64;
  float4* posl = (float4*)smem;
  float4* outp = (float4*)(smem + (size_t)NPTS * 16);
  unsigned long long* redk =
      (unsigned long long*)(smem + (size_t)(NPTS + M) * 16);  // [2][NW]
  const float* pb = pos + (size_t)b * NPTS * 3;
  f32x2 px[EP2], py[EP2], pz[EP2], d[EP2];
#pragma unroll
  for (int e = 0; e < EP2; ++e) {
    int i0 = t + (2 * e) * BLK;
    int i1 = t + (2 * e + 1) * BLK;
    float x0 = pb[i0 * 3 + 0], y0 = pb[i0 * 3 + 1], z0 = pb[i0 * 3 + 2];
    float x1 = pb[i1 * 3 + 0], y1 = pb[i1 * 3 + 1], z1 = pb[i1 * 3 + 2];
    px[e] = (f32x2){x0, x1};
    py[e] = (f32x2){y0, y1};
    pz[e] = (f32x2){z0, z1};
    posl[i0] = make_float4(x0, y0, z0, 0.f);
    posl[i1] = make_float4(x1, y1, z1, 0.f);
  }
  float sx = pb[0], sy = pb[1], sz = pb[2];
  if (t == 0) outp[0] = make_float4(sx, sy, sz, 0.f);
  f32x2 m2 = (f32x2){-1.f, -1.f};
#pragma unroll
  for (int e = 0; e < EP2; ++e) {
    d[e] = dist2v(px[e], py[e], pz[e], sx, sy, sz);
    m2.x = fmaxf(m2.x, d[e].x);
    m2.y = fmaxf(m2.y, d[e].y);
  }
  for (int it = 1; it < M; ++it) {
    const float vstar = waveMaxF32(fmaxf(m2.x, m2.y));
    unsigned cand = 0xffffffffu;
#pragma unroll
    for (int e = 0; e < EP2; ++e) {
      unsigned c0 = (d[e].x == vstar) ? (unsigned)(t + (2 * e) * BLK) : 0xffffffffu;
      unsigned c1 = (d[e].y == vstar) ? (unsigned)(t + (2 * e + 1) * BLK) : 0xffffffffu;
      cand = cand < c0 ? cand : c0;
      cand = cand < c1 ? cand : c1;
    }
    cand = waveMinU32(cand);
    unsigned sel;
    if constexpr (NW > 1) {
      if ((t & 63) == 0) {
        unsigned long long key =
            ((unsigned long long)__float_as_uint(vstar) << 32) |
            (unsigned)(0x7fffffffu - cand);
        redk[(it & 1) * NW + (t >> 6)] = key;
      }
      __syncthreads();
      unsigned long long kk = redk[(it & 1) * NW + 0];
#pragma unroll
      for (int w = 1; w < NW; ++w) {
        unsigned long long o = redk[(it & 1) * NW + w];
        kk = (kk > o) ? kk : o;
      }
      sel = 0x7fffffffu - (unsigned)(kk & 0xffffffffULL);
    } else {
      sel = cand;
    }
    float4 sp = posl[sel];
    if (t == 0) outp[it] = sp;
    m2 = (f32x2){-1.f, -1.f};
#pragma unroll
    for (int e = 0; e < EP2; ++e) {
      f32x2 nd = dist2v(px[e], py[e], pz[e], sp.x, sp.y, sp.z);
      d[e].x = fminf(d[e].x, nd.x);
      d[e].y = fminf(d[e].y, nd.y);
      m2.x = fmaxf(m2.x, d[e].x);
      m2.y = fmaxf(m2.y, d[e].y);
    }
  }
  if constexpr (NW > 1) __syncthreads();
  for (int m = t; m < M; m += BLK) {
    float4 q = outp[m];
    pos_out[(size_t)(b * M + m) * 3 + 0] = q.x;
    pos_out[(size_t)(b * M + m) * 3 + 1] = q.y;
    pos_out[(size_t)(b * M + m) * 3 + 2] = q.z;
  }
}

// ---- radius neighbors (<=64 nearest within r), rank-select overflow ----
template <int NPTS, int M>
DEVI void radius_body(char* smem, const float* __restrict__ pos,
                      const float* __restrict__ pos_s, float r2,
                      int* __restrict__ nbr, int* __restrict__ cnt, int blk,
                      int t) {
  unsigned long long* candkey = (unsigned long long*)smem;
  int* ctrp = (int*)(smem + (size_t)NPTS * 8);
  const int b = blk / M;
  const float* pb = pos + (size_t)b * NPTS * 3;
  const float cx = pos_s[(size_t)blk * 3 + 0];
  const float cy = pos_s[(size_t)blk * 3 + 1];
  const float cz = pos_s[(size_t)blk * 3 + 2];
  if (t == 0) *ctrp = 0;
  __syncthreads();
  for (int j = t; j < NPTS; j += 256) {
    float d2 = dist2f(pb[j * 3 + 0], pb[j * 3 + 1], pb[j * 3 + 2], cx, cy, cz);
    if (d2 <= r2) {
      int p = atomicAdd(ctrp, 1);
      candkey[p] = packMinKey(d2, j);
      if (p < KNB) nbr[(size_t)blk * KNB + p] = j;
    }
  }
  __syncthreads();
  const int c = *ctrp;
  if (c <= KNB) {
    if (t == 0) cnt[blk] = c;
    return;
  }
  for (int s = t; s < c; s += 256) {
    unsigned long long mykey = candkey[s];
    int rank = 0;
#pragma unroll 4
    for (int j = 0; j < c; ++j) {
      rank += (candkey[j] < mykey) ? 1 : 0;
    }
    if (rank < KNB)
      nbr[(size_t)blk * KNB + rank] = (int)(unsigned)(mykey & 0xffffffffULL);
  }
  if (t == 0) cnt[blk] = KNB;
}

// ---- stage 1 conv: 35 -> 64 -> 64 -> 64, max over nbrs (4 slots x 64ch) ----
DEVI void conv1_body(char* smem, const float* __restrict__ x0buf,
                     const float* __restrict__ pos,
                     const float* __restrict__ pos_s,
                     const int* __restrict__ nbr, const int* __restrict__ cntp,
                     const float* __restrict__ w0, const float* __restrict__ b0,
                     const float* __restrict__ w1, const float* __restrict__ b1,
                     const float* __restrict__ w2, const float* __restrict__ b2,
                     float* __restrict__ x1, int blk, int t) {
  float(*ins)[36] = (float(*)[36])smem;
  float(*hh)[65] = (float(*)[65])(smem + 576);
  float(*sred)[65] = (float(*)[65])(smem + 1616);
  const int slot = t >> 6;
  const int ch = t & 63;
  const int b = blk >> 10;
  const int c = cntp[blk];
  const float cx = pos_s[(size_t)blk * 3 + 0];
  const float cy = pos_s[(size_t)blk * 3 + 1];
  const float cz = pos_s[(size_t)blk * 3 + 2];
  float best = -__builtin_inff();
  for (int r0 = 0; r0 < c; r0 += 4) {
    const int r = r0 + slot;
    const bool act = r < c;
    const int j = nbr[(size_t)blk * KNB + (act ? r : 0)];
    if (ch < 32) {
      ins[slot][ch] = x0buf[((size_t)(b * N0) + j) * 32 + ch];
    } else if (ch < 35) {
      float pv = pos[((size_t)(b * N0) + j) * 3 + (ch - 32)];
      float cv = (ch == 32) ? cx : (ch == 33) ? cy : cz;
      ins[slot][ch] = pv - cv;
    }
    __syncthreads();
    float v = b0[ch];
#pragma unroll
    for (int i = 0; i < 35; ++i) v = fmaf(ins[slot][i], w0[i * 64 + ch], v);
    v = fmaxf(v, 0.f);
    hh[slot][ch] = v;
    __syncthreads();
    float v2 = b1[ch];
#pragma unroll
    for (int i = 0; i < 64; ++i) v2 = fmaf(hh[slot][i], w1[i * 64 + ch], v2);
    v2 = fmaxf(v2, 0.f);
    __syncthreads();
    hh[slot][ch] = v2;
    __syncthreads();
    float v3 = b2[ch];
#pragma unroll
    for (int i = 0; i < 64; ++i) v3 = fmaf(hh[slot][i], w2[i * 64 + ch], v3);
    if (act) best = fmaxf(best, v3);
    __syncthreads();
  }
  sred[slot][ch] = best;
  __syncthreads();
  if (t < 64) {
    float v = sred[0][t];
#pragma unroll
    for (int s = 1; s < 4; ++s) v = fmaxf(v, sred[s][t]);
    x1[(size_t)blk * 64 + t] = v;
  }
}

// ---- stage 2 conv via split-bf16 MFMA: 67 -> 128 -> 128 -> 256 ----
// Per-wave row ownership (wave w writes/reads only h rows [16w,16w+16)) ->
// no interior barriers needed; only around the red alias.
DEVI void conv2_mfma_body(char* smem, const float* __restrict__ x1,
                          const float* __restrict__ pos1,
                          const float* __restrict__ pos2,
                          const int* __restrict__ nbr,
                          const int* __restrict__ cntp,
                          const unsigned short* __restrict__ w0h,
                          const float* __restrict__ b0,
                          const unsigned short* __restrict__ w1h,
                          const float* __restrict__ b1,
                          const unsigned short* __restrict__ w2h,
                          const float* __restrict__ b2,
                          float* __restrict__ x2, int blk, int t) {
  float(*h1)[132] = (float(*)[132])smem;
  float(*h2)[132] = (float(*)[132])(smem + 33792);
  float* red = (float*)smem;  // alias h1 (dead after L2 reads)
  const int b = blk >> 8;
  const int c = cntp[blk];
  const int w = t >> 6;
  const int lane = t & 63;
  const int cb = lane & 15;
  const int kb = lane >> 4;
  const int mrow = w * 16 + cb;  // A-fragment row
  const int jrow = nbr[(size_t)blk * KNB + (mrow < c ? mrow : c - 1)];
  const float* xrow = x1 + ((size_t)(b * 1024) + jrow) * 64;
  const float cx = pos2[(size_t)blk * 3 + 0];
  const float cy = pos2[(size_t)blk * 3 + 1];
  const float cz = pos2[(size_t)blk * 3 + 2];

  // ---------- L1: K=67 (pad 96, KS=3), N=128 ----------
  f32x4 acc1[8];
#pragma unroll
  for (int nt = 0; nt < 8; ++nt) acc1[nt] = (f32x4){0.f, 0.f, 0.f, 0.f};
#pragma unroll
  for (int ks = 0; ks < 2; ++ks) {
    float xv[8];
    *(float4*)&xv[0] = *(const float4*)&xrow[ks * 32 + kb * 8];
    *(float4*)&xv[4] = *(const float4*)&xrow[ks * 32 + kb * 8 + 4];
    bf16x8 ahi, alo;
    mkfrag(xv, ahi, alo);
#pragma unroll
    for (int nt = 0; nt < 8; ++nt) {
      size_t off = ((size_t)(nt * 3 + ks) * 64 + lane) * 8;
      bf16x8 bhi = *(const bf16x8*)(w0h + off);
      acc1[nt] = __builtin_amdgcn_mfma_f32_16x16x32_bf16(ahi, bhi, acc1[nt], 0, 0, 0);
      acc1[nt] = __builtin_amdgcn_mfma_f32_16x16x32_bf16(alo, bhi, acc1[nt], 0, 0, 0);
    }
  }
  {  // ks=2: k=64..66 = pos-diff (kb==0, e<3); weights zero-padded past 67
    float xv[8] = {0.f, 0.f, 0.f, 0.f, 0.f, 0.f, 0.f, 0.f};
    if (kb == 0) {
      xv[0] = pos1[((size_t)(b * 1024) + jrow) * 3 + 0] - cx;
      xv[1] = pos1[((size_t)(b * 1024) + jrow) * 3 + 1] - cy;
      xv[2] = pos1[((size_t)(b * 1024) + jrow) * 3 + 2] - cz;
    }
    bf16x8 ahi, alo;
    mkfrag(xv, ahi, alo);
#pragma unroll
    for (int nt = 0; nt < 8; ++nt) {
      size_t off = ((size_t)(nt * 3 + 2) * 64 + lane) * 8;
      bf16x8 bhi = *(const bf16x8*)(w0h + off);
      acc1[nt] = __builtin_amdgcn_mfma_f32_16x16x32_bf16(ahi, bhi, acc1[nt], 0, 0, 0);
      acc1[nt] = __builtin_amdgcn_mfma_f32_16x16x32_bf16(alo, bhi, acc1[nt], 0, 0, 0);
    }
  }
  {  // h1 = ReLU(acc1 + b0); C/D row = w*16 + kb*4 + r (same wave's slab)
    const int mw = w * 16 + kb * 4;
#pragma unroll
    for (int nt = 0; nt < 8; ++nt) {
      float bias = b0[nt * 16 + cb];
#pragma unroll
      for (int r = 0; r < 4; ++r)
        h1[mw + r][nt * 16 + cb] = fmaxf(acc1[nt][r] + bias, 0.f);
    }
  }

  // ---------- L2: K=128 (KS=4), N=128 ---------- (per-wave rows, no barrier)
  f32x4 acc2[8];
#pragma unroll
  for (int nt = 0; nt < 8; ++nt) acc2[nt] = (f32x4){0.f, 0.f, 0.f, 0.f};
#pragma unroll
  for (int ks = 0; ks < 4; ++ks) {
    bf16x8 ahi, alo;
    mkfrag(&h1[mrow][ks * 32 + kb * 8], ahi, alo);
#pragma unroll
    for (int nt = 0; nt < 8; ++nt) {
      size_t off = ((size_t)(nt * 4 + ks) * 64 + lane) * 8;
      bf16x8 bhi = *(const bf16x8*)(w1h + off);
      acc2[nt] = __builtin_amdgcn_mfma_f32_16x16x32_bf16(ahi, bhi, acc2[nt], 0, 0, 0);
      acc2[nt] = __builtin_amdgcn_mfma_f32_16x16x32_bf16(alo, bhi, acc2[nt], 0, 0, 0);
    }
  }
  {
    const int mw = w * 16 + kb * 4;
#pragma unroll
    for (int nt = 0; nt < 8; ++nt) {
      float bias = b1[nt * 16 + cb];
#pragma unroll
      for (int r = 0; r < 4; ++r)
        h2[mw + r][nt * 16 + cb] = fmaxf(acc2[nt][r] + bias, 0.f);
    }
  }

  // ---------- L3: K=128 (KS=4), N=256 ---------- (per-wave rows, no barrier)
  f32x4 acc3[16];
#pragma unroll
  for (int nt = 0; nt < 16; ++nt) acc3[nt] = (f32x4){0.f, 0.f, 0.f, 0.f};
#pragma unroll
  for (int ks = 0; ks < 4; ++ks) {
    bf16x8 ahi, alo;
    mkfrag(&h2[mrow][ks * 32 + kb * 8], ahi, alo);
#pragma unroll
    for (int nt = 0; nt < 16; ++nt) {
      size_t off = ((size_t)(nt * 4 + ks) * 64 + lane) * 8;
      bf16x8 bhi = *(const bf16x8*)(w2h + off);
      acc3[nt] = __builtin_amdgcn_mfma_f32_16x16x32_bf16(ahi, bhi, acc3[nt], 0, 0, 0);
      acc3[nt] = __builtin_amdgcn_mfma_f32_16x16x32_bf16(alo, bhi, acc3[nt], 0, 0, 0);
    }
  }
  __syncthreads();  // all h1 reads done before red (aliases h1)
  {
    const int mw = w * 16 + kb * 4;
#pragma unroll
    for (int nt = 0; nt < 16; ++nt) {
      float bias = b2[nt * 16 + cb];
      float mx = -__builtin_inff();
#pragma unroll
      for (int r = 0; r < 4; ++r) {
        if (mw + r < c) mx = fmaxf(mx, acc3[nt][r] + bias);
      }
      red[(w * 4 + kb) * 256 + nt * 16 + cb] = mx;
    }
  }
  __syncthreads();
  {
    float v = red[t];
#pragma unroll
    for (int g = 1; g < 16; ++g) v = fmaxf(v, red[g * 256 + t]);
    x2[(size_t)blk * 256 + t] = v;
  }
}

// ================= merged launch kernels ====================================

__global__ void __launch_bounds__(256) l1_kernel(
    const float* __restrict__ pos, float* __restrict__ pos1,
    const int* __restrict__ feat, const float* __restrict__ emb,
    const float* __restrict__ pid, float* __restrict__ x0buf) {
  __shared__ __attribute__((aligned(16))) char smem[81984];
  if (blockIdx.x < 8) {
    fps_body<4096, 1024, 256>(smem, pos, pos1, blockIdx.x, threadIdx.x);
  } else {
    x0_body(feat, emb, pid, x0buf, blockIdx.x - 8, threadIdx.x);
  }
}

__global__ void __launch_bounds__(256) l2_kernel(
    const float* __restrict__ pos1, float* __restrict__ pos2,
    const float* __restrict__ pos, float r2a, int* __restrict__ nbr1,
    int* __restrict__ cnt1) {
  __shared__ __attribute__((aligned(16))) char smem[33024];
  if (blockIdx.x < 8) {
    fps_body<1024, 256, 256>(smem, pos1, pos2, blockIdx.x, threadIdx.x);
  } else {
    radius_body<4096, 1024>(smem, pos, pos1, r2a, nbr1, cnt1, blockIdx.x - 8,
                            threadIdx.x);
  }
}

__global__ void __launch_bounds__(256) l3_kernel(
    const float* __restrict__ pos2, float* __restrict__ pos3, float r2b,
    int* __restrict__ nbr2, int* __restrict__ cnt2,
    const float* __restrict__ pos1, const float* __restrict__ x0buf,
    const float* __restrict__ pos, const int* __restrict__ nbr1,
    const int* __restrict__ cnt1, const float* __restrict__ w0,
    const float* __restrict__ b0, const float* __restrict__ w1,
    const float* __restrict__ b1, const float* __restrict__ w2,
    const float* __restrict__ b2, float* __restrict__ x1) {
  __shared__ __attribute__((aligned(16))) char smem[8448];
  if (blockIdx.x < 8) {
    if (threadIdx.x < 64)
      fps_body<256, 64, 64>(smem, pos2, pos3, blockIdx.x, threadIdx.x);
  } else if (blockIdx.x < 8 + 2048) {
    radius_body<1024, 256>(smem, pos1, pos2, r2b, nbr2, cnt2, blockIdx.x - 8,
                           threadIdx.x);
  } else {
    conv1_body(smem, x0buf, pos, pos1, nbr1, cnt1, w0, b0, w1, b1, w2, b2, x1,
               blockIdx.x - (8 + 2048), threadIdx.x);
  }
}

// L4: radius3 (blocks 0..511) || conv2-MFMA (blocks 512..2559)
__global__ void __launch_bounds__(256) l4_kernel(
    const float* __restrict__ pos2, const float* __restrict__ pos3, float r2c,
    int* __restrict__ nbr3, int* __restrict__ cnt3,
    const float* __restrict__ x1, const float* __restrict__ pos1,
    const int* __restrict__ nbr2, const int* __restrict__ cnt2,
    const unsigned short* __restrict__ v0h, const float* __restrict__ b0,
    const unsigned short* __restrict__ v1h, const float* __restrict__ b1,
    const unsigned short* __restrict__ v2h, const float* __restrict__ b2,
    float* __restrict__ x2) {
  __shared__ __attribute__((aligned(16))) char smem[67584];
  if (blockIdx.x < 512) {
    radius_body<256, 64>(smem, pos2, pos3, r2c, nbr3, cnt3, blockIdx.x,
                         threadIdx.x);
  } else {
    conv2_mfma_body(smem, x1, pos1, pos2, nbr2, cnt2, v0h, b0, v1h, b1, v2h,
                    b2, x2, blockIdx.x - 512, threadIdx.x);
  }
}

// ---------------- weight packing into MFMA-B fragment order -----------------
// B-fragment for mfma_f32_16x16x32_bf16: lane l holds col n = l&15,
// k = (l>>4)*8 + e (e=0..7). Packed: elem = ((nt*KS + ks)*64 + l)*8 + e
// where n = nt*16 + (l&15), k = ks*32 + (l>>4)*8 + e; k >= Kreal -> 0.
__global__ void __launch_bounds__(256) pack_kernel(
    const float* __restrict__ W, int Kreal, int KS, int N,
    unsigned short* __restrict__ hi, unsigned short* __restrict__ lo) {
  int gid = blockIdx.x * 256 + threadIdx.x;
  int total = (N / 16) * KS * 64 * 8;
  if (gid >= total) return;
  int e = gid & 7;
  int l = (gid >> 3) & 63;
  int rest = gid >> 9;
  int ks = rest % KS;
  int nt = rest / KS;
  int n = nt * 16 + (l & 15);
  int k = ks * 32 + (l >> 4) * 8 + e;
  float val = (k < Kreal) ? W[(size_t)k * N + n] : 0.f;
  unsigned short h = bfhi(val);
  float r = val - bf2f(h);
  hi[gid] = h;
  lo[gid] = bfhi(r);
}

// ---------------- stage 3 conv via split-bf16 MFMA (2-term, barrier-light) --
// One block per center; wave w owns rows [16w,16w+16) of every LDS tile ->
// no interior barriers. L1's A read straight from global x2 (L2-resident).
__global__ void __launch_bounds__(256) conv3_mfma(
    const float* __restrict__ x2, const float* __restrict__ pos2,
    const float* __restrict__ pos3, const int* __restrict__ nbr,
    const int* __restrict__ cntp,
    const unsigned short* __restrict__ w0h, const float* __restrict__ b0,
    const unsigned short* __restrict__ w1h, const float* __restrict__ b1,
    const unsigned short* __restrict__ w2h, const float* __restrict__ b2,
    float* __restrict__ out) {
  __shared__ __attribute__((aligned(16))) float h1s[64 * 268];   // K2=256 rows
  __shared__ __attribute__((aligned(16))) float h2cs[64 * 140];  // 128-col chunk
  const int blk = blockIdx.x;
  const int t = threadIdx.x;
  const int b = blk >> 6;
  const int c = cntp[blk];
  const int w = t >> 6;
  const int lane = t & 63;
  const int cb = lane & 15;
  const int kb = lane >> 4;
  const float cx = pos3[(size_t)blk * 3 + 0];
  const float cy = pos3[(size_t)blk * 3 + 1];
  const float cz = pos3[(size_t)blk * 3 + 2];
  const int mrow = w * 16 + cb;
  const int jrow = nbr[(size_t)blk * KNB + (mrow < c ? mrow : c - 1)];
  const float* xrow = x2 + ((size_t)(b * 256) + jrow) * 256;

  // ---------- L1: K=259 (pad 288, KS=9), N=256 ----------
  f32x4 acc1[16];
#pragma unroll
  for (int nt = 0; nt < 16; ++nt) acc1[nt] = (f32x4){0.f, 0.f, 0.f, 0.f};
#pragma unroll
  for (int ks = 0; ks < 8; ++ks) {
    float xv[8];
    *(float4*)&xv[0] = *(const float4*)&xrow[ks * 32 + kb * 8];
    *(float4*)&xv[4] = *(const float4*)&xrow[ks * 32 + kb * 8 + 4];
    bf16x8 ahi, alo;
    mkfrag(xv, ahi, alo);
#pragma unroll
    for (int nt = 0; nt < 16; ++nt) {
      size_t off = ((size_t)(nt * 9 + ks) * 64 + lane) * 8;
      bf16x8 bhi = *(const bf16x8*)(w0h + off);
      acc1[nt] = __builtin_amdgcn_mfma_f32_16x16x32_bf16(ahi, bhi, acc1[nt], 0, 0, 0);
      acc1[nt] = __builtin_amdgcn_mfma_f32_16x16x32_bf16(alo, bhi, acc1[nt], 0, 0, 0);
    }
  }
  {  // ks=8: k=256..258 pos-diff (kb==0, e<3); weights zero past 259
    float xv[8] = {0.f, 0.f, 0.f, 0.f, 0.f, 0.f, 0.f, 0.f};
    if (kb == 0) {
      xv[0] = pos2[((size_t)(b * 256) + jrow) * 3 + 0] - cx;
      xv[1] = pos2[((size_t)(b * 256) + jrow) * 3 + 1] - cy;
      xv[2] = pos2[((size_t)(b * 256) + jrow) * 3 + 2] - cz;
    }
    bf16x8 ahi, alo;
    mkfrag(xv, ahi, alo);
#pragma unroll
    for (int nt = 0; nt < 16; ++nt) {
      size_t off = ((size_t)(nt * 9 + 8) * 64 + lane) * 8;
      bf16x8 bhi = *(const bf16x8*)(w0h + off);
      acc1[nt] = __builtin_amdgcn_mfma_f32_16x16x32_bf16(ahi, bhi, acc1[nt], 0, 0, 0);
      acc1[nt] = __builtin_amdgcn_mfma_f32_16x16x32_bf16(alo, bhi, acc1[nt], 0, 0, 0);
    }
  }
  {  // h1 = ReLU(acc1 + b0); rows mw+r in this wave's slab
    const int mw = w * 16 + kb * 4;
#pragma unroll
    for (int nt = 0; nt < 16; ++nt) {
      float bias = b0[nt * 16 + cb];
#pragma unroll
      for (int r = 0; r < 4; ++r)
        h1s[(mw + r) * 268 + nt * 16 + cb] = fmaxf(acc1[nt][r] + bias, 0.f);
    }
  }

  // ---------- L2 (K=256, N=512 in 4 chunks) + L3 (K=512 streamed) ----------
  f32x4 acc3[32];
#pragma unroll
  for (int nt = 0; nt < 32; ++nt) acc3[nt] = (f32x4){0.f, 0.f, 0.f, 0.f};
  for (int ch = 0; ch < 4; ++ch) {
    f32x4 acc2[8];
#pragma unroll
    for (int nt = 0; nt < 8; ++nt) acc2[nt] = (f32x4){0.f, 0.f, 0.f, 0.f};
#pragma unroll
    for (int ks = 0; ks < 8; ++ks) {
      bf16x8 ahi, alo;
      mkfrag(&h1s[mrow * 268 + ks * 32 + kb * 8], ahi, alo);
#pragma unroll
      for (int nt = 0; nt < 8; ++nt) {
        size_t off = ((size_t)((ch * 8 + nt) * 8 + ks) * 64 + lane) * 8;
        bf16x8 bhi = *(const bf16x8*)(w1h + off);
        acc2[nt] = __builtin_amdgcn_mfma_f32_16x16x32_bf16(ahi, bhi, acc2[nt], 0, 0, 0);
        acc2[nt] = __builtin_amdgcn_mfma_f32_16x16x32_bf16(alo, bhi, acc2[nt], 0, 0, 0);
      }
    }
    {  // h2 chunk = ReLU(acc2 + b1); per-wave rows, no barrier
      const int mw = w * 16 + kb * 4;
#pragma unroll
      for (int nt = 0; nt < 8; ++nt) {
        float bias = b1[ch * 128 + nt * 16 + cb];
#pragma unroll
        for (int r = 0; r < 4; ++r)
          h2cs[(mw + r) * 140 + nt * 16 + cb] = fmaxf(acc2[nt][r] + bias, 0.f);
      }
    }
#pragma unroll
    for (int ks3 = 0; ks3 < 4; ++ks3) {
      bf16x8 ahi, alo;
      mkfrag(&h2cs[mrow * 140 + ks3 * 32 + kb * 8], ahi, alo);
#pragma unroll
      for (int nt = 0; nt < 32; ++nt) {
        size_t off = ((size_t)(nt * 16 + ch * 4 + ks3) * 64 + lane) * 8;
        bf16x8 bhi = *(const bf16x8*)(w2h + off);
        acc3[nt] = __builtin_amdgcn_mfma_f32_16x16x32_bf16(ahi, bhi, acc3[nt], 0, 0, 0);
        acc3[nt] = __builtin_amdgcn_mfma_f32_16x16x32_bf16(alo, bhi, acc3[nt], 0, 0, 0);
      }
    }
  }

  // ---------- bias + masked row-max ----------
  __syncthreads();  // all h1s reads done before alias reuse
  float* redw = h1s;  // need 16*512 floats
  {
    const int mw = w * 16 + kb * 4;
#pragma unroll
    for (int nt = 0; nt < 32; ++nt) {
      float bias = b2[nt * 16 + cb];
      float mx = -__builtin_inff();
#pragma unroll
      for (int r = 0; r < 4; ++r) {
        if (mw + r < c) mx = fmaxf(mx, acc3[nt][r] + bias);
      }
      redw[(w * 4 + kb) * 512 + nt * 16 + cb] = mx;
    }
  }
  __syncthreads();
#pragma unroll
  for (int half = 0; half < 2; ++half) {
    int col = t + half * 256;
    float v = redw[col];
#pragma unroll
    for (int g = 1; g < 16; ++g) v = fmaxf(v, redw[g * 512 + col]);
    out[(size_t)blk * 512 + col] = v;
  }
}

extern "C" void kernel_launch(void* const* d_in, const int* in_sizes, int n_in,
                              void* d_out, int out_size, void* d_ws, size_t ws_size,
                              hipStream_t stream) {
  const int* feat = (const int*)d_in[0];
  const float* pos = (const float*)d_in[1];
  const float* emb = (const float*)d_in[2];
  const float* pid = (const float*)d_in[3];
  const float* s1w0 = (const float*)d_in[4];
  const float* s1b0 = (const float*)d_in[5];
  const float* s1w1 = (const float*)d_in[6];
  const float* s1b1 = (const float*)d_in[7];
  const float* s1w2 = (const float*)d_in[8];
  const float* s1b2 = (const float*)d_in[9];
  const float* s2w0 = (const float*)d_in[10];
  const float* s2b0 = (const float*)d_in[11];
  const float* s2w1 = (const float*)d_in[12];
  const float* s2b1 = (const float*)d_in[13];
  const float* s2w2 = (const float*)d_in[14];
  const float* s2b2 = (const float*)d_in[15];
  const float* s3w0 = (const float*)d_in[16];
  const float* s3b0 = (const float*)d_in[17];
  const float* s3w1 = (const float*)d_in[18];
  const float* s3b1 = (const float*)d_in[19];
  const float* s3w2 = (const float*)d_in[20];
  const float* s3b2 = (const float*)d_in[21];
  (void)in_sizes; (void)n_in; (void)out_size; (void)ws_size;

  char* ws = (char*)d_ws;
  size_t off = 0;
  auto alloc = [&](size_t nbytes) {
    void* p = ws + off;
    off = (off + nbytes + 255) & ~(size_t)255;
    return p;
  };
  float* x0 = (float*)alloc((size_t)B * N0 * 32 * 4);
  float* pos1 = (float*)alloc((size_t)B * 1024 * 3 * 4);
  int* nbr1 = (int*)alloc((size_t)B * 1024 * KNB * 4);
  int* cnt1 = (int*)alloc((size_t)B * 1024 * 4);
  float* x1 = (float*)alloc((size_t)B * 1024 * 64 * 4);
  float* pos2 = (float*)alloc((size_t)B * 256 * 3 * 4);
  int* nbr2 = (int*)alloc((size_t)B * 256 * KNB * 4);
  int* cnt2 = (int*)alloc((size_t)B * 256 * 4);
  float* x2 = (float*)alloc((size_t)B * 256 * 256 * 4);
  int* nbr3 = (int*)alloc((size_t)B * 64 * KNB * 4);
  int* cnt3 = (int*)alloc((size_t)B * 64 * 4);
  // packed split-bf16 weights (hi used; lo kept for conv3/conv2 packing calls)
  const int T0 = 16 * 9 * 64 * 8;
  const int T1 = 32 * 8 * 64 * 8;
  const int T2 = 32 * 16 * 64 * 8;
  unsigned short* w0h = (unsigned short*)alloc((size_t)T0 * 2);
  unsigned short* w0l = (unsigned short*)alloc((size_t)T0 * 2);
  unsigned short* w1h = (unsigned short*)alloc((size_t)T1 * 2);
  unsigned short* w1l = (unsigned short*)alloc((size_t)T1 * 2);
  unsigned short* w2h = (unsigned short*)alloc((size_t)T2 * 2);
  unsigned short* w2l = (unsigned short*)alloc((size_t)T2 * 2);
  const int U0 = 8 * 3 * 64 * 8;
  const int U1 = 8 * 4 * 64 * 8;
  const int U2 = 16 * 4 * 64 * 8;
  unsigned short* v0h = (unsigned short*)alloc((size_t)U0 * 2);
  unsigned short* v0l = (unsigned short*)alloc((size_t)U0 * 2);
  unsigned short* v1h = (unsigned short*)alloc((size_t)U1 * 2);
  unsigned short* v1l = (unsigned short*)alloc((size_t)U1 * 2);
  unsigned short* v2h = (unsigned short*)alloc((size_t)U2 * 2);
  unsigned short* v2l = (unsigned short*)alloc((size_t)U2 * 2);

  float* xout = (float*)d_out;                 // (B,64,512)
  float* pos3 = xout + (size_t)B * 64 * 512;   // (B,64,3)

  const float r2a = (float)(0.05 * 0.05);
  const float r2b = (float)(0.3 * 0.3);
  const float r2c = (float)(0.5 * 0.5);

  pack_kernel<<<(T0 + 255) / 256, 256, 0, stream>>>(s3w0, 259, 9, 256, w0h, w0l);
  pack_kernel<<<(T1 + 255) / 256, 256, 0, stream>>>(s3w1, 256, 8, 512, w1h, w1l);
  pack_kernel<<<(T2 + 255) / 256, 256, 0, stream>>>(s3w2, 512, 16, 512, w2h, w2l);
  pack_kernel<<<(U0 + 255) / 256, 256, 0, stream>>>(s2w0, 67, 3, 128, v0h, v0l);
  pack_kernel<<<(U1 + 255) / 256, 256, 0, stream>>>(s2w1, 128, 4, 128, v1h, v1l);
  pack_kernel<<<(U2 + 255) / 256, 256, 0, stream>>>(s2w2, 128, 4, 256, v2h, v2l);

  l1_kernel<<<8 + 4096, 256, 0, stream>>>(pos, pos1, feat, emb, pid, x0);
  l2_kernel<<<8 + 8192, 256, 0, stream>>>(pos1, pos2, pos, r2a, nbr1, cnt1);
  l3_kernel<<<8 + 2048 + 8192, 256, 0, stream>>>(
      pos2, pos3, r2b, nbr2, cnt2, pos1, x0, pos, nbr1, cnt1,
      s1w0, s1b0, s1w1, s1b1, s1w2, s1b2, x1);
  l4_kernel<<<512 + 2048, 256, 0, stream>>>(
      pos2, pos3, r2c, nbr3, cnt3, x1, pos1, nbr2, cnt2,
      v0h, s2b0, v1h, s2b1, v2h, s2b2, x2);
  conv3_mfma<<<B * 64, 256, 0, stream>>>(x2, pos2, pos3, nbr3, cnt3,
                                         w0h, s3b0, w1h, s3b1, w2h, s3b2, xout);
}

// Round 11
// 1247.744 us; speedup vs baseline: 1.2363x; 1.0256x over previous
//
#include <hip/hip_runtime.h>

#define DEVI static __device__ __forceinline__

constexpr int B = 8;
constexpr int N0 = 4096;
constexpr int KNB = 64;

typedef float f32x2 __attribute__((ext_vector_type(2)));
typedef float f32x4 __attribute__((ext_vector_type(4)));
typedef short bf16x8 __attribute__((ext_vector_type(8)));

// d2 exactly as numpy: ((dx*dx + dy*dy) + dz*dz), no FMA contraction.
DEVI float dist2f(float ax, float ay, float az, float bx, float by, float bz) {
#pragma clang fp contract(off)
  float dx = ax - bx;
  float dy = ay - by;
  float dz = az - bz;
  return (dx * dx + dy * dy) + dz * dz;
}
DEVI f32x2 dist2v(f32x2 ax, f32x2 ay, f32x2 az, float bx, float by, float bz) {
#pragma clang fp contract(off)
  f32x2 dx = ax - bx;
  f32x2 dy = ay - by;
  f32x2 dz = az - bz;
  return (dx * dx + dy * dy) + dz * dz;
}

DEVI unsigned long long packMinKey(float v, int i) {
  return ((unsigned long long)__float_as_uint(v) << 32) | (unsigned int)i;
}

// ---- u64 max wave-64 reduction on the VALU pipe (DPP), broadcast via
// readlane(63). old=self, bound_ctrl off -> shifted-in lanes keep own key
// (no-op in max combine). Proven bit-exact in R3.
template <int CTRL, int RM>
DEVI unsigned long long dppMaxU64(unsigned long long k) {
  unsigned lo = (unsigned)k, hi = (unsigned)(k >> 32);
  unsigned mlo = (unsigned)__builtin_amdgcn_update_dpp((int)lo, (int)lo, CTRL, RM, 0xf, false);
  unsigned mhi = (unsigned)__builtin_amdgcn_update_dpp((int)hi, (int)hi, CTRL, RM, 0xf, false);
  unsigned long long o = ((unsigned long long)mhi << 32) | mlo;
  return (k > o) ? k : o;
}
DEVI unsigned long long waveReduceMaxU64(unsigned long long k) {
  k = dppMaxU64<0x111, 0xf>(k);  // row_shr:1
  k = dppMaxU64<0x112, 0xf>(k);  // row_shr:2
  k = dppMaxU64<0x114, 0xf>(k);  // row_shr:4
  k = dppMaxU64<0x118, 0xf>(k);  // row_shr:8
  k = dppMaxU64<0x142, 0xa>(k);  // row_bcast:15 -> rows 1,3
  k = dppMaxU64<0x143, 0xc>(k);  // row_bcast:31 -> rows 2,3
  unsigned lo = (unsigned)__builtin_amdgcn_readlane((int)(unsigned)k, 63);
  unsigned hi = (unsigned)__builtin_amdgcn_readlane((int)(unsigned)(k >> 32), 63);
  return ((unsigned long long)hi << 32) | lo;
}

// ---- bf16 split helpers (RNE) ----
DEVI unsigned short bfhi(float x) {
  unsigned u = __float_as_uint(x);
  return (unsigned short)((u + 0x7FFFu + ((u >> 16) & 1u)) >> 16);
}
DEVI float bf2f(unsigned short h) { return __uint_as_float(((unsigned)h) << 16); }
DEVI void mkfrag(const float* p, bf16x8& hi, bf16x8& lo) {
#pragma unroll
  for (int e = 0; e < 8; ++e) {
    float x = p[e];
    unsigned short h = bfhi(x);
    float r = x - bf2f(h);
    unsigned short l2 = bfhi(r);
    hi[e] = (short)h;
    lo[e] = (short)l2;
  }
}

// ================= device bodies ======

DEVI void x0_body(const int* __restrict__ feat, const float* __restrict__ emb,
                  const float* __restrict__ pid, float* __restrict__ x0buf,
                  int bx, int t) {
  int gid = bx * 256 + t;
  if (gid >= B * N0 * 32) return;
  int c = gid & 31;
  int bn = gid >> 5;
  int n = bn & (N0 - 1);
  int f = feat[bn];
  float v = emb[f * 32 + c];
  if (n < 1024) v += pid[n * 32 + c];
  x0buf[gid] = v;
}

// ---- weight packing into MFMA-B fragment order (body form) ----
// B-fragment: lane l holds col n = l&15, k = (l>>4)*8+e. Packed:
// elem = ((nt*KS+ks)*64+l)*8+e; k >= Kreal -> 0.
DEVI void pack_body(int gid, const float* __restrict__ W, int Kreal, int KS,
                    int N, unsigned short* __restrict__ hi,
                    unsigned short* __restrict__ lo) {
  int e = gid & 7;
  int l = (gid >> 3) & 63;
  int rest = gid >> 9;
  int ks = rest % KS;
  int nt = rest / KS;
  int n = nt * 16 + (l & 15);
  int k = ks * 32 + (l >> 4) * 8 + e;
  float val = (k < Kreal) ? W[(size_t)k * N + n] : 0.f;
  unsigned short h = bfhi(val);
  float r = val - bf2f(h);
  hi[gid] = h;
  lo[gid] = bfhi(r);
}

// ---- farthest point sampling (selection semantics == jnp.argmax) ----
// Single-phase: per-lane (lane-max, in-lane lowest idx) packed into one u64
// key (inverted idx low word: max key == max d2, ties -> lowest idx), one
// 6-level u64 DPP wave reduce; cross-wave via 1 leader-write + 1 barrier.
template <int NPTS, int M, int BLK>
DEVI void fps_body(char* smem, const float* __restrict__ pos,
                   float* __restrict__ pos_out, int b, int t) {
  constexpr int EPT = NPTS / BLK;
  constexpr int EP2 = EPT / 2;
  constexpr int NW = BLK / 64;
  float4* posl = (float4*)smem;
  float4* outp = (float4*)(smem + (size_t)NPTS * 16);
  unsigned long long* redk =
      (unsigned long long*)(smem + (size_t)(NPTS + M) * 16);  // [2][NW]
  const float* pb = pos + (size_t)b * NPTS * 3;
  f32x2 px[EP2], py[EP2], pz[EP2], d[EP2];
#pragma unroll
  for (int e = 0; e < EP2; ++e) {
    int i0 = t + (2 * e) * BLK;
    int i1 = t + (2 * e + 1) * BLK;
    float x0 = pb[i0 * 3 + 0], y0 = pb[i0 * 3 + 1], z0 = pb[i0 * 3 + 2];
    float x1 = pb[i1 * 3 + 0], y1 = pb[i1 * 3 + 1], z1 = pb[i1 * 3 + 2];
    px[e] = (f32x2){x0, x1};
    py[e] = (f32x2){y0, y1};
    pz[e] = (f32x2){z0, z1};
    posl[i0] = make_float4(x0, y0, z0, 0.f);
    posl[i1] = make_float4(x1, y1, z1, 0.f);
  }
  float sx = pb[0], sy = pb[1], sz = pb[2];
  if (t == 0) outp[0] = make_float4(sx, sy, sz, 0.f);
  f32x2 m2 = (f32x2){-1.f, -1.f};
#pragma unroll
  for (int e = 0; e < EP2; ++e) {
    d[e] = dist2v(px[e], py[e], pz[e], sx, sy, sz);
    m2.x = fmaxf(m2.x, d[e].x);
    m2.y = fmaxf(m2.y, d[e].y);
  }
  for (int it = 1; it < M; ++it) {
    const float lm = fmaxf(m2.x, m2.y);  // this lane's max (>=1 match below)
    // in-lane lowest index attaining lm (tree min)
    unsigned cand = 0xffffffffu;
#pragma unroll
    for (int e = 0; e < EP2; ++e) {
      unsigned c0 = (d[e].x == lm) ? (unsigned)(t + (2 * e) * BLK) : 0xffffffffu;
      unsigned c1 = (d[e].y == lm) ? (unsigned)(t + (2 * e + 1) * BLK) : 0xffffffffu;
      unsigned cc = c0 < c1 ? c0 : c1;
      cand = cand < cc ? cand : cc;
    }
    unsigned long long k =
        ((unsigned long long)__float_as_uint(lm) << 32) |
        (unsigned)(0x7fffffffu - cand);
    k = waveReduceMaxU64(k);
    unsigned sel;
    if constexpr (NW > 1) {
      if ((t & 63) == 0) redk[(it & 1) * NW + (t >> 6)] = k;
      __syncthreads();  // double-buffered -> single barrier is race-free
      unsigned long long kk = redk[(it & 1) * NW + 0];
#pragma unroll
      for (int w = 1; w < NW; ++w) {
        unsigned long long o = redk[(it & 1) * NW + w];
        kk = (kk > o) ? kk : o;
      }
      sel = 0x7fffffffu - (unsigned)(kk & 0xffffffffULL);
    } else {
      sel = 0x7fffffffu - (unsigned)(k & 0xffffffffULL);
    }
    float4 sp = posl[sel];  // LDS broadcast
    if (t == 0) outp[it] = sp;
    f32x2 mm = (f32x2){-1.f, -1.f};
#pragma unroll
    for (int e = 0; e < EP2; ++e) {
      f32x2 nd = dist2v(px[e], py[e], pz[e], sp.x, sp.y, sp.z);
      d[e].x = fminf(d[e].x, nd.x);
      d[e].y = fminf(d[e].y, nd.y);
      mm.x = fmaxf(mm.x, d[e].x);
      mm.y = fmaxf(mm.y, d[e].y);
    }
    m2 = mm;
  }
  if constexpr (NW > 1) __syncthreads();
  for (int m = t; m < M; m += BLK) {
    float4 q = outp[m];
    pos_out[(size_t)(b * M + m) * 3 + 0] = q.x;
    pos_out[(size_t)(b * M + m) * 3 + 1] = q.y;
    pos_out[(size_t)(b * M + m) * 3 + 2] = q.z;
  }
}

// ---- radius neighbors (<=64 nearest within r), rank-select overflow ----
template <int NPTS, int M>
DEVI void radius_body(char* smem, const float* __restrict__ pos,
                      const float* __restrict__ pos_s, float r2,
                      int* __restrict__ nbr, int* __restrict__ cnt, int blk,
                      int t) {
  unsigned long long* candkey = (unsigned long long*)smem;
  int* ctrp = (int*)(smem + (size_t)NPTS * 8);
  const int b = blk / M;
  const float* pb = pos + (size_t)b * NPTS * 3;
  const float cx = pos_s[(size_t)blk * 3 + 0];
  const float cy = pos_s[(size_t)blk * 3 + 1];
  const float cz = pos_s[(size_t)blk * 3 + 2];
  if (t == 0) *ctrp = 0;
  __syncthreads();
  for (int j = t; j < NPTS; j += 256) {
    float d2 = dist2f(pb[j * 3 + 0], pb[j * 3 + 1], pb[j * 3 + 2], cx, cy, cz);
    if (d2 <= r2) {
      int p = atomicAdd(ctrp, 1);
      candkey[p] = packMinKey(d2, j);
      if (p < KNB) nbr[(size_t)blk * KNB + p] = j;
    }
  }
  __syncthreads();
  const int c = *ctrp;
  if (c <= KNB) {
    if (t == 0) cnt[blk] = c;
    return;
  }
  for (int s = t; s < c; s += 256) {
    unsigned long long mykey = candkey[s];
    int rank = 0;
#pragma unroll 4
    for (int j = 0; j < c; ++j) {
      rank += (candkey[j] < mykey) ? 1 : 0;
    }
    if (rank < KNB)
      nbr[(size_t)blk * KNB + rank] = (int)(unsigned)(mykey & 0xffffffffULL);
  }
  if (t == 0) cnt[blk] = KNB;
}

// ---- stage 1 conv: 35 -> 64 -> 64 -> 64, max over nbrs (4 slots x 64ch) ----
DEVI void conv1_body(char* smem, const float* __restrict__ x0buf,
                     const float* __restrict__ pos,
                     const float* __restrict__ pos_s,
                     const int* __restrict__ nbr, const int* __restrict__ cntp,
                     const float* __restrict__ w0, const float* __restrict__ b0,
                     const float* __restrict__ w1, const float* __restrict__ b1,
                     const float* __restrict__ w2, const float* __restrict__ b2,
                     float* __restrict__ x1, int blk, int t) {
  float(*ins)[36] = (float(*)[36])smem;
  float(*hh)[65] = (float(*)[65])(smem + 576);
  float(*sred)[65] = (float(*)[65])(smem + 1616);
  const int slot = t >> 6;
  const int ch = t & 63;
  const int b = blk >> 10;
  const int c = cntp[blk];
  const float cx = pos_s[(size_t)blk * 3 + 0];
  const float cy = pos_s[(size_t)blk * 3 + 1];
  const float cz = pos_s[(size_t)blk * 3 + 2];
  float best = -__builtin_inff();
  for (int r0 = 0; r0 < c; r0 += 4) {
    const int r = r0 + slot;
    const bool act = r < c;
    const int j = nbr[(size_t)blk * KNB + (act ? r : 0)];
    if (ch < 32) {
      ins[slot][ch] = x0buf[((size_t)(b * N0) + j) * 32 + ch];
    } else if (ch < 35) {
      float pv = pos[((size_t)(b * N0) + j) * 3 + (ch - 32)];
      float cv = (ch == 32) ? cx : (ch == 33) ? cy : cz;
      ins[slot][ch] = pv - cv;
    }
    __syncthreads();
    float v = b0[ch];
#pragma unroll
    for (int i = 0; i < 35; ++i) v = fmaf(ins[slot][i], w0[i * 64 + ch], v);
    v = fmaxf(v, 0.f);
    hh[slot][ch] = v;
    __syncthreads();
    float v2 = b1[ch];
#pragma unroll
    for (int i = 0; i < 64; ++i) v2 = fmaf(hh[slot][i], w1[i * 64 + ch], v2);
    v2 = fmaxf(v2, 0.f);
    __syncthreads();
    hh[slot][ch] = v2;
    __syncthreads();
    float v3 = b2[ch];
#pragma unroll
    for (int i = 0; i < 64; ++i) v3 = fmaf(hh[slot][i], w2[i * 64 + ch], v3);
    if (act) best = fmaxf(best, v3);
    __syncthreads();
  }
  sred[slot][ch] = best;
  __syncthreads();
  if (t < 64) {
    float v = sred[0][t];
#pragma unroll
    for (int s = 1; s < 4; ++s) v = fmaxf(v, sred[s][t]);
    x1[(size_t)blk * 64 + t] = v;
  }
}

// ---- stage 2 conv via split-bf16 MFMA: 67 -> 128 -> 128 -> 256 ----
DEVI void conv2_mfma_body(char* smem, const float* __restrict__ x1,
                          const float* __restrict__ pos1,
                          const float* __restrict__ pos2,
                          const int* __restrict__ nbr,
                          const int* __restrict__ cntp,
                          const unsigned short* __restrict__ w0h,
                          const float* __restrict__ b0,
                          const unsigned short* __restrict__ w1h,
                          const float* __restrict__ b1,
                          const unsigned short* __restrict__ w2h,
                          const float* __restrict__ b2,
                          float* __restrict__ x2, int blk, int t) {
  float(*h1)[132] = (float(*)[132])smem;
  float(*h2)[132] = (float(*)[132])(smem + 33792);
  float* red = (float*)smem;  // alias h1 (dead after L2 reads)
  const int b = blk >> 8;
  const int c = cntp[blk];
  const int w = t >> 6;
  const int lane = t & 63;
  const int cb = lane & 15;
  const int kb = lane >> 4;
  const int mrow = w * 16 + cb;  // A-fragment row
  const int jrow = nbr[(size_t)blk * KNB + (mrow < c ? mrow : c - 1)];
  const float* xrow = x1 + ((size_t)(b * 1024) + jrow) * 64;
  const float cx = pos2[(size_t)blk * 3 + 0];
  const float cy = pos2[(size_t)blk * 3 + 1];
  const float cz = pos2[(size_t)blk * 3 + 2];

  // ---------- L1: K=67 (pad 96, KS=3), N=128 ----------
  f32x4 acc1[8];
#pragma unroll
  for (int nt = 0; nt < 8; ++nt) acc1[nt] = (f32x4){0.f, 0.f, 0.f, 0.f};
#pragma unroll
  for (int ks = 0; ks < 2; ++ks) {
    float xv[8];
    *(float4*)&xv[0] = *(const float4*)&xrow[ks * 32 + kb * 8];
    *(float4*)&xv[4] = *(const float4*)&xrow[ks * 32 + kb * 8 + 4];
    bf16x8 ahi, alo;
    mkfrag(xv, ahi, alo);
#pragma unroll
    for (int nt = 0; nt < 8; ++nt) {
      size_t off = ((size_t)(nt * 3 + ks) * 64 + lane) * 8;
      bf16x8 bhi = *(const bf16x8*)(w0h + off);
      acc1[nt] = __builtin_amdgcn_mfma_f32_16x16x32_bf16(ahi, bhi, acc1[nt], 0, 0, 0);
      acc1[nt] = __builtin_amdgcn_mfma_f32_16x16x32_bf16(alo, bhi, acc1[nt], 0, 0, 0);
    }
  }
  {  // ks=2: k=64..66 = pos-diff (kb==0, e<3); weights zero-padded past 67
    float xv[8] = {0.f, 0.f, 0.f, 0.f, 0.f, 0.f, 0.f, 0.f};
    if (kb == 0) {
      xv[0] = pos1[((size_t)(b * 1024) + jrow) * 3 + 0] - cx;
      xv[1] = pos1[((size_t)(b * 1024) + jrow) * 3 + 1] - cy;
      xv[2] = pos1[((size_t)(b * 1024) + jrow) * 3 + 2] - cz;
    }
    bf16x8 ahi, alo;
    mkfrag(xv, ahi, alo);
#pragma unroll
    for (int nt = 0; nt < 8; ++nt) {
      size_t off = ((size_t)(nt * 3 + 2) * 64 + lane) * 8;
      bf16x8 bhi = *(const bf16x8*)(w0h + off);
      acc1[nt] = __builtin_amdgcn_mfma_f32_16x16x32_bf16(ahi, bhi, acc1[nt], 0, 0, 0);
      acc1[nt] = __builtin_amdgcn_mfma_f32_16x16x32_bf16(alo, bhi, acc1[nt], 0, 0, 0);
    }
  }
  {
    const int mw = w * 16 + kb * 4;
#pragma unroll
    for (int nt = 0; nt < 8; ++nt) {
      float bias = b0[nt * 16 + cb];
#pragma unroll
      for (int r = 0; r < 4; ++r)
        h1[mw + r][nt * 16 + cb] = fmaxf(acc1[nt][r] + bias, 0.f);
    }
  }

  // ---------- L2: K=128 (KS=4), N=128 ---------- (per-wave rows, no barrier)
  f32x4 acc2[8];
#pragma unroll
  for (int nt = 0; nt < 8; ++nt) acc2[nt] = (f32x4){0.f, 0.f, 0.f, 0.f};
#pragma unroll
  for (int ks = 0; ks < 4; ++ks) {
    bf16x8 ahi, alo;
    mkfrag(&h1[mrow][ks * 32 + kb * 8], ahi, alo);
#pragma unroll
    for (int nt = 0; nt < 8; ++nt) {
      size_t off = ((size_t)(nt * 4 + ks) * 64 + lane) * 8;
      bf16x8 bhi = *(const bf16x8*)(w1h + off);
      acc2[nt] = __builtin_amdgcn_mfma_f32_16x16x32_bf16(ahi, bhi, acc2[nt], 0, 0, 0);
      acc2[nt] = __builtin_amdgcn_mfma_f32_16x16x32_bf16(alo, bhi, acc2[nt], 0, 0, 0);
    }
  }
  {
    const int mw = w * 16 + kb * 4;
#pragma unroll
    for (int nt = 0; nt < 8; ++nt) {
      float bias = b1[nt * 16 + cb];
#pragma unroll
      for (int r = 0; r < 4; ++r)
        h2[mw + r][nt * 16 + cb] = fmaxf(acc2[nt][r] + bias, 0.f);
    }
  }

  // ---------- L3: K=128 (KS=4), N=256 ---------- (per-wave rows, no barrier)
  f32x4 acc3[16];
#pragma unroll
  for (int nt = 0; nt < 16; ++nt) acc3[nt] = (f32x4){0.f, 0.f, 0.f, 0.f};
#pragma unroll
  for (int ks = 0; ks < 4; ++ks) {
    bf16x8 ahi, alo;
    mkfrag(&h2[mrow][ks * 32 + kb * 8], ahi, alo);
#pragma unroll
    for (int nt = 0; nt < 16; ++nt) {
      size_t off = ((size_t)(nt * 4 + ks) * 64 + lane) * 8;
      bf16x8 bhi = *(const bf16x8*)(w2h + off);
      acc3[nt] = __builtin_amdgcn_mfma_f32_16x16x32_bf16(ahi, bhi, acc3[nt], 0, 0, 0);
      acc3[nt] = __builtin_amdgcn_mfma_f32_16x16x32_bf16(alo, bhi, acc3[nt], 0, 0, 0);
    }
  }
  __syncthreads();  // all h1 reads done before red (aliases h1)
  {
    const int mw = w * 16 + kb * 4;
#pragma unroll
    for (int nt = 0; nt < 16; ++nt) {
      float bias = b2[nt * 16 + cb];
      float mx = -__builtin_inff();
#pragma unroll
      for (int r = 0; r < 4; ++r) {
        if (mw + r < c) mx = fmaxf(mx, acc3[nt][r] + bias);
      }
      red[(w * 4 + kb) * 256 + nt * 16 + cb] = mx;
    }
  }
  __syncthreads();
  {
    float v = red[t];
#pragma unroll
    for (int g = 1; g < 16; ++g) v = fmaxf(v, red[g * 256 + t]);
    x2[(size_t)blk * 256 + t] = v;
  }
}

// ================= merged launch kernels ====================================

constexpr int PK_T0 = 16 * 9 * 64 * 8;   // conv3 L1
constexpr int PK_T1 = 32 * 8 * 64 * 8;   // conv3 L2
constexpr int PK_T2 = 32 * 16 * 64 * 8;  // conv3 L3
constexpr int PK_U0 = 8 * 3 * 64 * 8;    // conv2 L1
constexpr int PK_U1 = 8 * 4 * 64 * 8;    // conv2 L2
constexpr int PK_U2 = 16 * 4 * 64 * 8;   // conv2 L3
constexpr int PK_TOTAL = PK_T0 + PK_T1 + PK_T2 + PK_U0 + PK_U1 + PK_U2;  // 528384
constexpr int PK_BLOCKS = PK_TOTAL / 256;  // 2064

// L1: fps1 (0..7) || x0 (8..4103) || weight packing (4104..4104+2064)
__global__ void __launch_bounds__(256) l1_kernel(
    const float* __restrict__ pos, float* __restrict__ pos1,
    const int* __restrict__ feat, const float* __restrict__ emb,
    const float* __restrict__ pid, float* __restrict__ x0buf,
    const float* __restrict__ s3w0, const float* __restrict__ s3w1,
    const float* __restrict__ s3w2, const float* __restrict__ s2w0,
    const float* __restrict__ s2w1, const float* __restrict__ s2w2,
    unsigned short* __restrict__ w0h, unsigned short* __restrict__ w0l,
    unsigned short* __restrict__ w1h, unsigned short* __restrict__ w1l,
    unsigned short* __restrict__ w2h, unsigned short* __restrict__ w2l,
    unsigned short* __restrict__ v0h, unsigned short* __restrict__ v0l,
    unsigned short* __restrict__ v1h, unsigned short* __restrict__ v1l,
    unsigned short* __restrict__ v2h, unsigned short* __restrict__ v2l) {
  __shared__ __attribute__((aligned(16))) char smem[81984];
  int bx = blockIdx.x;
  if (bx < 8) {
    fps_body<4096, 1024, 256>(smem, pos, pos1, bx, threadIdx.x);
    return;
  }
  bx -= 8;
  if (bx < 4096) {
    x0_body(feat, emb, pid, x0buf, bx, threadIdx.x);
    return;
  }
  bx -= 4096;
  int gid = bx * 256 + threadIdx.x;
  if (gid < PK_T0) { pack_body(gid, s3w0, 259, 9, 256, w0h, w0l); return; }
  gid -= PK_T0;
  if (gid < PK_T1) { pack_body(gid, s3w1, 256, 8, 512, w1h, w1l); return; }
  gid -= PK_T1;
  if (gid < PK_T2) { pack_body(gid, s3w2, 512, 16, 512, w2h, w2l); return; }
  gid -= PK_T2;
  if (gid < PK_U0) { pack_body(gid, s2w0, 67, 3, 128, v0h, v0l); return; }
  gid -= PK_U0;
  if (gid < PK_U1) { pack_body(gid, s2w1, 128, 4, 128, v1h, v1l); return; }
  gid -= PK_U1;
  if (gid < PK_U2) { pack_body(gid, s2w2, 128, 4, 256, v2h, v2l); return; }
}

// L2: fps2 single-wave (blocks 0..7) || radius1 (blocks 8..8199)
__global__ void __launch_bounds__(256) l2_kernel(
    const float* __restrict__ pos1, float* __restrict__ pos2,
    const float* __restrict__ pos, float r2a, int* __restrict__ nbr1,
    int* __restrict__ cnt1) {
  __shared__ __attribute__((aligned(16))) char smem[33024];
  if (blockIdx.x < 8) {
    if (threadIdx.x < 64)
      fps_body<1024, 256, 64>(smem, pos1, pos2, blockIdx.x, threadIdx.x);
  } else {
    radius_body<4096, 1024>(smem, pos, pos1, r2a, nbr1, cnt1, blockIdx.x - 8,
                            threadIdx.x);
  }
}

// L3: fps3 (blocks 0..7, wave0 only) || radius2 (8..2055) || conv1 (2056..10247)
__global__ void __launch_bounds__(256) l3_kernel(
    const float* __restrict__ pos2, float* __restrict__ pos3, float r2b,
    int* __restrict__ nbr2, int* __restrict__ cnt2,
    const float* __restrict__ pos1, const float* __restrict__ x0buf,
    const float* __restrict__ pos, const int* __restrict__ nbr1,
    const int* __restrict__ cnt1, const float* __restrict__ w0,
    const float* __restrict__ b0, const float* __restrict__ w1,
    const float* __restrict__ b1, const float* __restrict__ w2,
    const float* __restrict__ b2, float* __restrict__ x1) {
  __shared__ __attribute__((aligned(16))) char smem[8448];
  if (blockIdx.x < 8) {
    if (threadIdx.x < 64)
      fps_body<256, 64, 64>(smem, pos2, pos3, blockIdx.x, threadIdx.x);
  } else if (blockIdx.x < 8 + 2048) {
    radius_body<1024, 256>(smem, pos1, pos2, r2b, nbr2, cnt2, blockIdx.x - 8,
                           threadIdx.x);
  } else {
    conv1_body(smem, x0buf, pos, pos1, nbr1, cnt1, w0, b0, w1, b1, w2, b2, x1,
               blockIdx.x - (8 + 2048), threadIdx.x);
  }
}

// L4: radius3 (blocks 0..511) || conv2-MFMA (blocks 512..2559)
__global__ void __launch_bounds__(256) l4_kernel(
    const float* __restrict__ pos2, const float* __restrict__ pos3, float r2c,
    int* __restrict__ nbr3, int* __restrict__ cnt3,
    const float* __restrict__ x1, const float* __restrict__ pos1,
    const int* __restrict__ nbr2, const int* __restrict__ cnt2,
    const unsigned short* __restrict__ v0h, const float* __restrict__ b0,
    const unsigned short* __restrict__ v1h, const float* __restrict__ b1,
    const unsigned short* __restrict__ v2h, const float* __restrict__ b2,
    float* __restrict__ x2) {
  __shared__ __attribute__((aligned(16))) char smem[67584];
  if (blockIdx.x < 512) {
    radius_body<256, 64>(smem, pos2, pos3, r2c, nbr3, cnt3, blockIdx.x,
                         threadIdx.x);
  } else {
    conv2_mfma_body(smem, x1, pos1, pos2, nbr2, cnt2, v0h, b0, v1h, b1, v2h,
                    b2, x2, blockIdx.x - 512, threadIdx.x);
  }
}

// ---------------- stage 3 conv via split-bf16 MFMA (2-term, barrier-light) --
__global__ void __launch_bounds__(256) conv3_mfma(
    const float* __restrict__ x2, const float* __restrict__ pos2,
    const float* __restrict__ pos3, const int* __restrict__ nbr,
    const int* __restrict__ cntp,
    const unsigned short* __restrict__ w0h, const float* __restrict__ b0,
    const unsigned short* __restrict__ w1h, const float* __restrict__ b1,
    const unsigned short* __restrict__ w2h, const float* __restrict__ b2,
    float* __restrict__ out) {
  __shared__ __attribute__((aligned(16))) float h1s[64 * 268];
  __shared__ __attribute__((aligned(16))) float h2cs[64 * 140];
  const int blk = blockIdx.x;
  const int t = threadIdx.x;
  const int b = blk >> 6;
  const int c = cntp[blk];
  const int w = t >> 6;
  const int lane = t & 63;
  const int cb = lane & 15;
  const int kb = lane >> 4;
  const float cx = pos3[(size_t)blk * 3 + 0];
  const float cy = pos3[(size_t)blk * 3 + 1];
  const float cz = pos3[(size_t)blk * 3 + 2];
  const int mrow = w * 16 + cb;
  const int jrow = nbr[(size_t)blk * KNB + (mrow < c ? mrow : c - 1)];
  const float* xrow = x2 + ((size_t)(b * 256) + jrow) * 256;

  f32x4 acc1[16];
#pragma unroll
  for (int nt = 0; nt < 16; ++nt) acc1[nt] = (f32x4){0.f, 0.f, 0.f, 0.f};
#pragma unroll
  for (int ks = 0; ks < 8; ++ks) {
    float xv[8];
    *(float4*)&xv[0] = *(const float4*)&xrow[ks * 32 + kb * 8];
    *(float4*)&xv[4] = *(const float4*)&xrow[ks * 32 + kb * 8 + 4];
    bf16x8 ahi, alo;
    mkfrag(xv, ahi, alo);
#pragma unroll
    for (int nt = 0; nt < 16; ++nt) {
      size_t off = ((size_t)(nt * 9 + ks) * 64 + lane) * 8;
      bf16x8 bhi = *(const bf16x8*)(w0h + off);
      acc1[nt] = __builtin_amdgcn_mfma_f32_16x16x32_bf16(ahi, bhi, acc1[nt], 0, 0, 0);
      acc1[nt] = __builtin_amdgcn_mfma_f32_16x16x32_bf16(alo, bhi, acc1[nt], 0, 0, 0);
    }
  }
  {
    float xv[8] = {0.f, 0.f, 0.f, 0.f, 0.f, 0.f, 0.f, 0.f};
    if (kb == 0) {
      xv[0] = pos2[((size_t)(b * 256) + jrow) * 3 + 0] - cx;
      xv[1] = pos2[((size_t)(b * 256) + jrow) * 3 + 1] - cy;
      xv[2] = pos2[((size_t)(b * 256) + jrow) * 3 + 2] - cz;
    }
    bf16x8 ahi, alo;
    mkfrag(xv, ahi, alo);
#pragma unroll
    for (int nt = 0; nt < 16; ++nt) {
      size_t off = ((size_t)(nt * 9 + 8) * 64 + lane) * 8;
      bf16x8 bhi = *(const bf16x8*)(w0h + off);
      acc1[nt] = __builtin_amdgcn_mfma_f32_16x16x32_bf16(ahi, bhi, acc1[nt], 0, 0, 0);
      acc1[nt] = __builtin_amdgcn_mfma_f32_16x16x32_bf16(alo, bhi, acc1[nt], 0, 0, 0);
    }
  }
  {
    const int mw = w * 16 + kb * 4;
#pragma unroll
    for (int nt = 0; nt < 16; ++nt) {
      float bias = b0[nt * 16 + cb];
#pragma unroll
      for (int r = 0; r < 4; ++r)
        h1s[(mw + r) * 268 + nt * 16 + cb] = fmaxf(acc1[nt][r] + bias, 0.f);
    }
  }

  f32x4 acc3[32];
#pragma unroll
  for (int nt = 0; nt < 32; ++nt) acc3[nt] = (f32x4){0.f, 0.f, 0.f, 0.f};
  for (int ch = 0; ch < 4; ++ch) {
    f32x4 acc2[8];
#pragma unroll
    for (int nt = 0; nt < 8; ++nt) acc2[nt] = (f32x4){0.f, 0.f, 0.f, 0.f};
#pragma unroll
    for (int ks = 0; ks < 8; ++ks) {
      bf16x8 ahi, alo;
      mkfrag(&h1s[mrow * 268 + ks * 32 + kb * 8], ahi, alo);
#pragma unroll
      for (int nt = 0; nt < 8; ++nt) {
        size_t off = ((size_t)((ch * 8 + nt) * 8 + ks) * 64 + lane) * 8;
        bf16x8 bhi = *(const bf16x8*)(w1h + off);
        acc2[nt] = __builtin_amdgcn_mfma_f32_16x16x32_bf16(ahi, bhi, acc2[nt], 0, 0, 0);
        acc2[nt] = __builtin_amdgcn_mfma_f32_16x16x32_bf16(alo, bhi, acc2[nt], 0, 0, 0);
      }
    }
    {
      const int mw = w * 16 + kb * 4;
#pragma unroll
      for (int nt = 0; nt < 8; ++nt) {
        float bias = b1[ch * 128 + nt * 16 + cb];
#pragma unroll
        for (int r = 0; r < 4; ++r)
          h2cs[(mw + r) * 140 + nt * 16 + cb] = fmaxf(acc2[nt][r] + bias, 0.f);
      }
    }
#pragma unroll
    for (int ks3 = 0; ks3 < 4; ++ks3) {
      bf16x8 ahi, alo;
      mkfrag(&h2cs[mrow * 140 + ks3 * 32 + kb * 8], ahi, alo);
#pragma unroll
      for (int nt = 0; nt < 32; ++nt) {
        size_t off = ((size_t)(nt * 16 + ch * 4 + ks3) * 64 + lane) * 8;
        bf16x8 bhi = *(const bf16x8*)(w2h + off);
        acc3[nt] = __builtin_amdgcn_mfma_f32_16x16x32_bf16(ahi, bhi, acc3[nt], 0, 0, 0);
        acc3[nt] = __builtin_amdgcn_mfma_f32_16x16x32_bf16(alo, bhi, acc3[nt], 0, 0, 0);
      }
    }
  }

  __syncthreads();  // all h1s reads done before alias reuse
  float* redw = h1s;
  {
    const int mw = w * 16 + kb * 4;
#pragma unroll
    for (int nt = 0; nt < 32; ++nt) {
      float bias = b2[nt * 16 + cb];
      float mx = -__builtin_inff();
#pragma unroll
      for (int r = 0; r < 4; ++r) {
        if (mw + r < c) mx = fmaxf(mx, acc3[nt][r] + bias);
      }
      redw[(w * 4 + kb) * 512 + nt * 16 + cb] = mx;
    }
  }
  __syncthreads();
#pragma unroll
  for (int half = 0; half < 2; ++half) {
    int col = t + half * 256;
    float v = redw[col];
#pragma unroll
    for (int g = 1; g < 16; ++g) v = fmaxf(v, redw[g * 512 + col]);
    out[(size_t)blk * 512 + col] = v;
  }
}

extern "C" void kernel_launch(void* const* d_in, const int* in_sizes, int n_in,
                              void* d_out, int out_size, void* d_ws, size_t ws_size,
                              hipStream_t stream) {
  const int* feat = (const int*)d_in[0];
  const float* pos = (const float*)d_in[1];
  const float* emb = (const float*)d_in[2];
  const float* pid = (const float*)d_in[3];
  const float* s1w0 = (const float*)d_in[4];
  const float* s1b0 = (const float*)d_in[5];
  const float* s1w1 = (const float*)d_in[6];
  const float* s1b1 = (const float*)d_in[7];
  const float* s1w2 = (const float*)d_in[8];
  const float* s1b2 = (const float*)d_in[9];
  const float* s2w0 = (const float*)d_in[10];
  const float* s2b0 = (const float*)d_in[11];
  const float* s2w1 = (const float*)d_in[12];
  const float* s2b1 = (const float*)d_in[13];
  const float* s2w2 = (const float*)d_in[14];
  const float* s2b2 = (const float*)d_in[15];
  const float* s3w0 = (const float*)d_in[16];
  const float* s3b0 = (const float*)d_in[17];
  const float* s3w1 = (const float*)d_in[18];
  const float* s3b1 = (const float*)d_in[19];
  const float* s3w2 = (const float*)d_in[20];
  const float* s3b2 = (const float*)d_in[21];
  (void)in_sizes; (void)n_in; (void)out_size; (void)ws_size;

  char* ws = (char*)d_ws;
  size_t off = 0;
  auto alloc = [&](size_t nbytes) {
    void* p = ws + off;
    off = (off + nbytes + 255) & ~(size_t)255;
    return p;
  };
  float* x0 = (float*)alloc((size_t)B * N0 * 32 * 4);
  float* pos1 = (float*)alloc((size_t)B * 1024 * 3 * 4);
  int* nbr1 = (int*)alloc((size_t)B * 1024 * KNB * 4);
  int* cnt1 = (int*)alloc((size_t)B * 1024 * 4);
  float* x1 = (float*)alloc((size_t)B * 1024 * 64 * 4);
  float* pos2 = (float*)alloc((size_t)B * 256 * 3 * 4);
  int* nbr2 = (int*)alloc((size_t)B * 256 * KNB * 4);
  int* cnt2 = (int*)alloc((size_t)B * 256 * 4);
  float* x2 = (float*)alloc((size_t)B * 256 * 256 * 4);
  int* nbr3 = (int*)alloc((size_t)B * 64 * KNB * 4);
  int* cnt3 = (int*)alloc((size_t)B * 64 * 4);
  unsigned short* w0h = (unsigned short*)alloc((size_t)PK_T0 * 2);
  unsigned short* w0l = (unsigned short*)alloc((size_t)PK_T0 * 2);
  unsigned short* w1h = (unsigned short*)alloc((size_t)PK_T1 * 2);
  unsigned short* w1l = (unsigned short*)alloc((size_t)PK_T1 * 2);
  unsigned short* w2h = (unsigned short*)alloc((size_t)PK_T2 * 2);
  unsigned short* w2l = (unsigned short*)alloc((size_t)PK_T2 * 2);
  unsigned short* v0h = (unsigned short*)alloc((size_t)PK_U0 * 2);
  unsigned short* v0l = (unsigned short*)alloc((size_t)PK_U0 * 2);
  unsigned short* v1h = (unsigned short*)alloc((size_t)PK_U1 * 2);
  unsigned short* v1l = (unsigned short*)alloc((size_t)PK_U1 * 2);
  unsigned short* v2h = (unsigned short*)alloc((size_t)PK_U2 * 2);
  unsigned short* v2l = (unsigned short*)alloc((size_t)PK_U2 * 2);

  float* xout = (float*)d_out;                 // (B,64,512)
  float* pos3 = xout + (size_t)B * 64 * 512;   // (B,64,3)

  const float r2a = (float)(0.05 * 0.05);
  const float r2b = (float)(0.3 * 0.3);
  const float r2c = (float)(0.5 * 0.5);

  l1_kernel<<<8 + 4096 + PK_BLOCKS, 256, 0, stream>>>(
      pos, pos1, feat, emb, pid, x0, s3w0, s3w1, s3w2, s2w0, s2w1, s2w2,
      w0h, w0l, w1h, w1l, w2h, w2l, v0h, v0l, v1h, v1l, v2h, v2l);
  l2_kernel<<<8 + 8192, 256, 0, stream>>>(pos1, pos2, pos, r2a, nbr1, cnt1);
  l3_kernel<<<8 + 2048 + 8192, 256, 0, stream>>>(
      pos2, pos3, r2b, nbr2, cnt2, pos1, x0, pos, nbr1, cnt1,
      s1w0, s1b0, s1w1, s1b1, s1w2, s1b2, x1);
  l4_kernel<<<512 + 2048, 256, 0, stream>>>(
      pos2, pos3, r2c, nbr3, cnt3, x1, pos1, nbr2, cnt2,
      v0h, s2b0, v1h, s2b1, v2h, s2b2, x2);
  conv3_mfma<<<B * 64, 256, 0, stream>>>(x2, pos2, pos3, nbr3, cnt3,
                                         w0h, s3b0, w1h, s3b1, w2h, s3b2, xout);
}